// Round 2
// baseline (591.716 us; speedup 1.0000x reference)
//
#include <hip/hip_runtime.h>
#include <math.h>

#define N_NODES 30000
#define N_EDGES 480000

// ---------------------------------------------------------------------------
// Kernel 1: per-node precompute  x0 = node_s @ W1_0 * inv_m   (N,32)
//                                x1 = einsum(node_v, W1_1) * inv_m (N,32,3)
// stored as xnode[n][128]: [0:32]=x0[w], [32+d*32+w]=x1[w][d]  (d-major planes
// so the edge kernel's gathers are coalesced across the 32-lane group)
// ---------------------------------------------------------------------------
__global__ __launch_bounds__(256) void node_pre_kernel(
    const float* __restrict__ node_s,   // (N,32)
    const float* __restrict__ node_v,   // (N,32,3)
    const float* __restrict__ W1_0,     // (32,32) [u][w]
    const float* __restrict__ W1_1,     // (32,32) [u][w]
    float* __restrict__ xnode)          // (N,128)
{
    __shared__ float sW0[32 * 32];
    __shared__ float sW1[32 * 32];
    int tid = threadIdx.x;
    for (int i = tid; i < 1024; i += 256) {
        sW0[i] = W1_0[i];
        sW1[i] = W1_1[i];
    }
    __syncthreads();
    int node = blockIdx.x * 8 + (tid >> 5);
    int w = tid & 31;
    const float inv_m = 0.1767766953f;  // 1/sqrt(32)
    float x0 = 0.f, x1a = 0.f, x1b = 0.f, x1c = 0.f;
    const float* sp = node_s + (size_t)node * 32;
    const float* vp = node_v + (size_t)node * 96;
#pragma unroll
    for (int u = 0; u < 32; ++u) {
        float su = sp[u];
        float w0 = sW0[u * 32 + w];
        float w1 = sW1[u * 32 + w];
        x0 = fmaf(su, w0, x0);
        float v0 = vp[u * 3 + 0];
        float v1 = vp[u * 3 + 1];
        float v2 = vp[u * 3 + 2];
        x1a = fmaf(v0, w1, x1a);
        x1b = fmaf(v1, w1, x1b);
        x1c = fmaf(v2, w1, x1c);
    }
    float* xp = xnode + (size_t)node * 128;
    xp[w]      = x0  * inv_m;
    xp[32 + w] = x1a * inv_m;
    xp[64 + w] = x1b * inv_m;
    xp[96 + w] = x1c * inv_m;
}

// ---------------------------------------------------------------------------
// Kernel 2: per-edge weights + tensor products + scatter-add to agg[src].
// Block = 256 threads = 8 edges x 32 lanes (lane = channel u).
// agg[n][256]: [0:32]=s_a(k=u), [32:64]=s_b(k=32+u),
//              [64 + d*64 + k] = v (k=u for v_a, k=32+u for v_b)
// ---------------------------------------------------------------------------
__global__ __launch_bounds__(256) void edge_kernel(
    const float* __restrict__ edge_attr,     // (E,4)
    const float* __restrict__ edge_scalars,  // (E,8)
    const float* __restrict__ Wfc1,          // (8,8)  [k][i]
    const float* __restrict__ Wfc2,          // (8,128) [i][j]
    const int* __restrict__ edge_src,
    const int* __restrict__ edge_dst,
    const float* __restrict__ xnode,         // (N,128)
    float* __restrict__ agg)                 // (N,256)
{
    __shared__ float sWfc2[8 * 128];
    __shared__ float sWfc1[64];
    __shared__ float sH[8][8];
    int tid = threadIdx.x;
    if (tid < 64) sWfc1[tid] = Wfc1[tid];
    for (int i = tid; i < 1024; i += 256) sWfc2[i] = Wfc2[i];
    __syncthreads();

    int e0 = blockIdx.x * 8;
    // --- phase 1: h = ssp(es @ Wfc1 / sqrt(8)) for the block's 8 edges ---
    if (tid < 64) {
        int el = tid >> 3;
        int i = tid & 7;
        const float* es = edge_scalars + (size_t)(e0 + el) * 8;
        float acc = 0.f;
#pragma unroll
        for (int k = 0; k < 8; ++k) acc = fmaf(es[k], sWfc1[k * 8 + i], acc);
        acc *= 0.3535533906f;  // 1/sqrt(8)
        // stable softplus(x) - log(2)
        float ax = fabsf(acc);
        float sp = fmaxf(acc, 0.f) + log1pf(expf(-ax));
        sH[el][i] = sp - 0.6931471806f;
    }
    __syncthreads();

    // --- phase 2: one 32-lane group per edge ---
    int el = tid >> 5;
    int u = tid & 31;
    int e = e0 + el;
    float a00 = 0.f, a01 = 0.f, a10 = 0.f, a11 = 0.f;
#pragma unroll
    for (int i = 0; i < 8; ++i) {
        float h = sH[el][i];
        a00 = fmaf(h, sWfc2[i * 128 + u], a00);
        a01 = fmaf(h, sWfc2[i * 128 + 32 + u], a01);
        a10 = fmaf(h, sWfc2[i * 128 + 64 + u], a10);
        a11 = fmaf(h, sWfc2[i * 128 + 96 + u], a11);
    }
    const float inv8 = 0.3535533906f;  // 1/sqrt(8)
    a00 *= inv8; a01 *= inv8; a10 *= inv8; a11 *= inv8;

    int src = edge_src[e];
    int dst = edge_dst[e];
    float4 ea = *(const float4*)(edge_attr + (size_t)e * 4);
    float sh0 = ea.x;
    float s1x = ea.y, s1y = ea.z, s1z = ea.w;

    const float* xp = xnode + (size_t)dst * 128;
    float x0  = xp[u];
    float xd0 = xp[32 + u];
    float xd1 = xp[64 + u];
    float xd2 = xp[96 + u];

    const float inv_sqrt3 = 0.5773502692f;
    float dot = xd0 * s1x + xd1 * s1y + xd2 * s1z;
    float s_a = a00 * x0 * sh0;
    float s_b = a11 * dot * inv_sqrt3;
    float w01x0 = a01 * x0;
    float va0 = w01x0 * s1x, va1 = w01x0 * s1y, va2 = w01x0 * s1z;
    float vb0 = a10 * xd0 * sh0, vb1 = a10 * xd1 * sh0, vb2 = a10 * xd2 * sh0;

    float* ap = agg + (size_t)src * 256;
    unsafeAtomicAdd(ap + u,       s_a);
    unsafeAtomicAdd(ap + 32 + u,  s_b);
    unsafeAtomicAdd(ap + 64 + u,  va0);
    unsafeAtomicAdd(ap + 128 + u, va1);
    unsafeAtomicAdd(ap + 192 + u, va2);
    unsafeAtomicAdd(ap + 96 + u,  vb0);
    unsafeAtomicAdd(ap + 160 + u, vb1);
    unsafeAtomicAdd(ap + 224 + u, vb2);
}

// ---------------------------------------------------------------------------
// Kernel 3: per-node output  out0 = agg_s @ W2_0 * inv_nb*inv_2m + sc0
//                            out1 = agg_v @ W2_1 * inv_nb*inv_2m + sc1
// out[n][0:32] = o0[w];  out[n][32 + 3*w + d] = o1[w][d]
// ---------------------------------------------------------------------------
__global__ __launch_bounds__(256) void node_out_kernel(
    const float* __restrict__ node_s,
    const float* __restrict__ node_v,
    const float* __restrict__ node_attr,  // (N,8)
    const float* __restrict__ W2_0,       // (64,32) [k][w]
    const float* __restrict__ W2_1,       // (64,32) [k][w]
    const float* __restrict__ Wsc0,       // (32,8,32) [u][v][w]
    const float* __restrict__ Wsc1,       // (32,8,32)
    const float* __restrict__ agg,        // (N,256)
    float* __restrict__ out)              // (N,128)
{
    __shared__ float sW20[64 * 32];
    __shared__ float sW21[64 * 32];
    __shared__ float sWsc0[32 * 8 * 32];
    __shared__ float sWsc1[32 * 8 * 32];
    int tid = threadIdx.x;
    for (int i = tid; i < 2048; i += 256) { sW20[i] = W2_0[i]; sW21[i] = W2_1[i]; }
    for (int i = tid; i < 8192; i += 256) { sWsc0[i] = Wsc0[i]; sWsc1[i] = Wsc1[i]; }
    __syncthreads();

    int node = blockIdx.x * 8 + (tid >> 5);
    int w = tid & 31;
    const float scale2 = 0.25f * 0.125f;  // inv_nb * inv_2m = 1/sqrt(16)*1/sqrt(64)
    const float sc_norm = 0.0625f;        // 1/sqrt(32*8)

    const float* ap = agg + (size_t)node * 256;
    float o0 = 0.f, o1x = 0.f, o1y = 0.f, o1z = 0.f;
#pragma unroll 8
    for (int k = 0; k < 64; ++k) {
        float w20 = sW20[k * 32 + w];
        float w21 = sW21[k * 32 + w];
        o0  = fmaf(ap[k],       w20, o0);
        o1x = fmaf(ap[64 + k],  w21, o1x);
        o1y = fmaf(ap[128 + k], w21, o1y);
        o1z = fmaf(ap[192 + k], w21, o1z);
    }
    o0 *= scale2; o1x *= scale2; o1y *= scale2; o1z *= scale2;

    // self-connection
    const float* sp  = node_s + (size_t)node * 32;
    const float* vp  = node_v + (size_t)node * 96;
    const float* atp = node_attr + (size_t)node * 8;
    float a[8];
#pragma unroll
    for (int v = 0; v < 8; ++v) a[v] = atp[v];
    float sc0 = 0.f, sc1x = 0.f, sc1y = 0.f, sc1z = 0.f;
#pragma unroll 4
    for (int u = 0; u < 32; ++u) {
        float m0 = 0.f, m1 = 0.f;
#pragma unroll
        for (int v = 0; v < 8; ++v) {
            m0 = fmaf(a[v], sWsc0[(u * 8 + v) * 32 + w], m0);
            m1 = fmaf(a[v], sWsc1[(u * 8 + v) * 32 + w], m1);
        }
        float su = sp[u];
        sc0 = fmaf(su, m0, sc0);
        float v0 = vp[u * 3 + 0];
        float v1 = vp[u * 3 + 1];
        float v2 = vp[u * 3 + 2];
        sc1x = fmaf(v0, m1, sc1x);
        sc1y = fmaf(v1, m1, sc1y);
        sc1z = fmaf(v2, m1, sc1z);
    }
    o0  = fmaf(sc0,  sc_norm, o0);
    o1x = fmaf(sc1x, sc_norm, o1x);
    o1y = fmaf(sc1y, sc_norm, o1y);
    o1z = fmaf(sc1z, sc_norm, o1z);

    float* op = out + (size_t)node * 128;
    op[w]              = o0;
    op[32 + 3 * w]     = o1x;
    op[32 + 3 * w + 1] = o1y;
    op[32 + 3 * w + 2] = o1z;
}

extern "C" void kernel_launch(void* const* d_in, const int* in_sizes, int n_in,
                              void* d_out, int out_size, void* d_ws, size_t ws_size,
                              hipStream_t stream) {
    const float* node_s       = (const float*)d_in[0];
    const float* node_v       = (const float*)d_in[1];
    const float* node_attr    = (const float*)d_in[2];
    const float* edge_attr    = (const float*)d_in[3];
    const float* edge_scalars = (const float*)d_in[4];
    const float* W1_0 = (const float*)d_in[5];
    const float* W1_1 = (const float*)d_in[6];
    const float* Wfc1 = (const float*)d_in[7];
    const float* Wfc2 = (const float*)d_in[8];
    const float* W2_0 = (const float*)d_in[9];
    const float* W2_1 = (const float*)d_in[10];
    const float* Wsc0 = (const float*)d_in[11];
    const float* Wsc1 = (const float*)d_in[12];
    const int* edge_src = (const int*)d_in[13];
    const int* edge_dst = (const int*)d_in[14];

    float* xnode = (float*)d_ws;                         // N*128 f32 = 15.36 MB
    float* agg   = xnode + (size_t)N_NODES * 128;        // N*256 f32 = 30.72 MB

    hipMemsetAsync(agg, 0, (size_t)N_NODES * 256 * sizeof(float), stream);
    node_pre_kernel<<<N_NODES / 8, 256, 0, stream>>>(node_s, node_v, W1_0, W1_1, xnode);
    edge_kernel<<<N_EDGES / 8, 256, 0, stream>>>(edge_attr, edge_scalars, Wfc1, Wfc2,
                                                 edge_src, edge_dst, xnode, agg);
    node_out_kernel<<<N_NODES / 8, 256, 0, stream>>>(node_s, node_v, node_attr,
                                                     W2_0, W2_1, Wsc0, Wsc1, agg,
                                                     (float*)d_out);
}

// Round 3
// 389.601 us; speedup vs baseline: 1.5188x; 1.5188x over previous
//
#include <hip/hip_runtime.h>
#include <math.h>

#define N_NODES 30000
#define N_EDGES 480000

__device__ __forceinline__ unsigned short f2bf(float f) {
    unsigned u = __float_as_uint(f);
    u += 0x7fff + ((u >> 16) & 1);          // RNE
    return (unsigned short)(u >> 16);
}
__device__ __forceinline__ float bf2f(unsigned short s) {
    return __uint_as_float(((unsigned)s) << 16);
}

// ---------------------------------------------------------------------------
// Kernel 1: per-node precompute x0/x1, stored bf16 as xnode[n][128]:
// [0:32]=x0[w], [32+d*32+w]=x1[w][d]
// ---------------------------------------------------------------------------
__global__ __launch_bounds__(256) void node_pre_kernel(
    const float* __restrict__ node_s,   // (N,32)
    const float* __restrict__ node_v,   // (N,32,3)
    const float* __restrict__ W1_0,     // (32,32) [u][w]
    const float* __restrict__ W1_1,     // (32,32) [u][w]
    unsigned short* __restrict__ xnode) // (N,128) bf16
{
    __shared__ float sW0[1024];
    __shared__ float sW1[1024];
    int tid = threadIdx.x;
    for (int i = tid; i < 1024; i += 256) { sW0[i] = W1_0[i]; sW1[i] = W1_1[i]; }
    __syncthreads();
    int node = blockIdx.x * 8 + (tid >> 5);
    int w = tid & 31;
    const float inv_m = 0.1767766953f;  // 1/sqrt(32)
    float x0 = 0.f, x1a = 0.f, x1b = 0.f, x1c = 0.f;
    const float* sp = node_s + (size_t)node * 32;
    const float* vp = node_v + (size_t)node * 96;
#pragma unroll
    for (int u = 0; u < 32; ++u) {
        float su = sp[u];
        float w0 = sW0[u * 32 + w];
        float w1 = sW1[u * 32 + w];
        x0 = fmaf(su, w0, x0);
        float v0 = vp[u * 3 + 0];
        float v1 = vp[u * 3 + 1];
        float v2 = vp[u * 3 + 2];
        x1a = fmaf(v0, w1, x1a);
        x1b = fmaf(v1, w1, x1b);
        x1c = fmaf(v2, w1, x1c);
    }
    unsigned short* xp = xnode + (size_t)node * 128;
    xp[w]      = f2bf(x0  * inv_m);
    xp[32 + w] = f2bf(x1a * inv_m);
    xp[64 + w] = f2bf(x1b * inv_m);
    xp[96 + w] = f2bf(x1c * inv_m);
}

// ---------------------------------------------------------------------------
// CSR build: degree count -> single-block scan -> bucket edge ids
// ---------------------------------------------------------------------------
__global__ __launch_bounds__(256) void deg_kernel(const int* __restrict__ edge_src,
                                                  int* __restrict__ deg) {
    int e = blockIdx.x * 256 + threadIdx.x;
    atomicAdd(&deg[edge_src[e]], 1);
}

__global__ __launch_bounds__(1024) void scan_kernel(const int* __restrict__ deg,
                                                    int* __restrict__ offs,
                                                    int* __restrict__ cursor) {
    // 1024 threads, 30 nodes per thread (covers 30720 >= 30000)
    int tid = threadIdx.x;
    int base = tid * 30;
    int s = 0;
    for (int k = 0; k < 30; ++k) {
        int n = base + k;
        if (n < N_NODES) s += deg[n];
    }
    int lane = tid & 63, wid = tid >> 6;
    int inc = s;
#pragma unroll
    for (int d = 1; d < 64; d <<= 1) {
        int o = __shfl_up(inc, d, 64);
        if (lane >= d) inc += o;
    }
    __shared__ int wsum[16];
    if (lane == 63) wsum[wid] = inc;
    __syncthreads();
    if (tid < 16) {
        int v = wsum[tid];
        int t = v;
#pragma unroll
        for (int d = 1; d < 16; d <<= 1) {
            int o = __shfl_up(t, d, 64);
            if (tid >= d) t += o;
        }
        wsum[tid] = t - v;  // exclusive
    }
    __syncthreads();
    int run = inc - s + wsum[wid];  // exclusive prefix for this thread
    for (int k = 0; k < 30; ++k) {
        int n = base + k;
        if (n < N_NODES) {
            offs[n] = run;
            cursor[n] = run;
            run += deg[n];
        }
    }
    if (tid == 1023) offs[N_NODES] = run;  // == E
}

__global__ __launch_bounds__(256) void fill_kernel(const int* __restrict__ edge_src,
                                                   int* __restrict__ cursor,
                                                   int* __restrict__ rEid) {
    int e = blockIdx.x * 256 + threadIdx.x;
    int pos = atomicAdd(&cursor[edge_src[e]], 1);
    rEid[pos] = e;
}

// ---------------------------------------------------------------------------
// Kernel 5: node-centric aggregation, NO atomics.
// One wave (64 lanes) per node; half-wave (32 lanes = channel u) per edge.
// Per-edge MLP weights recomputed from register-resident Wfc1/Wfc2.
// agg[n][256]: [0:32]=s_a, [32:64]=s_b, [64+64d+u]=va_d, [64+64d+32+u]=vb_d
// ---------------------------------------------------------------------------
__global__ __launch_bounds__(256) void gather_kernel(
    const int* __restrict__ offs,
    const int* __restrict__ rEid,
    const int* __restrict__ edge_dst,
    const float* __restrict__ edge_attr,     // (E,4)
    const float* __restrict__ edge_scalars,  // (E,8)
    const float* __restrict__ Wfc1,          // (8,8)  [k][i]
    const float* __restrict__ Wfc2,          // (8,128)
    const unsigned short* __restrict__ xnode,
    float* __restrict__ agg)
{
    int tid = threadIdx.x;
    int lane = tid & 63;
    int u = lane & 31;
    int half = lane >> 5;
    int lb = lane & 32;
    int node = blockIdx.x * 4 + (tid >> 6);

    // register-resident weights (no LDS streaming: ds_read is 5.8cyc/instr)
    float wfc1r[8];
#pragma unroll
    for (int j = 0; j < 8; ++j) wfc1r[j] = Wfc1[j * 8 + (u & 7)];
    float wf[8][4];
#pragma unroll
    for (int i = 0; i < 8; ++i)
#pragma unroll
        for (int c = 0; c < 4; ++c) wf[i][c] = Wfc2[i * 128 + c * 32 + u];

    int beg = offs[node], end = offs[node + 1];
    float a_sa = 0.f, a_sb = 0.f;
    float a_va0 = 0.f, a_va1 = 0.f, a_va2 = 0.f;
    float a_vb0 = 0.f, a_vb1 = 0.f, a_vb2 = 0.f;
    const float inv8 = 0.3535533906f;       // 1/sqrt(8)
    const float inv_sqrt3 = 0.5773502692f;

    for (int i = beg + half; i < end; i += 2) {
        int eid = rEid[i];
        int dst = edge_dst[eid];
        float4 ea  = *(const float4*)(edge_attr + (size_t)eid * 4);
        float4 es0 = *(const float4*)(edge_scalars + (size_t)eid * 8);
        float4 es1 = *(const float4*)(edge_scalars + (size_t)eid * 8 + 4);
        // h_i for i = u&7 (redundant x4 within half-wave)
        float acc = es0.x * wfc1r[0];
        acc = fmaf(es0.y, wfc1r[1], acc);
        acc = fmaf(es0.z, wfc1r[2], acc);
        acc = fmaf(es0.w, wfc1r[3], acc);
        acc = fmaf(es1.x, wfc1r[4], acc);
        acc = fmaf(es1.y, wfc1r[5], acc);
        acc = fmaf(es1.z, wfc1r[6], acc);
        acc = fmaf(es1.w, wfc1r[7], acc);
        acc *= inv8;
        float ax = fabsf(acc);
        float t = __expf(-ax);
        float hme = fmaxf(acc, 0.f) + __logf(1.f + t) - 0.6931471806f;
        // share h across the half-wave, contract with Wfc2 (registers)
        float a00 = 0.f, a01 = 0.f, a10 = 0.f, a11 = 0.f;
#pragma unroll
        for (int i2 = 0; i2 < 8; ++i2) {
            float hi = __shfl(hme, lb + i2, 64);
            a00 = fmaf(hi, wf[i2][0], a00);
            a01 = fmaf(hi, wf[i2][1], a01);
            a10 = fmaf(hi, wf[i2][2], a10);
            a11 = fmaf(hi, wf[i2][3], a11);
        }
        a00 *= inv8; a01 *= inv8; a10 *= inv8; a11 *= inv8;

        const unsigned short* xp = xnode + (size_t)dst * 128;
        float x0  = bf2f(xp[u]);
        float xd0 = bf2f(xp[32 + u]);
        float xd1 = bf2f(xp[64 + u]);
        float xd2 = bf2f(xp[96 + u]);
        float sh0 = ea.x, s1x = ea.y, s1y = ea.z, s1z = ea.w;

        float dot = xd0 * s1x + xd1 * s1y + xd2 * s1z;
        a_sa = fmaf(a00 * sh0, x0, a_sa);
        a_sb = fmaf(a11 * inv_sqrt3, dot, a_sb);
        float w01x0 = a01 * x0;
        a_va0 = fmaf(w01x0, s1x, a_va0);
        a_va1 = fmaf(w01x0, s1y, a_va1);
        a_va2 = fmaf(w01x0, s1z, a_va2);
        float t10 = a10 * sh0;
        a_vb0 = fmaf(t10, xd0, a_vb0);
        a_vb1 = fmaf(t10, xd1, a_vb1);
        a_vb2 = fmaf(t10, xd2, a_vb2);
    }
    // combine halves
    a_sa  += __shfl_xor(a_sa, 32, 64);
    a_sb  += __shfl_xor(a_sb, 32, 64);
    a_va0 += __shfl_xor(a_va0, 32, 64);
    a_va1 += __shfl_xor(a_va1, 32, 64);
    a_va2 += __shfl_xor(a_va2, 32, 64);
    a_vb0 += __shfl_xor(a_vb0, 32, 64);
    a_vb1 += __shfl_xor(a_vb1, 32, 64);
    a_vb2 += __shfl_xor(a_vb2, 32, 64);

    float* ap = agg + (size_t)node * 256;
    if (half == 0) {
        ap[u]       = a_sa;
        ap[32 + u]  = a_sb;
        ap[64 + u]  = a_va0;
        ap[96 + u]  = a_vb0;
    } else {
        ap[128 + u] = a_va1;
        ap[160 + u] = a_vb1;
        ap[192 + u] = a_va2;
        ap[224 + u] = a_vb2;
    }
}

// ---------------------------------------------------------------------------
// Kernel 6: fused W2-apply + self-connection + output.
// 4 nodes per thread so each ds_read of a weight amortizes over 4 fmas.
// ---------------------------------------------------------------------------
#define VE(A, B, C, idx) ((idx) < 4 ? (&(A).x)[(idx)] : (idx) < 8 ? (&(B).x)[(idx) - 4] : (&(C).x)[(idx) - 8])

__global__ __launch_bounds__(256, 2) void final_kernel(
    const float* __restrict__ node_s,
    const float* __restrict__ node_v,
    const float* __restrict__ node_attr,  // (N,8)
    const float* __restrict__ W2_0,       // (64,32) [k][w]
    const float* __restrict__ W2_1,       // (64,32) [k][w]
    const float* __restrict__ Wsc0,       // (32,8,32) [u][v][w]
    const float* __restrict__ Wsc1,       // (32,8,32)
    const float* __restrict__ agg,        // (N,256)
    float* __restrict__ out)              // (N,128)
{
    __shared__ float sW20[2048];
    __shared__ float sW21[2048];
    __shared__ float sWsc0[8192];
    __shared__ float sWsc1[8192];
    int tid = threadIdx.x;
    for (int i = tid; i < 2048; i += 256) { sW20[i] = W2_0[i]; sW21[i] = W2_1[i]; }
    for (int i = tid; i < 8192; i += 256) { sWsc0[i] = Wsc0[i]; sWsc1[i] = Wsc1[i]; }
    __syncthreads();

    int w = tid & 31;
    int n0 = blockIdx.x * 32 + (tid >> 5) * 4;
    int n[4];
#pragma unroll
    for (int j = 0; j < 4; ++j) n[j] = min(n0 + j, N_NODES - 1);

    // ---- W2 stage ----
    float o0[4] = {0.f, 0.f, 0.f, 0.f}, o1x[4] = {0.f, 0.f, 0.f, 0.f};
    float o1y[4] = {0.f, 0.f, 0.f, 0.f}, o1z[4] = {0.f, 0.f, 0.f, 0.f};
    for (int k4 = 0; k4 < 64; k4 += 4) {
        float4 p0[4], p1[4], p2[4], p3[4];
#pragma unroll
        for (int j = 0; j < 4; ++j) {
            const float* ap = agg + (size_t)n[j] * 256;
            p0[j] = *(const float4*)(ap + k4);
            p1[j] = *(const float4*)(ap + 64 + k4);
            p2[j] = *(const float4*)(ap + 128 + k4);
            p3[j] = *(const float4*)(ap + 192 + k4);
        }
#pragma unroll
        for (int kk = 0; kk < 4; ++kk) {
            float w20 = sW20[(k4 + kk) * 32 + w];
            float w21 = sW21[(k4 + kk) * 32 + w];
#pragma unroll
            for (int j = 0; j < 4; ++j) {
                o0[j]  = fmaf((&p0[j].x)[kk], w20, o0[j]);
                o1x[j] = fmaf((&p1[j].x)[kk], w21, o1x[j]);
                o1y[j] = fmaf((&p2[j].x)[kk], w21, o1y[j]);
                o1z[j] = fmaf((&p3[j].x)[kk], w21, o1z[j]);
            }
        }
    }

    // ---- self-connection stage ----
    float a[4][8];
#pragma unroll
    for (int j = 0; j < 4; ++j) {
        float4 a0 = *(const float4*)(node_attr + (size_t)n[j] * 8);
        float4 a1 = *(const float4*)(node_attr + (size_t)n[j] * 8 + 4);
        a[j][0] = a0.x; a[j][1] = a0.y; a[j][2] = a0.z; a[j][3] = a0.w;
        a[j][4] = a1.x; a[j][5] = a1.y; a[j][6] = a1.z; a[j][7] = a1.w;
    }
    float sc0[4] = {0.f, 0.f, 0.f, 0.f}, sc1x[4] = {0.f, 0.f, 0.f, 0.f};
    float sc1y[4] = {0.f, 0.f, 0.f, 0.f}, sc1z[4] = {0.f, 0.f, 0.f, 0.f};
    for (int uc = 0; uc < 32; uc += 4) {
        float4 sv[4], vv0[4], vv1[4], vv2[4];
#pragma unroll
        for (int j = 0; j < 4; ++j) {
            sv[j] = *(const float4*)(node_s + (size_t)n[j] * 32 + uc);
            const float* vp = node_v + (size_t)n[j] * 96 + uc * 3;
            vv0[j] = *(const float4*)(vp);
            vv1[j] = *(const float4*)(vp + 4);
            vv2[j] = *(const float4*)(vp + 8);
        }
#pragma unroll
        for (int kk = 0; kk < 4; ++kk) {
            int u = uc + kk;
            float m0[4] = {0.f, 0.f, 0.f, 0.f}, m1[4] = {0.f, 0.f, 0.f, 0.f};
#pragma unroll
            for (int v = 0; v < 8; ++v) {
                float q0 = sWsc0[(u * 8 + v) * 32 + w];
                float q1 = sWsc1[(u * 8 + v) * 32 + w];
#pragma unroll
                for (int j = 0; j < 4; ++j) {
                    m0[j] = fmaf(a[j][v], q0, m0[j]);
                    m1[j] = fmaf(a[j][v], q1, m1[j]);
                }
            }
#pragma unroll
            for (int j = 0; j < 4; ++j) {
                float s  = (&sv[j].x)[kk];
                float vx = VE(vv0[j], vv1[j], vv2[j], kk * 3 + 0);
                float vy = VE(vv0[j], vv1[j], vv2[j], kk * 3 + 1);
                float vz = VE(vv0[j], vv1[j], vv2[j], kk * 3 + 2);
                sc0[j]  = fmaf(s,  m0[j], sc0[j]);
                sc1x[j] = fmaf(vx, m1[j], sc1x[j]);
                sc1y[j] = fmaf(vy, m1[j], sc1y[j]);
                sc1z[j] = fmaf(vz, m1[j], sc1z[j]);
            }
        }
    }

    const float scale2  = 0.03125f;  // 1/sqrt(16)*1/sqrt(64)
    const float sc_norm = 0.0625f;   // 1/sqrt(32*8)
#pragma unroll
    for (int j = 0; j < 4; ++j) {
        if (n0 + j < N_NODES) {
            float* op = out + (size_t)n[j] * 128;
            op[w]              = fmaf(sc0[j],  sc_norm, o0[j]  * scale2);
            op[32 + 3 * w]     = fmaf(sc1x[j], sc_norm, o1x[j] * scale2);
            op[32 + 3 * w + 1] = fmaf(sc1y[j], sc_norm, o1y[j] * scale2);
            op[32 + 3 * w + 2] = fmaf(sc1z[j], sc_norm, o1z[j] * scale2);
        }
    }
}

extern "C" void kernel_launch(void* const* d_in, const int* in_sizes, int n_in,
                              void* d_out, int out_size, void* d_ws, size_t ws_size,
                              hipStream_t stream) {
    const float* node_s       = (const float*)d_in[0];
    const float* node_v       = (const float*)d_in[1];
    const float* node_attr    = (const float*)d_in[2];
    const float* edge_attr    = (const float*)d_in[3];
    const float* edge_scalars = (const float*)d_in[4];
    const float* W1_0 = (const float*)d_in[5];
    const float* W1_1 = (const float*)d_in[6];
    const float* Wfc1 = (const float*)d_in[7];
    const float* Wfc2 = (const float*)d_in[8];
    const float* W2_0 = (const float*)d_in[9];
    const float* W2_1 = (const float*)d_in[10];
    const float* Wsc0 = (const float*)d_in[11];
    const float* Wsc1 = (const float*)d_in[12];
    const int* edge_src = (const int*)d_in[13];
    const int* edge_dst = (const int*)d_in[14];

    // workspace layout (bytes), total ~40.7MB <= 46.08MB proven in round 2
    char* ws = (char*)d_ws;
    unsigned short* xnode = (unsigned short*)(ws);              // N*128*2  = 7,680,000
    float* agg   = (float*)(ws + 7680000);                      // N*256*4  = 30,720,000
    int*   rEid  = (int*)(ws + 38400000);                       // E*4      = 1,920,000
    int*   deg   = (int*)(ws + 40320000);                       // N*4
    int*   offs  = (int*)(ws + 40440000);                       // (N+1)*4 (pad to 120016)
    int*   cursor= (int*)(ws + 40560016);                       // N*4

    hipMemsetAsync(deg, 0, (size_t)N_NODES * sizeof(int), stream);
    node_pre_kernel<<<N_NODES / 8, 256, 0, stream>>>(node_s, node_v, W1_0, W1_1, xnode);
    deg_kernel<<<N_EDGES / 256, 256, 0, stream>>>(edge_src, deg);
    scan_kernel<<<1, 1024, 0, stream>>>(deg, offs, cursor);
    fill_kernel<<<N_EDGES / 256, 256, 0, stream>>>(edge_src, cursor, rEid);
    gather_kernel<<<N_NODES / 4, 256, 0, stream>>>(offs, rEid, edge_dst, edge_attr,
                                                   edge_scalars, Wfc1, Wfc2, xnode, agg);
    final_kernel<<<(N_NODES + 31) / 32, 256, 0, stream>>>(node_s, node_v, node_attr,
                                                          W2_0, W2_1, Wsc0, Wsc1, agg,
                                                          (float*)d_out);
}

// Round 4
// 384.957 us; speedup vs baseline: 1.5371x; 1.0121x over previous
//
#include <hip/hip_runtime.h>
#include <math.h>

#define N_NODES 30000
#define N_EDGES 480000

__device__ __forceinline__ unsigned short f2bf(float f) {
    unsigned u = __float_as_uint(f);
    u += 0x7fff + ((u >> 16) & 1);          // RNE
    return (unsigned short)(u >> 16);
}
__device__ __forceinline__ float bfLO(unsigned v) { return __uint_as_float(v << 16); }
__device__ __forceinline__ float bfHI(unsigned v) { return __uint_as_float(v & 0xffff0000u); }
__device__ __forceinline__ unsigned packbf(float a, float b) {
    return (unsigned)f2bf(a) | ((unsigned)f2bf(b) << 16);
}

#define VE(A, B, C, idx) ((idx) < 4 ? (&(A).x)[(idx)] : (idx) < 8 ? (&(B).x)[(idx) - 4] : (&(C).x)[(idx) - 8])

// ---------------------------------------------------------------------------
// front: fused node precompute (x0/x1 -> xnode bf16-packed) + self-connection
// (-> out, overwritten). 4 nodes/thread amortizes LDS weight reads.
// xnode[n] layout: per channel u: 4 bf16 {x0, x1x, x1y, x1z} = one uint2.
// ---------------------------------------------------------------------------
__global__ __launch_bounds__(256, 3) void front_kernel(
    const float* __restrict__ node_s,     // (N,32)
    const float* __restrict__ node_v,     // (N,32,3)
    const float* __restrict__ node_attr,  // (N,8)
    const float* __restrict__ W1_0,       // (32,32) [u][w]
    const float* __restrict__ W1_1,
    const float* __restrict__ Wsc0,       // (32,8,32) [u][v][w]
    const float* __restrict__ Wsc1,
    unsigned short* __restrict__ xnode,   // (N,128) bf16 packed
    float* __restrict__ out)              // (N,128) f32
{
    __shared__ float sW10[1024];
    __shared__ float sW11[1024];
    __shared__ unsigned sWsc0p[4096];   // v-pairs packed bf16: [(u*4+p)*32 + w]
    __shared__ unsigned sWsc1p[4096];
    int tid = threadIdx.x;
    for (int i = tid; i < 1024; i += 256) { sW10[i] = W1_0[i]; sW11[i] = W1_1[i]; }
    for (int i = tid; i < 4096; i += 256) {
        int u = i >> 7, r = i & 127, p = r >> 5, ww = r & 31;
        sWsc0p[i] = packbf(Wsc0[(u * 8 + 2 * p) * 32 + ww], Wsc0[(u * 8 + 2 * p + 1) * 32 + ww]);
        sWsc1p[i] = packbf(Wsc1[(u * 8 + 2 * p) * 32 + ww], Wsc1[(u * 8 + 2 * p + 1) * 32 + ww]);
    }
    __syncthreads();

    int w = tid & 31;
    int n0 = blockIdx.x * 32 + (tid >> 5) * 4;
    int n[4];
#pragma unroll
    for (int j = 0; j < 4; ++j) n[j] = min(n0 + j, N_NODES - 1);

    float a[4][8];
#pragma unroll
    for (int j = 0; j < 4; ++j) {
        float4 a0 = *(const float4*)(node_attr + (size_t)n[j] * 8);
        float4 a1 = *(const float4*)(node_attr + (size_t)n[j] * 8 + 4);
        a[j][0] = a0.x; a[j][1] = a0.y; a[j][2] = a0.z; a[j][3] = a0.w;
        a[j][4] = a1.x; a[j][5] = a1.y; a[j][6] = a1.z; a[j][7] = a1.w;
    }

    float x0[4]  = {0.f, 0.f, 0.f, 0.f}, x1a[4] = {0.f, 0.f, 0.f, 0.f};
    float x1b[4] = {0.f, 0.f, 0.f, 0.f}, x1c[4] = {0.f, 0.f, 0.f, 0.f};
    float sc0[4] = {0.f, 0.f, 0.f, 0.f}, s1x[4] = {0.f, 0.f, 0.f, 0.f};
    float s1y[4] = {0.f, 0.f, 0.f, 0.f}, s1z[4] = {0.f, 0.f, 0.f, 0.f};

    for (int uc = 0; uc < 32; uc += 4) {
        float4 sv[4], vv0[4], vv1[4], vv2[4];
#pragma unroll
        for (int j = 0; j < 4; ++j) {
            sv[j] = *(const float4*)(node_s + (size_t)n[j] * 32 + uc);
            const float* vp = node_v + (size_t)n[j] * 96 + uc * 3;
            vv0[j] = *(const float4*)(vp);
            vv1[j] = *(const float4*)(vp + 4);
            vv2[j] = *(const float4*)(vp + 8);
        }
#pragma unroll
        for (int kk = 0; kk < 4; ++kk) {
            int u = uc + kk;
            float w0k = sW10[u * 32 + w];
            float w1k = sW11[u * 32 + w];
            float q0v[8], q1v[8];
#pragma unroll
            for (int p = 0; p < 4; ++p) {
                unsigned q0 = sWsc0p[(u * 4 + p) * 32 + w];
                unsigned q1 = sWsc1p[(u * 4 + p) * 32 + w];
                q0v[2 * p] = bfLO(q0); q0v[2 * p + 1] = bfHI(q0);
                q1v[2 * p] = bfLO(q1); q1v[2 * p + 1] = bfHI(q1);
            }
#pragma unroll
            for (int j = 0; j < 4; ++j) {
                float m0 = 0.f, m1 = 0.f;
#pragma unroll
                for (int v = 0; v < 8; ++v) {
                    m0 = fmaf(a[j][v], q0v[v], m0);
                    m1 = fmaf(a[j][v], q1v[v], m1);
                }
                float s  = (&sv[j].x)[kk];
                float vx = VE(vv0[j], vv1[j], vv2[j], kk * 3 + 0);
                float vy = VE(vv0[j], vv1[j], vv2[j], kk * 3 + 1);
                float vz = VE(vv0[j], vv1[j], vv2[j], kk * 3 + 2);
                x0[j]  = fmaf(s,  w0k, x0[j]);
                x1a[j] = fmaf(vx, w1k, x1a[j]);
                x1b[j] = fmaf(vy, w1k, x1b[j]);
                x1c[j] = fmaf(vz, w1k, x1c[j]);
                sc0[j] = fmaf(s,  m0, sc0[j]);
                s1x[j] = fmaf(vx, m1, s1x[j]);
                s1y[j] = fmaf(vy, m1, s1y[j]);
                s1z[j] = fmaf(vz, m1, s1z[j]);
            }
        }
    }

    const float inv_m   = 0.1767766953f;  // 1/sqrt(32)
    const float sc_norm = 0.0625f;        // 1/sqrt(32*8)
#pragma unroll
    for (int j = 0; j < 4; ++j) {
        if (n0 + j < N_NODES) {
            uint2 pk;
            pk.x = packbf(x0[j] * inv_m, x1a[j] * inv_m);
            pk.y = packbf(x1b[j] * inv_m, x1c[j] * inv_m);
            *(uint2*)(xnode + (size_t)n[j] * 128 + w * 4) = pk;
            float* op = out + (size_t)n[j] * 128;
            op[w]              = sc0[j] * sc_norm;
            op[32 + 3 * w]     = s1x[j] * sc_norm;
            op[32 + 3 * w + 1] = s1y[j] * sc_norm;
            op[32 + 3 * w + 2] = s1z[j] * sc_norm;
        }
    }
}

// ---------------------------------------------------------------------------
// CSR build
// ---------------------------------------------------------------------------
__global__ __launch_bounds__(256) void deg_kernel(const int* __restrict__ edge_src,
                                                  int* __restrict__ deg) {
    int e = blockIdx.x * 256 + threadIdx.x;
    atomicAdd(&deg[edge_src[e]], 1);
}

__global__ __launch_bounds__(1024) void scan_kernel(const int* __restrict__ deg,
                                                    int* __restrict__ offs,
                                                    int* __restrict__ cursor) {
    int tid = threadIdx.x;
    int base = tid * 30;
    int s = 0;
#pragma unroll
    for (int k = 0; k < 30; ++k) {
        int n = base + k;
        if (n < N_NODES) s += deg[n];
    }
    int lane = tid & 63, wid = tid >> 6;
    int inc = s;
#pragma unroll
    for (int d = 1; d < 64; d <<= 1) {
        int o = __shfl_up(inc, d, 64);
        if (lane >= d) inc += o;
    }
    __shared__ int wsum[16];
    if (lane == 63) wsum[wid] = inc;
    __syncthreads();
    if (tid < 16) {
        int v = wsum[tid];
        int t = v;
#pragma unroll
        for (int d = 1; d < 16; d <<= 1) {
            int o = __shfl_up(t, d, 64);
            if (tid >= d) t += o;
        }
        wsum[tid] = t - v;
    }
    __syncthreads();
    int run = inc - s + wsum[wid];
    for (int k = 0; k < 30; ++k) {
        int n = base + k;
        if (n < N_NODES) {
            offs[n] = run;
            cursor[n] = run;
            run += deg[n];
        }
    }
    if (tid == 1023) offs[N_NODES] = run;
}

// ---------------------------------------------------------------------------
// fill: CSR bucketing fused with the per-edge radial MLP (h = ssp(es@Wfc1/√8)).
// Writes h (bf16 x8), edge_attr (bf16 x4), dst — all permuted to CSR order so
// gather's per-edge loads are streaming.
// ---------------------------------------------------------------------------
__global__ __launch_bounds__(256) void fill_kernel(
    const float* __restrict__ edge_attr,     // (E,4)
    const float* __restrict__ edge_scalars,  // (E,8)
    const float* __restrict__ Wfc1,          // (8,8) [k][i]
    const int* __restrict__ edge_src,
    const int* __restrict__ edge_dst,
    int* __restrict__ cursor,
    unsigned short* __restrict__ hPerm,      // (E,8) bf16
    unsigned short* __restrict__ eaPerm,     // (E,4) bf16
    int* __restrict__ dstPerm)               // (E)
{
    __shared__ float sW[64];
    int tid = threadIdx.x;
    if (tid < 64) sW[tid] = Wfc1[tid];
    __syncthreads();

    int e = blockIdx.x * 256 + tid;
    float4 es0 = *(const float4*)(edge_scalars + (size_t)e * 8);
    float4 es1 = *(const float4*)(edge_scalars + (size_t)e * 8 + 4);
    float4 ea  = *(const float4*)(edge_attr + (size_t)e * 4);
    int src = edge_src[e];
    int dst = edge_dst[e];
    int pos = atomicAdd(&cursor[src], 1);

    const float inv8 = 0.3535533906f;
    float h[8];
#pragma unroll
    for (int i = 0; i < 8; ++i) {
        float acc = es0.x * sW[0 * 8 + i];
        acc = fmaf(es0.y, sW[1 * 8 + i], acc);
        acc = fmaf(es0.z, sW[2 * 8 + i], acc);
        acc = fmaf(es0.w, sW[3 * 8 + i], acc);
        acc = fmaf(es1.x, sW[4 * 8 + i], acc);
        acc = fmaf(es1.y, sW[5 * 8 + i], acc);
        acc = fmaf(es1.z, sW[6 * 8 + i], acc);
        acc = fmaf(es1.w, sW[7 * 8 + i], acc);
        acc *= inv8;
        float ax = fabsf(acc);
        float t = __expf(-ax);
        h[i] = fmaxf(acc, 0.f) + __logf(1.f + t) - 0.6931471806f;
    }
    uint4 hp;
    hp.x = packbf(h[0], h[1]); hp.y = packbf(h[2], h[3]);
    hp.z = packbf(h[4], h[5]); hp.w = packbf(h[6], h[7]);
    *(uint4*)(hPerm + (size_t)pos * 8) = hp;
    uint2 eo;
    eo.x = packbf(ea.x, ea.y); eo.y = packbf(ea.z, ea.w);
    *(uint2*)(eaPerm + (size_t)pos * 4) = eo;
    dstPerm[pos] = dst;
}

// ---------------------------------------------------------------------------
// gather: wave per node, half-wave per edge (interleaved for balance).
// All per-edge data streams in CSR order; one uint2 gather for xnode[dst].
// One-iteration dst lookahead pipelines the gather chain.
// ---------------------------------------------------------------------------
__global__ __launch_bounds__(256) void gather_kernel(
    const int* __restrict__ offs,
    const unsigned short* __restrict__ hPerm,
    const unsigned short* __restrict__ eaPerm,
    const int* __restrict__ dstPerm,
    const float* __restrict__ Wfc2,          // (8,128)
    const unsigned short* __restrict__ xnode,
    unsigned short* __restrict__ agg)        // (N,256) bf16
{
    int tid = threadIdx.x;
    int lane = tid & 63;
    int u = lane & 31;
    int half = lane >> 5;
    int node = blockIdx.x * 4 + (tid >> 6);

    const float inv8 = 0.3535533906f;
    const float inv_s3 = 0.5773502692f;
    float wf0[8], wf1[8], wf2[8], wf3[8];
#pragma unroll
    for (int i = 0; i < 8; ++i) {
        wf0[i] = Wfc2[i * 128 + u] * inv8;
        wf1[i] = Wfc2[i * 128 + 32 + u] * inv8;
        wf2[i] = Wfc2[i * 128 + 64 + u] * inv8;
        wf3[i] = Wfc2[i * 128 + 96 + u] * inv8 * inv_s3;
    }

    int beg = offs[node], end = offs[node + 1];
    float a_sa = 0.f, a_sb = 0.f;
    float a_va0 = 0.f, a_va1 = 0.f, a_va2 = 0.f;
    float a_vb0 = 0.f, a_vb1 = 0.f, a_vb2 = 0.f;

    int i = beg + half;
    int dstc = (i < end) ? dstPerm[i] : 0;
    for (; i < end; i += 2) {
        // issue the random gather first (dst was prefetched last iteration)
        uint2 xv = *(const uint2*)(xnode + (size_t)dstc * 128 + u * 4);
        int i2 = i + 2;
        dstc = (i2 < end) ? dstPerm[i2] : 0;   // prefetch next dst
        uint4 hp = *(const uint4*)(hPerm + (size_t)i * 8);
        uint2 eap = *(const uint2*)(eaPerm + (size_t)i * 4);

        float h0 = bfLO(hp.x), h1 = bfHI(hp.x), h2 = bfLO(hp.y), h3 = bfHI(hp.y);
        float h4 = bfLO(hp.z), h5 = bfHI(hp.z), h6 = bfLO(hp.w), h7 = bfHI(hp.w);
        float a00 = h0 * wf0[0], a01 = h0 * wf1[0], a10 = h0 * wf2[0], a11 = h0 * wf3[0];
        a00 = fmaf(h1, wf0[1], a00); a01 = fmaf(h1, wf1[1], a01); a10 = fmaf(h1, wf2[1], a10); a11 = fmaf(h1, wf3[1], a11);
        a00 = fmaf(h2, wf0[2], a00); a01 = fmaf(h2, wf1[2], a01); a10 = fmaf(h2, wf2[2], a10); a11 = fmaf(h2, wf3[2], a11);
        a00 = fmaf(h3, wf0[3], a00); a01 = fmaf(h3, wf1[3], a01); a10 = fmaf(h3, wf2[3], a10); a11 = fmaf(h3, wf3[3], a11);
        a00 = fmaf(h4, wf0[4], a00); a01 = fmaf(h4, wf1[4], a01); a10 = fmaf(h4, wf2[4], a10); a11 = fmaf(h4, wf3[4], a11);
        a00 = fmaf(h5, wf0[5], a00); a01 = fmaf(h5, wf1[5], a01); a10 = fmaf(h5, wf2[5], a10); a11 = fmaf(h5, wf3[5], a11);
        a00 = fmaf(h6, wf0[6], a00); a01 = fmaf(h6, wf1[6], a01); a10 = fmaf(h6, wf2[6], a10); a11 = fmaf(h6, wf3[6], a11);
        a00 = fmaf(h7, wf0[7], a00); a01 = fmaf(h7, wf1[7], a01); a10 = fmaf(h7, wf2[7], a10); a11 = fmaf(h7, wf3[7], a11);

        float sh0 = bfLO(eap.x), s1xe = bfHI(eap.x), s1ye = bfLO(eap.y), s1ze = bfHI(eap.y);
        float x0 = bfLO(xv.x), xd0 = bfHI(xv.x), xd1 = bfLO(xv.y), xd2 = bfHI(xv.y);

        float dot = xd0 * s1xe + xd1 * s1ye + xd2 * s1ze;
        a_sa = fmaf(a00 * sh0, x0, a_sa);
        a_sb = fmaf(a11, dot, a_sb);
        float w01x0 = a01 * x0;
        a_va0 = fmaf(w01x0, s1xe, a_va0);
        a_va1 = fmaf(w01x0, s1ye, a_va1);
        a_va2 = fmaf(w01x0, s1ze, a_va2);
        float t10 = a10 * sh0;
        a_vb0 = fmaf(t10, xd0, a_vb0);
        a_vb1 = fmaf(t10, xd1, a_vb1);
        a_vb2 = fmaf(t10, xd2, a_vb2);
    }
    a_sa  += __shfl_xor(a_sa, 32, 64);
    a_sb  += __shfl_xor(a_sb, 32, 64);
    a_va0 += __shfl_xor(a_va0, 32, 64);
    a_va1 += __shfl_xor(a_va1, 32, 64);
    a_va2 += __shfl_xor(a_va2, 32, 64);
    a_vb0 += __shfl_xor(a_vb0, 32, 64);
    a_vb1 += __shfl_xor(a_vb1, 32, 64);
    a_vb2 += __shfl_xor(a_vb2, 32, 64);

    unsigned short* ap = agg + (size_t)node * 256;
    if (half == 0) {
        ap[u]       = f2bf(a_sa);
        ap[32 + u]  = f2bf(a_sb);
        ap[64 + u]  = f2bf(a_va0);
        ap[96 + u]  = f2bf(a_vb0);
    } else {
        ap[128 + u] = f2bf(a_va1);
        ap[160 + u] = f2bf(a_vb1);
        ap[192 + u] = f2bf(a_va2);
        ap[224 + u] = f2bf(a_vb2);
    }
}

// ---------------------------------------------------------------------------
// out1: out += (agg @ W2) * inv_nb * inv_2m   (RMW on front's self-connection)
// W2 in LDS f32 with +1-pad transposed layout [w][65] (conflict-free).
// agg read as packed bf16 uint4 (broadcast across the 32-lane group).
// ---------------------------------------------------------------------------
__global__ __launch_bounds__(256) void out1_kernel(
    const float* __restrict__ W2_0,       // (64,32) [k][w]
    const float* __restrict__ W2_1,
    const unsigned short* __restrict__ agg,
    float* __restrict__ out)
{
    __shared__ float sW20[32 * 65];
    __shared__ float sW21[32 * 65];
    int tid = threadIdx.x;
    for (int i = tid; i < 2048; i += 256) {
        int k = i >> 5, ww = i & 31;
        sW20[ww * 65 + k] = W2_0[k * 32 + ww];
        sW21[ww * 65 + k] = W2_1[k * 32 + ww];
    }
    __syncthreads();

    int w = tid & 31;
    int nb = blockIdx.x * 16 + (tid >> 5) * 2;
    const float scale2 = 0.03125f;  // 1/sqrt(16) * 1/sqrt(64)
#pragma unroll
    for (int j = 0; j < 2; ++j) {
        int n = nb + j;
        const unsigned* ag = (const unsigned*)(agg + (size_t)n * 256);
        float o0 = 0.f, o1x = 0.f, o1y = 0.f, o1z = 0.f;
        for (int pp = 0; pp < 32; pp += 4) {
            uint4 sA = *(const uint4*)(ag + pp);
            uint4 vX = *(const uint4*)(ag + 32 + pp);
            uint4 vY = *(const uint4*)(ag + 64 + pp);
            uint4 vZ = *(const uint4*)(ag + 96 + pp);
            unsigned su[4] = {sA.x, sA.y, sA.z, sA.w};
            unsigned xu[4] = {vX.x, vX.y, vX.z, vX.w};
            unsigned yu[4] = {vY.x, vY.y, vY.z, vY.w};
            unsigned zu[4] = {vZ.x, vZ.y, vZ.z, vZ.w};
#pragma unroll
            for (int t = 0; t < 4; ++t) {
                int k = 2 * (pp + t);
                float w20a = sW20[w * 65 + k],     w21a = sW21[w * 65 + k];
                float w20b = sW20[w * 65 + k + 1], w21b = sW21[w * 65 + k + 1];
                o0  = fmaf(bfLO(su[t]), w20a, o0);  o0  = fmaf(bfHI(su[t]), w20b, o0);
                o1x = fmaf(bfLO(xu[t]), w21a, o1x); o1x = fmaf(bfHI(xu[t]), w21b, o1x);
                o1y = fmaf(bfLO(yu[t]), w21a, o1y); o1y = fmaf(bfHI(yu[t]), w21b, o1y);
                o1z = fmaf(bfLO(zu[t]), w21a, o1z); o1z = fmaf(bfHI(zu[t]), w21b, o1z);
            }
        }
        float* op = out + (size_t)n * 128;
        op[w]              += o0  * scale2;
        op[32 + 3 * w]     += o1x * scale2;
        op[32 + 3 * w + 1] += o1y * scale2;
        op[32 + 3 * w + 2] += o1z * scale2;
    }
}

extern "C" void kernel_launch(void* const* d_in, const int* in_sizes, int n_in,
                              void* d_out, int out_size, void* d_ws, size_t ws_size,
                              hipStream_t stream) {
    const float* node_s       = (const float*)d_in[0];
    const float* node_v       = (const float*)d_in[1];
    const float* node_attr    = (const float*)d_in[2];
    const float* edge_attr    = (const float*)d_in[3];
    const float* edge_scalars = (const float*)d_in[4];
    const float* W1_0 = (const float*)d_in[5];
    const float* W1_1 = (const float*)d_in[6];
    const float* Wfc1 = (const float*)d_in[7];
    const float* Wfc2 = (const float*)d_in[8];
    const float* W2_0 = (const float*)d_in[9];
    const float* W2_1 = (const float*)d_in[10];
    const float* Wsc0 = (const float*)d_in[11];
    const float* Wsc1 = (const float*)d_in[12];
    const int* edge_src = (const int*)d_in[13];
    const int* edge_dst = (const int*)d_in[14];

    // workspace layout (bytes), total 36,840,016 <= 40.68MB proven in r2/r3
    char* ws = (char*)d_ws;
    unsigned short* xnode  = (unsigned short*)(ws);             // N*128*2 = 7,680,000
    unsigned short* hPerm  = (unsigned short*)(ws + 7680000);   // E*8*2   = 7,680,000
    unsigned short* eaPerm = (unsigned short*)(ws + 15360000);  // E*4*2   = 3,840,000
    int*   dstPerm = (int*)(ws + 19200000);                     // E*4     = 1,920,000
    unsigned short* agg    = (unsigned short*)(ws + 21120000);  // N*256*2 = 15,360,000
    int*   deg    = (int*)(ws + 36480000);                      // N*4
    int*   offs   = (int*)(ws + 36600000);                      // (N+1)*4 pad 120,016
    int*   cursor = (int*)(ws + 36720016);                      // N*4

    hipMemsetAsync(deg, 0, (size_t)N_NODES * sizeof(int), stream);
    front_kernel<<<(N_NODES + 31) / 32, 256, 0, stream>>>(node_s, node_v, node_attr,
                                                          W1_0, W1_1, Wsc0, Wsc1,
                                                          xnode, (float*)d_out);
    deg_kernel<<<N_EDGES / 256, 256, 0, stream>>>(edge_src, deg);
    scan_kernel<<<1, 1024, 0, stream>>>(deg, offs, cursor);
    fill_kernel<<<N_EDGES / 256, 256, 0, stream>>>(edge_attr, edge_scalars, Wfc1,
                                                   edge_src, edge_dst, cursor,
                                                   hPerm, eaPerm, dstPerm);
    gather_kernel<<<N_NODES / 4, 256, 0, stream>>>(offs, hPerm, eaPerm, dstPerm,
                                                   Wfc2, xnode, agg);
    out1_kernel<<<N_NODES / 16, 256, 0, stream>>>(W2_0, W2_1, agg, (float*)d_out);
}

// Round 5
// 297.912 us; speedup vs baseline: 1.9862x; 1.2922x over previous
//
#include <hip/hip_runtime.h>
#include <math.h>

#define N_NODES 30000
#define N_EDGES 480000

__device__ __forceinline__ unsigned short f2bf(float f) {
    unsigned u = __float_as_uint(f);
    u += 0x7fff + ((u >> 16) & 1);          // RNE
    return (unsigned short)(u >> 16);
}
__device__ __forceinline__ float bfLO(unsigned v) { return __uint_as_float(v << 16); }
__device__ __forceinline__ float bfHI(unsigned v) { return __uint_as_float(v & 0xffff0000u); }
__device__ __forceinline__ unsigned packbf(float a, float b) {
    return (unsigned)f2bf(a) | ((unsigned)f2bf(b) << 16);
}

#define VE(A, B, C, idx) ((idx) < 4 ? (&(A).x)[(idx)] : (idx) < 8 ? (&(B).x)[(idx) - 4] : (&(C).x)[(idx) - 8])

// ---------------------------------------------------------------------------
// front: fused (1) degree count for CSR, (2) node precompute x0/x1 -> xnode,
// (3) self-connection -> out. 2 nodes/thread, grid 1875 (= E/256 exactly).
// LDS: W1 pair packed bf16 (1 ds_read_b32/u), Wsc0+Wsc1 packed in uint2
// (4 ds_read_b64/u) -> 5 LDS instrs per u instead of 10.
// ---------------------------------------------------------------------------
__global__ __launch_bounds__(256) void front_kernel(
    const float* __restrict__ node_s,     // (N,32)
    const float* __restrict__ node_v,     // (N,32,3)
    const float* __restrict__ node_attr,  // (N,8)
    const float* __restrict__ W1_0,       // (32,32) [u][w]
    const float* __restrict__ W1_1,
    const float* __restrict__ Wsc0,       // (32,8,32) [u][v][w]
    const float* __restrict__ Wsc1,
    const int* __restrict__ edge_src,
    int* __restrict__ deg,
    unsigned short* __restrict__ xnode,   // (N,128) bf16 packed
    float* __restrict__ out)              // (N,128) f32
{
    __shared__ unsigned sW1p[1024];   // {W1_0, W1_1} bf16 pair at [u*32+w]
    __shared__ uint2 sWscP[4096];     // .x={Wsc0 v-pair}, .y={Wsc1 v-pair} at [(u*4+p)*32+w]
    int tid = threadIdx.x;

    // fused degree count (grid*256 == N_EDGES exactly)
    int e = blockIdx.x * 256 + tid;
    atomicAdd(&deg[edge_src[e]], 1);

    for (int i = tid; i < 1024; i += 256) sW1p[i] = packbf(W1_0[i], W1_1[i]);
    for (int i = tid; i < 4096; i += 256) {
        int u = i >> 7, r = i & 127, p = r >> 5, ww = r & 31;
        int b = (u * 8 + 2 * p) * 32 + ww;
        uint2 q;
        q.x = packbf(Wsc0[b], Wsc0[b + 32]);
        q.y = packbf(Wsc1[b], Wsc1[b + 32]);
        sWscP[i] = q;
    }
    __syncthreads();

    int w = tid & 31;
    int n0 = blockIdx.x * 16 + (tid >> 5) * 2;   // 2 nodes per thread

    float a[2][8];
#pragma unroll
    for (int j = 0; j < 2; ++j) {
        float4 a0 = *(const float4*)(node_attr + (size_t)(n0 + j) * 8);
        float4 a1 = *(const float4*)(node_attr + (size_t)(n0 + j) * 8 + 4);
        a[j][0] = a0.x; a[j][1] = a0.y; a[j][2] = a0.z; a[j][3] = a0.w;
        a[j][4] = a1.x; a[j][5] = a1.y; a[j][6] = a1.z; a[j][7] = a1.w;
    }

    float x0[2]  = {0.f, 0.f}, x1a[2] = {0.f, 0.f}, x1b[2] = {0.f, 0.f}, x1c[2] = {0.f, 0.f};
    float sc0[2] = {0.f, 0.f}, s1x[2] = {0.f, 0.f}, s1y[2] = {0.f, 0.f}, s1z[2] = {0.f, 0.f};

    for (int uc = 0; uc < 32; uc += 4) {
        float4 sv[2], vv0[2], vv1[2], vv2[2];
#pragma unroll
        for (int j = 0; j < 2; ++j) {
            sv[j] = *(const float4*)(node_s + (size_t)(n0 + j) * 32 + uc);
            const float* vp = node_v + (size_t)(n0 + j) * 96 + uc * 3;
            vv0[j] = *(const float4*)(vp);
            vv1[j] = *(const float4*)(vp + 4);
            vv2[j] = *(const float4*)(vp + 8);
        }
#pragma unroll
        for (int kk = 0; kk < 4; ++kk) {
            int u = uc + kk;
            unsigned wp = sW1p[u * 32 + w];
            float w0k = bfLO(wp), w1k = bfHI(wp);
            float q0v[8], q1v[8];
#pragma unroll
            for (int p = 0; p < 4; ++p) {
                uint2 q = sWscP[(u * 4 + p) * 32 + w];
                q0v[2 * p] = bfLO(q.x); q0v[2 * p + 1] = bfHI(q.x);
                q1v[2 * p] = bfLO(q.y); q1v[2 * p + 1] = bfHI(q.y);
            }
#pragma unroll
            for (int j = 0; j < 2; ++j) {
                float m0 = 0.f, m1 = 0.f;
#pragma unroll
                for (int v = 0; v < 8; ++v) {
                    m0 = fmaf(a[j][v], q0v[v], m0);
                    m1 = fmaf(a[j][v], q1v[v], m1);
                }
                float s  = (&sv[j].x)[kk];
                float vx = VE(vv0[j], vv1[j], vv2[j], kk * 3 + 0);
                float vy = VE(vv0[j], vv1[j], vv2[j], kk * 3 + 1);
                float vz = VE(vv0[j], vv1[j], vv2[j], kk * 3 + 2);
                x0[j]  = fmaf(s,  w0k, x0[j]);
                x1a[j] = fmaf(vx, w1k, x1a[j]);
                x1b[j] = fmaf(vy, w1k, x1b[j]);
                x1c[j] = fmaf(vz, w1k, x1c[j]);
                sc0[j] = fmaf(s,  m0, sc0[j]);
                s1x[j] = fmaf(vx, m1, s1x[j]);
                s1y[j] = fmaf(vy, m1, s1y[j]);
                s1z[j] = fmaf(vz, m1, s1z[j]);
            }
        }
    }

    const float inv_m   = 0.1767766953f;  // 1/sqrt(32)
    const float sc_norm = 0.0625f;        // 1/sqrt(32*8)
#pragma unroll
    for (int j = 0; j < 2; ++j) {
        int n = n0 + j;
        uint2 pk;
        pk.x = packbf(x0[j] * inv_m, x1a[j] * inv_m);
        pk.y = packbf(x1b[j] * inv_m, x1c[j] * inv_m);
        *(uint2*)(xnode + (size_t)n * 128 + w * 4) = pk;
        float* op = out + (size_t)n * 128;
        op[w]              = sc0[j] * sc_norm;
        op[32 + 3 * w]     = s1x[j] * sc_norm;
        op[32 + 3 * w + 1] = s1y[j] * sc_norm;
        op[32 + 3 * w + 2] = s1z[j] * sc_norm;
    }
}

// ---------------------------------------------------------------------------
// scan: single-block exclusive prefix over deg, LDS-staged for coalescing.
// ---------------------------------------------------------------------------
__global__ __launch_bounds__(1024) void scan_kernel(const int* __restrict__ deg,
                                                    int* __restrict__ offs,
                                                    int* __restrict__ cursor) {
    __shared__ int sdeg[N_NODES];
    __shared__ int wsum[16];
    int tid = threadIdx.x;
#pragma unroll
    for (int k = 0; k < 30; ++k) {
        int idx = k * 1024 + tid;
        if (idx < N_NODES) sdeg[idx] = deg[idx];
    }
    __syncthreads();

    int base = tid * 30;
    int s = 0;
    if (base < N_NODES) {
#pragma unroll
        for (int k = 0; k < 30; ++k) s += sdeg[base + k];
    }
    int lane = tid & 63, wid = tid >> 6;
    int inc = s;
#pragma unroll
    for (int d = 1; d < 64; d <<= 1) {
        int o = __shfl_up(inc, d, 64);
        if (lane >= d) inc += o;
    }
    if (lane == 63) wsum[wid] = inc;
    __syncthreads();
    if (tid < 16) {
        int v = wsum[tid];
        int t = v;
#pragma unroll
        for (int d = 1; d < 16; d <<= 1) {
            int o = __shfl_up(t, d, 64);
            if (tid >= d) t += o;
        }
        wsum[tid] = t - v;
    }
    __syncthreads();
    int run = inc - s + wsum[wid];
    if (base < N_NODES) {
#pragma unroll
        for (int k = 0; k < 30; ++k) {
            int n = base + k;
            int d = sdeg[n];
            sdeg[n] = run;       // overwrite with exclusive prefix (own slot only)
            run += d;
        }
    }
    __syncthreads();
#pragma unroll
    for (int k = 0; k < 30; ++k) {
        int idx = k * 1024 + tid;
        if (idx < N_NODES) {
            int v = sdeg[idx];
            offs[idx] = v;
            cursor[idx] = v;
        }
    }
    if (tid == 0) offs[N_NODES] = N_EDGES;
}

// ---------------------------------------------------------------------------
// fill: CSR bucketing fused with the per-edge radial MLP (h = ssp(es@Wfc1/√8)).
// ---------------------------------------------------------------------------
__global__ __launch_bounds__(256) void fill_kernel(
    const float* __restrict__ edge_attr,     // (E,4)
    const float* __restrict__ edge_scalars,  // (E,8)
    const float* __restrict__ Wfc1,          // (8,8) [k][i]
    const int* __restrict__ edge_src,
    const int* __restrict__ edge_dst,
    int* __restrict__ cursor,
    unsigned short* __restrict__ hPerm,      // (E,8) bf16
    unsigned short* __restrict__ eaPerm,     // (E,4) bf16
    int* __restrict__ dstPerm)               // (E)
{
    __shared__ float sW[64];
    int tid = threadIdx.x;
    if (tid < 64) sW[tid] = Wfc1[tid];
    __syncthreads();

    int e = blockIdx.x * 256 + tid;
    float4 es0 = *(const float4*)(edge_scalars + (size_t)e * 8);
    float4 es1 = *(const float4*)(edge_scalars + (size_t)e * 8 + 4);
    float4 ea  = *(const float4*)(edge_attr + (size_t)e * 4);
    int src = edge_src[e];
    int dst = edge_dst[e];
    int pos = atomicAdd(&cursor[src], 1);

    const float inv8 = 0.3535533906f;
    float h[8];
#pragma unroll
    for (int i = 0; i < 8; ++i) {
        float acc = es0.x * sW[0 * 8 + i];
        acc = fmaf(es0.y, sW[1 * 8 + i], acc);
        acc = fmaf(es0.z, sW[2 * 8 + i], acc);
        acc = fmaf(es0.w, sW[3 * 8 + i], acc);
        acc = fmaf(es1.x, sW[4 * 8 + i], acc);
        acc = fmaf(es1.y, sW[5 * 8 + i], acc);
        acc = fmaf(es1.z, sW[6 * 8 + i], acc);
        acc = fmaf(es1.w, sW[7 * 8 + i], acc);
        acc *= inv8;
        float ax = fabsf(acc);
        float t = __expf(-ax);
        h[i] = fmaxf(acc, 0.f) + __logf(1.f + t) - 0.6931471806f;
    }
    uint4 hp;
    hp.x = packbf(h[0], h[1]); hp.y = packbf(h[2], h[3]);
    hp.z = packbf(h[4], h[5]); hp.w = packbf(h[6], h[7]);
    *(uint4*)(hPerm + (size_t)pos * 8) = hp;
    uint2 eo;
    eo.x = packbf(ea.x, ea.y); eo.y = packbf(ea.z, ea.w);
    *(uint2*)(eaPerm + (size_t)pos * 4) = eo;
    dstPerm[pos] = dst;
}

// ---------------------------------------------------------------------------
// gather: wave per node, half-wave per edge, depth-2 software pipeline:
// dst prefetched 2 iterations ahead, xnode/h/ea 1 iteration ahead, so the
// random xnode gather has a full compute block (~45 instrs) to hide under.
// ---------------------------------------------------------------------------
__global__ __launch_bounds__(256) void gather_kernel(
    const int* __restrict__ offs,
    const unsigned short* __restrict__ hPerm,
    const unsigned short* __restrict__ eaPerm,
    const int* __restrict__ dstPerm,
    const float* __restrict__ Wfc2,          // (8,128)
    const unsigned short* __restrict__ xnode,
    unsigned short* __restrict__ agg)        // (N,256) bf16
{
    int tid = threadIdx.x;
    int lane = tid & 63;
    int u = lane & 31;
    int half = lane >> 5;
    int node = blockIdx.x * 4 + (tid >> 6);

    const float inv8 = 0.3535533906f;
    const float inv_s3 = 0.5773502692f;
    float wf0[8], wf1[8], wf2[8], wf3[8];
#pragma unroll
    for (int i = 0; i < 8; ++i) {
        wf0[i] = Wfc2[i * 128 + u] * inv8;
        wf1[i] = Wfc2[i * 128 + 32 + u] * inv8;
        wf2[i] = Wfc2[i * 128 + 64 + u] * inv8;
        wf3[i] = Wfc2[i * 128 + 96 + u] * inv8 * inv_s3;
    }

    int beg = offs[node], end = offs[node + 1];
    float a_sa = 0.f, a_sb = 0.f;
    float a_va0 = 0.f, a_va1 = 0.f, a_va2 = 0.f;
    float a_vb0 = 0.f, a_vb1 = 0.f, a_vb2 = 0.f;

    int i = beg + half;
    int dB = 0;
    uint4 hA = {0, 0, 0, 0}, hB = {0, 0, 0, 0};
    uint2 eA = {0, 0}, eB = {0, 0}, xA = {0, 0};
    if (i < end) {
        int dA = dstPerm[i];
        hA = *(const uint4*)(hPerm + (size_t)i * 8);
        eA = *(const uint2*)(eaPerm + (size_t)i * 4);
        xA = *(const uint2*)(xnode + (size_t)dA * 128 + u * 4);
    }
    if (i + 2 < end) {
        dB = dstPerm[i + 2];
        hB = *(const uint4*)(hPerm + (size_t)(i + 2) * 8);
        eB = *(const uint2*)(eaPerm + (size_t)(i + 2) * 4);
    }

    for (; i < end; i += 2) {
        // prefetch next x (dst known 2 iterations early) and stage i+4
        uint2 xB = {0, 0};
        if (i + 2 < end) xB = *(const uint2*)(xnode + (size_t)dB * 128 + u * 4);
        int dC = 0;
        uint4 hC = {0, 0, 0, 0};
        uint2 eC = {0, 0};
        if (i + 4 < end) {
            dC = dstPerm[i + 4];
            hC = *(const uint4*)(hPerm + (size_t)(i + 4) * 8);
            eC = *(const uint2*)(eaPerm + (size_t)(i + 4) * 4);
        }

        float h0 = bfLO(hA.x), h1 = bfHI(hA.x), h2 = bfLO(hA.y), h3 = bfHI(hA.y);
        float h4 = bfLO(hA.z), h5 = bfHI(hA.z), h6 = bfLO(hA.w), h7 = bfHI(hA.w);
        float a00 = h0 * wf0[0], a01 = h0 * wf1[0], a10 = h0 * wf2[0], a11 = h0 * wf3[0];
        a00 = fmaf(h1, wf0[1], a00); a01 = fmaf(h1, wf1[1], a01); a10 = fmaf(h1, wf2[1], a10); a11 = fmaf(h1, wf3[1], a11);
        a00 = fmaf(h2, wf0[2], a00); a01 = fmaf(h2, wf1[2], a01); a10 = fmaf(h2, wf2[2], a10); a11 = fmaf(h2, wf3[2], a11);
        a00 = fmaf(h3, wf0[3], a00); a01 = fmaf(h3, wf1[3], a01); a10 = fmaf(h3, wf2[3], a10); a11 = fmaf(h3, wf3[3], a11);
        a00 = fmaf(h4, wf0[4], a00); a01 = fmaf(h4, wf1[4], a01); a10 = fmaf(h4, wf2[4], a10); a11 = fmaf(h4, wf3[4], a11);
        a00 = fmaf(h5, wf0[5], a00); a01 = fmaf(h5, wf1[5], a01); a10 = fmaf(h5, wf2[5], a10); a11 = fmaf(h5, wf3[5], a11);
        a00 = fmaf(h6, wf0[6], a00); a01 = fmaf(h6, wf1[6], a01); a10 = fmaf(h6, wf2[6], a10); a11 = fmaf(h6, wf3[6], a11);
        a00 = fmaf(h7, wf0[7], a00); a01 = fmaf(h7, wf1[7], a01); a10 = fmaf(h7, wf2[7], a10); a11 = fmaf(h7, wf3[7], a11);

        float sh0 = bfLO(eA.x), s1xe = bfHI(eA.x), s1ye = bfLO(eA.y), s1ze = bfHI(eA.y);
        float x0 = bfLO(xA.x), xd0 = bfHI(xA.x), xd1 = bfLO(xA.y), xd2 = bfHI(xA.y);

        float dot = xd0 * s1xe + xd1 * s1ye + xd2 * s1ze;
        a_sa = fmaf(a00 * sh0, x0, a_sa);
        a_sb = fmaf(a11, dot, a_sb);
        float w01x0 = a01 * x0;
        a_va0 = fmaf(w01x0, s1xe, a_va0);
        a_va1 = fmaf(w01x0, s1ye, a_va1);
        a_va2 = fmaf(w01x0, s1ze, a_va2);
        float t10 = a10 * sh0;
        a_vb0 = fmaf(t10, xd0, a_vb0);
        a_vb1 = fmaf(t10, xd1, a_vb1);
        a_vb2 = fmaf(t10, xd2, a_vb2);

        hA = hB; eA = eB; xA = xB;
        hB = hC; eB = eC; dB = dC;
    }
    a_sa  += __shfl_xor(a_sa, 32, 64);
    a_sb  += __shfl_xor(a_sb, 32, 64);
    a_va0 += __shfl_xor(a_va0, 32, 64);
    a_va1 += __shfl_xor(a_va1, 32, 64);
    a_va2 += __shfl_xor(a_va2, 32, 64);
    a_vb0 += __shfl_xor(a_vb0, 32, 64);
    a_vb1 += __shfl_xor(a_vb1, 32, 64);
    a_vb2 += __shfl_xor(a_vb2, 32, 64);

    unsigned short* ap = agg + (size_t)node * 256;
    if (half == 0) {
        ap[u]       = f2bf(a_sa);
        ap[32 + u]  = f2bf(a_sb);
        ap[64 + u]  = f2bf(a_va0);
        ap[96 + u]  = f2bf(a_vb0);
    } else {
        ap[128 + u] = f2bf(a_va1);
        ap[160 + u] = f2bf(a_vb1);
        ap[192 + u] = f2bf(a_va2);
        ap[224 + u] = f2bf(a_vb2);
    }
}

// ---------------------------------------------------------------------------
// out1: out += (agg @ W2) * inv_nb * inv_2m   (RMW on front's self-connection)
// ---------------------------------------------------------------------------
__global__ __launch_bounds__(256) void out1_kernel(
    const float* __restrict__ W2_0,       // (64,32) [k][w]
    const float* __restrict__ W2_1,
    const unsigned short* __restrict__ agg,
    float* __restrict__ out)
{
    __shared__ float sW20[32 * 65];
    __shared__ float sW21[32 * 65];
    int tid = threadIdx.x;
    for (int i = tid; i < 2048; i += 256) {
        int k = i >> 5, ww = i & 31;
        sW20[ww * 65 + k] = W2_0[k * 32 + ww];
        sW21[ww * 65 + k] = W2_1[k * 32 + ww];
    }
    __syncthreads();

    int w = tid & 31;
    int nb = blockIdx.x * 16 + (tid >> 5) * 2;
    const float scale2 = 0.03125f;  // 1/sqrt(16) * 1/sqrt(64)
#pragma unroll
    for (int j = 0; j < 2; ++j) {
        int n = nb + j;
        const unsigned* ag = (const unsigned*)(agg + (size_t)n * 256);
        float o0 = 0.f, o1x = 0.f, o1y = 0.f, o1z = 0.f;
        for (int pp = 0; pp < 32; pp += 4) {
            uint4 sA = *(const uint4*)(ag + pp);
            uint4 vX = *(const uint4*)(ag + 32 + pp);
            uint4 vY = *(const uint4*)(ag + 64 + pp);
            uint4 vZ = *(const uint4*)(ag + 96 + pp);
            unsigned su[4] = {sA.x, sA.y, sA.z, sA.w};
            unsigned xu[4] = {vX.x, vX.y, vX.z, vX.w};
            unsigned yu[4] = {vY.x, vY.y, vY.z, vY.w};
            unsigned zu[4] = {vZ.x, vZ.y, vZ.z, vZ.w};
#pragma unroll
            for (int t = 0; t < 4; ++t) {
                int k = 2 * (pp + t);
                float w20a = sW20[w * 65 + k],     w21a = sW21[w * 65 + k];
                float w20b = sW20[w * 65 + k + 1], w21b = sW21[w * 65 + k + 1];
                o0  = fmaf(bfLO(su[t]), w20a, o0);  o0  = fmaf(bfHI(su[t]), w20b, o0);
                o1x = fmaf(bfLO(xu[t]), w21a, o1x); o1x = fmaf(bfHI(xu[t]), w21b, o1x);
                o1y = fmaf(bfLO(yu[t]), w21a, o1y); o1y = fmaf(bfHI(yu[t]), w21b, o1y);
                o1z = fmaf(bfLO(zu[t]), w21a, o1z); o1z = fmaf(bfHI(zu[t]), w21b, o1z);
            }
        }
        float* op = out + (size_t)n * 128;
        op[w]              += o0  * scale2;
        op[32 + 3 * w]     += o1x * scale2;
        op[32 + 3 * w + 1] += o1y * scale2;
        op[32 + 3 * w + 2] += o1z * scale2;
    }
}

extern "C" void kernel_launch(void* const* d_in, const int* in_sizes, int n_in,
                              void* d_out, int out_size, void* d_ws, size_t ws_size,
                              hipStream_t stream) {
    const float* node_s       = (const float*)d_in[0];
    const float* node_v       = (const float*)d_in[1];
    const float* node_attr    = (const float*)d_in[2];
    const float* edge_attr    = (const float*)d_in[3];
    const float* edge_scalars = (const float*)d_in[4];
    const float* W1_0 = (const float*)d_in[5];
    const float* W1_1 = (const float*)d_in[6];
    const float* Wfc1 = (const float*)d_in[7];
    const float* Wfc2 = (const float*)d_in[8];
    const float* W2_0 = (const float*)d_in[9];
    const float* W2_1 = (const float*)d_in[10];
    const float* Wsc0 = (const float*)d_in[11];
    const float* Wsc1 = (const float*)d_in[12];
    const int* edge_src = (const int*)d_in[13];
    const int* edge_dst = (const int*)d_in[14];

    // workspace layout (bytes), total 36,840,016 <= proven capacity
    char* ws = (char*)d_ws;
    unsigned short* xnode  = (unsigned short*)(ws);             // N*128*2 = 7,680,000
    unsigned short* hPerm  = (unsigned short*)(ws + 7680000);   // E*8*2   = 7,680,000
    unsigned short* eaPerm = (unsigned short*)(ws + 15360000);  // E*4*2   = 3,840,000
    int*   dstPerm = (int*)(ws + 19200000);                     // E*4     = 1,920,000
    unsigned short* agg    = (unsigned short*)(ws + 21120000);  // N*256*2 = 15,360,000
    int*   deg    = (int*)(ws + 36480000);                      // N*4
    int*   offs   = (int*)(ws + 36600000);                      // (N+1)*4 pad 120,016
    int*   cursor = (int*)(ws + 36720016);                      // N*4

    hipMemsetAsync(deg, 0, (size_t)N_NODES * sizeof(int), stream);
    front_kernel<<<1875, 256, 0, stream>>>(node_s, node_v, node_attr,
                                           W1_0, W1_1, Wsc0, Wsc1,
                                           edge_src, deg, xnode, (float*)d_out);
    scan_kernel<<<1, 1024, 0, stream>>>(deg, offs, cursor);
    fill_kernel<<<1875, 256, 0, stream>>>(edge_attr, edge_scalars, Wfc1,
                                          edge_src, edge_dst, cursor,
                                          hPerm, eaPerm, dstPerm);
    gather_kernel<<<7500, 256, 0, stream>>>(offs, hPerm, eaPerm, dstPerm,
                                            Wfc2, xnode, agg);
    out1_kernel<<<1875, 256, 0, stream>>>(W2_0, W2_1, agg, (float*)d_out);
}

// Round 6
// 271.870 us; speedup vs baseline: 2.1765x; 1.0958x over previous
//
#include <hip/hip_runtime.h>
#include <math.h>

#define N_NODES 30000
#define N_EDGES 480000

typedef __attribute__((ext_vector_type(8))) short short8;
typedef __attribute__((ext_vector_type(4))) float f32x4;

__device__ __forceinline__ unsigned short f2bf(float f) {
    unsigned u = __float_as_uint(f);
    u += 0x7fff + ((u >> 16) & 1);          // RNE
    return (unsigned short)(u >> 16);
}
__device__ __forceinline__ float bfLO(unsigned v) { return __uint_as_float(v << 16); }
__device__ __forceinline__ float bfHI(unsigned v) { return __uint_as_float(v & 0xffff0000u); }
__device__ __forceinline__ unsigned packbf(float a, float b) {
    return (unsigned)f2bf(a) | ((unsigned)f2bf(b) << 16);
}
// truncation pack (products of bf16-exact values: err <= 2^-8, no carry chain)
__device__ __forceinline__ unsigned ptk(float a, float b) {
    return (__float_as_uint(a) >> 16) | (__float_as_uint(b) & 0xffff0000u);
}

union U8 { short8 v; unsigned u[4]; };
union C4 { f32x4 v; float f[4]; };

// ---------------------------------------------------------------------------
// k_pre: scalar x-precompute (x0 = s@W1_0, x1 = v@W1_1, * 1/sqrt(32)) -> xnode
// bf16-packed uint2 per (n,u): {x0,x1x},{x1y,x1z}. Fused CSR degree count.
// 8 nodes/block of 256, grid 3750 (= E/128 for the deg fusion).
// ---------------------------------------------------------------------------
__global__ __launch_bounds__(256) void k_pre(
    const float* __restrict__ node_s,   // (N,32)
    const float* __restrict__ node_v,   // (N,32,3)
    const float* __restrict__ W1_0,     // (32,32) [u][w]
    const float* __restrict__ W1_1,
    const int* __restrict__ edge_src,
    int* __restrict__ deg,
    unsigned short* __restrict__ xnode) // (N,128) bf16 packed
{
    __shared__ float sW0[1024];
    __shared__ float sW1[1024];
    int tid = threadIdx.x;
    if (tid < 128) atomicAdd(&deg[edge_src[blockIdx.x * 128 + tid]], 1);
    for (int i = tid; i < 1024; i += 256) { sW0[i] = W1_0[i]; sW1[i] = W1_1[i]; }
    __syncthreads();
    int node = blockIdx.x * 8 + (tid >> 5);
    int w = tid & 31;
    const float inv_m = 0.1767766953f;  // 1/sqrt(32)
    float x0 = 0.f, x1a = 0.f, x1b = 0.f, x1c = 0.f;
    const float* sp = node_s + (size_t)node * 32;
    const float* vp = node_v + (size_t)node * 96;
#pragma unroll
    for (int u = 0; u < 32; ++u) {
        float su = sp[u];
        float w0 = sW0[u * 32 + w];
        float w1 = sW1[u * 32 + w];
        x0 = fmaf(su, w0, x0);
        x1a = fmaf(vp[u * 3 + 0], w1, x1a);
        x1b = fmaf(vp[u * 3 + 1], w1, x1b);
        x1c = fmaf(vp[u * 3 + 2], w1, x1c);
    }
    uint2 pk;
    pk.x = packbf(x0 * inv_m, x1a * inv_m);
    pk.y = packbf(x1b * inv_m, x1c * inv_m);
    *(uint2*)(xnode + (size_t)node * 128 + w * 4) = pk;
}

// ---------------------------------------------------------------------------
// k_sc: self-connection as MFMA GEMM.  sc0 = P_s @ Wsc0f, sc1 = P_v @ Wsc1f,
// P_s[n][u*8+v] = s[n][u]*a[n][v], P_v[(n,d)][u*8+v] = v[n][u][d]*a[n][v].
// Row-tiles of 16: tiles 0..1874 = s-rows, 1875..7499 = v-rows (exact fits).
// One tile per wave; Wsc*0.0625 held as register B-fragments (scale folded,
// 2^-4 exact). Writes out (f32) fully: [0:32]=sc0, [32+3w+d]=sc1.
// mfma_f32_16x16x32_bf16 layouts (HW-verified per guide):
//   A[m=lane&15][k=(lane>>4)*8+j], B[k=(lane>>4)*8+j][n=lane&15],
//   D col=lane&15, row=(lane>>4)*4+reg.
// ---------------------------------------------------------------------------
__global__ __launch_bounds__(256) void k_sc(
    const float* __restrict__ node_s,     // (N,32)
    const float* __restrict__ node_v,     // (N,32,3)
    const float* __restrict__ node_attr,  // (N,8)
    const float* __restrict__ Wsc0,       // (32,8,32) [u][v][w] = [uv][w]
    const float* __restrict__ Wsc1,
    float* __restrict__ out)              // (N,128)
{
    __shared__ float stg[4][688];
    int tid = threadIdx.x;
    int lane = tid & 63;
    int wv = tid >> 6;
    int t = blockIdx.x * 4 + wv;
    int col = lane & 15;
    int quad = lane >> 4;
    int m = lane & 15;
    bool is_s = (t < 1875);
    const float* Wm = is_s ? Wsc0 : Wsc1;
    const float sc_norm = 0.0625f;  // folded into B (exact pow2)

    // ---- B fragments: 8 k-chunks x 2 col-tiles, registers ----
    short8 b0[8], b1[8];
#pragma unroll
    for (int kc = 0; kc < 8; ++kc) {
        U8 f0, f1;
#pragma unroll
        for (int p = 0; p < 4; ++p) {
            int k0 = kc * 32 + quad * 8 + 2 * p;
            const float* wp = Wm + (size_t)k0 * 32;
            f0.u[p] = packbf(wp[col] * sc_norm,      wp[32 + col] * sc_norm);
            f1.u[p] = packbf(wp[col + 16] * sc_norm, wp[32 + col + 16] * sc_norm);
        }
        b0[kc] = f0.v;
        b1[kc] = f1.v;
    }

    // ---- stage this tile's factor data into wave-private LDS ----
    float* S = stg[wv];
    int fbase, fstep;
    int n_a;          // node of this lane's A-row (for a[] load)
    int nlo = 0;
    if (is_s) {
        for (int q = lane; q < 512; q += 64)
            S[(q >> 5) * 33 + (q & 31)] = node_s[(size_t)t * 512 + q];
        n_a = t * 16 + m;
        fbase = m * 33;
        fstep = 1;
    } else {
        int vt = t - 1875;
        int R0 = vt * 16;
        nlo = R0 / 3;
        int nhi = (R0 + 15) / 3;
        int cnt = (nhi - nlo + 1) * 96;
        const float* src = node_v + (size_t)nlo * 96;
        for (int q = lane; q < cnt; q += 64)
            S[(q / 96) * 97 + (q % 96)] = src[q];
        int R = R0 + m;
        n_a = R / 3;
        int d_a = R - n_a * 3;
        fbase = (n_a - nlo) * 97 + d_a;
        fstep = 3;
    }
    float4 A0 = *(const float4*)(node_attr + (size_t)n_a * 8);
    float4 A1 = *(const float4*)(node_attr + (size_t)n_a * 8 + 4);
    float aa0 = A0.x, aa1 = A0.y, aa2 = A0.z, aa3 = A0.w;
    float aa4 = A1.x, aa5 = A1.y, aa6 = A1.z, aa7 = A1.w;

    // ---- K loop: 8 chunks of 32 ----
    f32x4 acc0 = {0.f, 0.f, 0.f, 0.f};
    f32x4 acc1 = {0.f, 0.f, 0.f, 0.f};
#pragma unroll
    for (int kc = 0; kc < 8; ++kc) {
        int u = kc * 4 + quad;
        float f = S[fbase + u * fstep];
        U8 af;
        af.u[0] = ptk(f * aa0, f * aa1);
        af.u[1] = ptk(f * aa2, f * aa3);
        af.u[2] = ptk(f * aa4, f * aa5);
        af.u[3] = ptk(f * aa6, f * aa7);
        acc0 = __builtin_amdgcn_mfma_f32_16x16x32_bf16(af.v, b0[kc], acc0, 0, 0, 0);
        acc1 = __builtin_amdgcn_mfma_f32_16x16x32_bf16(af.v, b1[kc], acc1, 0, 0, 0);
    }

    // ---- epilogue ----
    C4 c0, c1;
    c0.v = acc0; c1.v = acc1;
    if (is_s) {
#pragma unroll
        for (int r = 0; r < 4; ++r) {
            int n = t * 16 + (quad << 2) + r;
            out[(size_t)n * 128 + col]      = c0.f[r];
            out[(size_t)n * 128 + col + 16] = c1.f[r];
        }
    } else {
        int R0 = (t - 1875) * 16;
#pragma unroll
        for (int r = 0; r < 4; ++r) {
            int R = R0 + (quad << 2) + r;
            int nn = R / 3;
            int dd = R - nn * 3;
            out[(size_t)nn * 128 + 32 + 3 * col + dd]        = c0.f[r];
            out[(size_t)nn * 128 + 32 + 3 * (col + 16) + dd] = c1.f[r];
        }
    }
}

// ---------------------------------------------------------------------------
// scan: single-block exclusive prefix over deg, LDS-staged.
// ---------------------------------------------------------------------------
__global__ __launch_bounds__(1024) void scan_kernel(const int* __restrict__ deg,
                                                    int* __restrict__ offs,
                                                    int* __restrict__ cursor) {
    __shared__ int sdeg[N_NODES];
    __shared__ int wsum[16];
    int tid = threadIdx.x;
#pragma unroll
    for (int k = 0; k < 30; ++k) {
        int idx = k * 1024 + tid;
        if (idx < N_NODES) sdeg[idx] = deg[idx];
    }
    __syncthreads();
    int base = tid * 30;
    int s = 0;
    if (base < N_NODES) {
#pragma unroll
        for (int k = 0; k < 30; ++k) s += sdeg[base + k];
    }
    int lane = tid & 63, wid = tid >> 6;
    int inc = s;
#pragma unroll
    for (int d = 1; d < 64; d <<= 1) {
        int o = __shfl_up(inc, d, 64);
        if (lane >= d) inc += o;
    }
    if (lane == 63) wsum[wid] = inc;
    __syncthreads();
    if (tid < 16) {
        int v = wsum[tid];
        int t = v;
#pragma unroll
        for (int d = 1; d < 16; d <<= 1) {
            int o = __shfl_up(t, d, 64);
            if (tid >= d) t += o;
        }
        wsum[tid] = t - v;
    }
    __syncthreads();
    int run = inc - s + wsum[wid];
    if (base < N_NODES) {
#pragma unroll
        for (int k = 0; k < 30; ++k) {
            int n = base + k;
            int d = sdeg[n];
            sdeg[n] = run;
            run += d;
        }
    }
    __syncthreads();
#pragma unroll
    for (int k = 0; k < 30; ++k) {
        int idx = k * 1024 + tid;
        if (idx < N_NODES) {
            int v = sdeg[idx];
            offs[idx] = v;
            cursor[idx] = v;
        }
    }
    if (tid == 0) offs[N_NODES] = N_EDGES;
}

// ---------------------------------------------------------------------------
// fill: per-edge radial MLP h = ssp(es@Wfc1/sqrt(8)); h and edge_attr written
// COALESCED at e; single scattered 8B write {dst, eid} at CSR position.
// ---------------------------------------------------------------------------
__global__ __launch_bounds__(256) void fill_kernel(
    const float* __restrict__ edge_attr,     // (E,4)
    const float* __restrict__ edge_scalars,  // (E,8)
    const float* __restrict__ Wfc1,          // (8,8) [k][i]
    const int* __restrict__ edge_src,
    const int* __restrict__ edge_dst,
    int* __restrict__ cursor,
    unsigned short* __restrict__ hE,         // (E,8) bf16, at e
    unsigned short* __restrict__ eaE,        // (E,4) bf16, at e
    int2* __restrict__ edPerm)               // (E) {dst, eid} at pos
{
    __shared__ float sW[64];
    int tid = threadIdx.x;
    if (tid < 64) sW[tid] = Wfc1[tid];
    __syncthreads();

    int e = blockIdx.x * 256 + tid;
    float4 es0 = *(const float4*)(edge_scalars + (size_t)e * 8);
    float4 es1 = *(const float4*)(edge_scalars + (size_t)e * 8 + 4);
    float4 ea  = *(const float4*)(edge_attr + (size_t)e * 4);
    int src = edge_src[e];
    int dst = edge_dst[e];
    int pos = atomicAdd(&cursor[src], 1);

    const float inv8 = 0.3535533906f;
    float h[8];
#pragma unroll
    for (int i = 0; i < 8; ++i) {
        float acc = es0.x * sW[0 * 8 + i];
        acc = fmaf(es0.y, sW[1 * 8 + i], acc);
        acc = fmaf(es0.z, sW[2 * 8 + i], acc);
        acc = fmaf(es0.w, sW[3 * 8 + i], acc);
        acc = fmaf(es1.x, sW[4 * 8 + i], acc);
        acc = fmaf(es1.y, sW[5 * 8 + i], acc);
        acc = fmaf(es1.z, sW[6 * 8 + i], acc);
        acc = fmaf(es1.w, sW[7 * 8 + i], acc);
        acc *= inv8;
        float ax = fabsf(acc);
        float tt = __expf(-ax);
        h[i] = fmaxf(acc, 0.f) + __logf(1.f + tt) - 0.6931471806f;
    }
    uint4 hp;
    hp.x = packbf(h[0], h[1]); hp.y = packbf(h[2], h[3]);
    hp.z = packbf(h[4], h[5]); hp.w = packbf(h[6], h[7]);
    *(uint4*)(hE + (size_t)e * 8) = hp;            // coalesced
    uint2 eo;
    eo.x = packbf(ea.x, ea.y); eo.y = packbf(ea.z, ea.w);
    *(uint2*)(eaE + (size_t)e * 4) = eo;           // coalesced
    int2 ed; ed.x = dst; ed.y = e;
    edPerm[pos] = ed;                              // single scattered 8B
}

// ---------------------------------------------------------------------------
// gather: wave per node, half-wave per edge; {dst,eid} streams in CSR order,
// h/ea/x are independent random loads issued one iteration ahead.
// ---------------------------------------------------------------------------
__global__ __launch_bounds__(256) void gather_kernel(
    const int* __restrict__ offs,
    const int2* __restrict__ edPerm,
    const unsigned short* __restrict__ hE,
    const unsigned short* __restrict__ eaE,
    const float* __restrict__ Wfc2,          // (8,128)
    const unsigned short* __restrict__ xnode,
    unsigned short* __restrict__ agg)        // (N,256) bf16
{
    int tid = threadIdx.x;
    int lane = tid & 63;
    int u = lane & 31;
    int half = lane >> 5;
    int node = blockIdx.x * 4 + (tid >> 6);

    const float inv8 = 0.3535533906f;
    const float inv_s3 = 0.5773502692f;
    float wf0[8], wf1[8], wf2[8], wf3[8];
#pragma unroll
    for (int i = 0; i < 8; ++i) {
        wf0[i] = Wfc2[i * 128 + u] * inv8;
        wf1[i] = Wfc2[i * 128 + 32 + u] * inv8;
        wf2[i] = Wfc2[i * 128 + 64 + u] * inv8;
        wf3[i] = Wfc2[i * 128 + 96 + u] * inv8 * inv_s3;
    }

    int beg = offs[node], end = offs[node + 1];
    float a_sa = 0.f, a_sb = 0.f;
    float a_va0 = 0.f, a_va1 = 0.f, a_va2 = 0.f;
    float a_vb0 = 0.f, a_vb1 = 0.f, a_vb2 = 0.f;

    int i = beg + half;
    int2 edB = {0, 0};
    uint4 hA = {0, 0, 0, 0};
    uint2 eA = {0, 0}, xA = {0, 0};
    if (i < end) {
        int2 edA = edPerm[i];
        xA = *(const uint2*)(xnode + (size_t)edA.x * 128 + u * 4);
        hA = *(const uint4*)(hE + (size_t)edA.y * 8);
        eA = *(const uint2*)(eaE + (size_t)edA.y * 4);
    }
    if (i + 2 < end) edB = edPerm[i + 2];

    for (; i < end; i += 2) {
        uint4 hB = {0, 0, 0, 0};
        uint2 eB = {0, 0}, xB = {0, 0};
        if (i + 2 < end) {
            xB = *(const uint2*)(xnode + (size_t)edB.x * 128 + u * 4);
            hB = *(const uint4*)(hE + (size_t)edB.y * 8);
            eB = *(const uint2*)(eaE + (size_t)edB.y * 4);
        }
        int2 edC = {0, 0};
        if (i + 4 < end) edC = edPerm[i + 4];

        float h0 = bfLO(hA.x), h1 = bfHI(hA.x), h2 = bfLO(hA.y), h3 = bfHI(hA.y);
        float h4 = bfLO(hA.z), h5 = bfHI(hA.z), h6 = bfLO(hA.w), h7 = bfHI(hA.w);
        float a00 = h0 * wf0[0], a01 = h0 * wf1[0], a10 = h0 * wf2[0], a11 = h0 * wf3[0];
        a00 = fmaf(h1, wf0[1], a00); a01 = fmaf(h1, wf1[1], a01); a10 = fmaf(h1, wf2[1], a10); a11 = fmaf(h1, wf3[1], a11);
        a00 = fmaf(h2, wf0[2], a00); a01 = fmaf(h2, wf1[2], a01); a10 = fmaf(h2, wf2[2], a10); a11 = fmaf(h2, wf3[2], a11);
        a00 = fmaf(h3, wf0[3], a00); a01 = fmaf(h3, wf1[3], a01); a10 = fmaf(h3, wf2[3], a10); a11 = fmaf(h3, wf3[3], a11);
        a00 = fmaf(h4, wf0[4], a00); a01 = fmaf(h4, wf1[4], a01); a10 = fmaf(h4, wf2[4], a10); a11 = fmaf(h4, wf3[4], a11);
        a00 = fmaf(h5, wf0[5], a00); a01 = fmaf(h5, wf1[5], a01); a10 = fmaf(h5, wf2[5], a10); a11 = fmaf(h5, wf3[5], a11);
        a00 = fmaf(h6, wf0[6], a00); a01 = fmaf(h6, wf1[6], a01); a10 = fmaf(h6, wf2[6], a10); a11 = fmaf(h6, wf3[6], a11);
        a00 = fmaf(h7, wf0[7], a00); a01 = fmaf(h7, wf1[7], a01); a10 = fmaf(h7, wf2[7], a10); a11 = fmaf(h7, wf3[7], a11);

        float sh0 = bfLO(eA.x), s1xe = bfHI(eA.x), s1ye = bfLO(eA.y), s1ze = bfHI(eA.y);
        float x0 = bfLO(xA.x), xd0 = bfHI(xA.x), xd1 = bfLO(xA.y), xd2 = bfHI(xA.y);

        float dot = xd0 * s1xe + xd1 * s1ye + xd2 * s1ze;
        a_sa = fmaf(a00 * sh0, x0, a_sa);
        a_sb = fmaf(a11, dot, a_sb);
        float w01x0 = a01 * x0;
        a_va0 = fmaf(w01x0, s1xe, a_va0);
        a_va1 = fmaf(w01x0, s1ye, a_va1);
        a_va2 = fmaf(w01x0, s1ze, a_va2);
        float t10 = a10 * sh0;
        a_vb0 = fmaf(t10, xd0, a_vb0);
        a_vb1 = fmaf(t10, xd1, a_vb1);
        a_vb2 = fmaf(t10, xd2, a_vb2);

        hA = hB; eA = eB; xA = xB; edB = edC;
    }
    a_sa  += __shfl_xor(a_sa, 32, 64);
    a_sb  += __shfl_xor(a_sb, 32, 64);
    a_va0 += __shfl_xor(a_va0, 32, 64);
    a_va1 += __shfl_xor(a_va1, 32, 64);
    a_va2 += __shfl_xor(a_va2, 32, 64);
    a_vb0 += __shfl_xor(a_vb0, 32, 64);
    a_vb1 += __shfl_xor(a_vb1, 32, 64);
    a_vb2 += __shfl_xor(a_vb2, 32, 64);

    unsigned short* ap = agg + (size_t)node * 256;
    if (half == 0) {
        ap[u]       = f2bf(a_sa);
        ap[32 + u]  = f2bf(a_sb);
        ap[64 + u]  = f2bf(a_va0);
        ap[96 + u]  = f2bf(a_vb0);
    } else {
        ap[128 + u] = f2bf(a_va1);
        ap[160 + u] = f2bf(a_vb1);
        ap[192 + u] = f2bf(a_va2);
        ap[224 + u] = f2bf(a_vb2);
    }
}

// ---------------------------------------------------------------------------
// out1: out += (agg @ W2) * inv_nb*inv_2m. 4 nodes/thread -> each LDS weight
// read amortizes over 4 fmas (LDS reads/node: 128 -> 32).
// ---------------------------------------------------------------------------
__global__ __launch_bounds__(256) void out1_kernel(
    const float* __restrict__ W2_0,       // (64,32) [k][w]
    const float* __restrict__ W2_1,
    const unsigned short* __restrict__ agg,
    float* __restrict__ out)
{
    __shared__ float sW20[32 * 65];
    __shared__ float sW21[32 * 65];
    int tid = threadIdx.x;
    for (int i = tid; i < 2048; i += 256) {
        int k = i >> 5, ww = i & 31;
        sW20[ww * 65 + k] = W2_0[k * 32 + ww];
        sW21[ww * 65 + k] = W2_1[k * 32 + ww];
    }
    __syncthreads();

    int w = tid & 31;
    int nb = blockIdx.x * 32 + (tid >> 5) * 4;
    const float scale2 = 0.03125f;  // 1/sqrt(16) * 1/sqrt(64)
    float o0[4] = {0.f, 0.f, 0.f, 0.f}, o1x[4] = {0.f, 0.f, 0.f, 0.f};
    float o1y[4] = {0.f, 0.f, 0.f, 0.f}, o1z[4] = {0.f, 0.f, 0.f, 0.f};
    const unsigned* ag[4];
#pragma unroll
    for (int j = 0; j < 4; ++j)
        ag[j] = (const unsigned*)(agg + (size_t)min(nb + j, N_NODES - 1) * 256);

    for (int pp = 0; pp < 32; pp += 4) {
        uint4 sA[4], vX[4], vY[4], vZ[4];
#pragma unroll
        for (int j = 0; j < 4; ++j) {
            sA[j] = *(const uint4*)(ag[j] + pp);
            vX[j] = *(const uint4*)(ag[j] + 32 + pp);
            vY[j] = *(const uint4*)(ag[j] + 64 + pp);
            vZ[j] = *(const uint4*)(ag[j] + 96 + pp);
        }
#pragma unroll
        for (int t = 0; t < 4; ++t) {
            int k = 2 * (pp + t);
            float w20a = sW20[w * 65 + k],     w21a = sW21[w * 65 + k];
            float w20b = sW20[w * 65 + k + 1], w21b = sW21[w * 65 + k + 1];
#pragma unroll
            for (int j = 0; j < 4; ++j) {
                unsigned su = (&sA[j].x)[t], xu = (&vX[j].x)[t];
                unsigned yu = (&vY[j].x)[t], zu = (&vZ[j].x)[t];
                o0[j]  = fmaf(bfLO(su), w20a, o0[j]);  o0[j]  = fmaf(bfHI(su), w20b, o0[j]);
                o1x[j] = fmaf(bfLO(xu), w21a, o1x[j]); o1x[j] = fmaf(bfHI(xu), w21b, o1x[j]);
                o1y[j] = fmaf(bfLO(yu), w21a, o1y[j]); o1y[j] = fmaf(bfHI(yu), w21b, o1y[j]);
                o1z[j] = fmaf(bfLO(zu), w21a, o1z[j]); o1z[j] = fmaf(bfHI(zu), w21b, o1z[j]);
            }
        }
    }
#pragma unroll
    for (int j = 0; j < 4; ++j) {
        int n = nb + j;
        if (n < N_NODES) {
            float* op = out + (size_t)n * 128;
            op[w]              += o0[j]  * scale2;
            op[32 + 3 * w]     += o1x[j] * scale2;
            op[32 + 3 * w + 1] += o1y[j] * scale2;
            op[32 + 3 * w + 2] += o1z[j] * scale2;
        }
    }
}

extern "C" void kernel_launch(void* const* d_in, const int* in_sizes, int n_in,
                              void* d_out, int out_size, void* d_ws, size_t ws_size,
                              hipStream_t stream) {
    const float* node_s       = (const float*)d_in[0];
    const float* node_v       = (const float*)d_in[1];
    const float* node_attr    = (const float*)d_in[2];
    const float* edge_attr    = (const float*)d_in[3];
    const float* edge_scalars = (const float*)d_in[4];
    const float* W1_0 = (const float*)d_in[5];
    const float* W1_1 = (const float*)d_in[6];
    const float* Wfc1 = (const float*)d_in[7];
    const float* Wfc2 = (const float*)d_in[8];
    const float* W2_0 = (const float*)d_in[9];
    const float* W2_1 = (const float*)d_in[10];
    const float* Wsc0 = (const float*)d_in[11];
    const float* Wsc1 = (const float*)d_in[12];
    const int* edge_src = (const int*)d_in[13];
    const int* edge_dst = (const int*)d_in[14];

    // workspace layout (bytes), total 38,760,016 <= proven capacity (46MB in r2)
    char* ws = (char*)d_ws;
    unsigned short* xnode = (unsigned short*)(ws);              // N*128*2 = 7,680,000
    unsigned short* hE    = (unsigned short*)(ws + 7680000);    // E*8*2   = 7,680,000
    unsigned short* eaE   = (unsigned short*)(ws + 15360000);   // E*4*2   = 3,840,000
    int2* edPerm          = (int2*)(ws + 19200000);             // E*8     = 3,840,000
    unsigned short* agg   = (unsigned short*)(ws + 23040000);   // N*256*2 = 15,360,000
    int* deg    = (int*)(ws + 38400000);                        // N*4
    int* offs   = (int*)(ws + 38520000);                        // (N+1)*4 pad
    int* cursor = (int*)(ws + 38640016);                        // N*4

    hipMemsetAsync(deg, 0, (size_t)N_NODES * sizeof(int), stream);
    k_pre<<<3750, 256, 0, stream>>>(node_s, node_v, W1_0, W1_1, edge_src, deg, xnode);
    k_sc<<<1875, 256, 0, stream>>>(node_s, node_v, node_attr, Wsc0, Wsc1, (float*)d_out);
    scan_kernel<<<1, 1024, 0, stream>>>(deg, offs, cursor);
    fill_kernel<<<1875, 256, 0, stream>>>(edge_attr, edge_scalars, Wfc1,
                                          edge_src, edge_dst, cursor, hE, eaE, edPerm);
    gather_kernel<<<7500, 256, 0, stream>>>(offs, edPerm, hE, eaE, Wfc2, xnode, agg);
    out1_kernel<<<938, 256, 0, stream>>>(W2_0, W2_1, agg, (float*)d_out);
}

// Round 7
// 242.630 us; speedup vs baseline: 2.4388x; 1.1205x over previous
//
#include <hip/hip_runtime.h>
#include <math.h>

#define N_NODES 30000
#define N_EDGES 480000

typedef __attribute__((ext_vector_type(8))) short short8;
typedef __attribute__((ext_vector_type(4))) float f32x4;

__device__ __forceinline__ unsigned short f2bf(float f) {
    unsigned u = __float_as_uint(f);
    u += 0x7fff + ((u >> 16) & 1);          // RNE
    return (unsigned short)(u >> 16);
}
__device__ __forceinline__ float bfLO(unsigned v) { return __uint_as_float(v << 16); }
__device__ __forceinline__ float bfHI(unsigned v) { return __uint_as_float(v & 0xffff0000u); }
__device__ __forceinline__ unsigned packbf(float a, float b) {
    return (unsigned)f2bf(a) | ((unsigned)f2bf(b) << 16);
}
// truncation pack (products of bf16-exact values: err <= 2^-8, no carry chain)
__device__ __forceinline__ unsigned ptk(float a, float b) {
    return (__float_as_uint(a) >> 16) | (__float_as_uint(b) & 0xffff0000u);
}

union U8 { short8 v; unsigned u[4]; };
union C4 { f32x4 v; float f[4]; };

// ---------------------------------------------------------------------------
// k_pre: blocks 0..3749: x-precompute -> xnode bf16 + fused CSR degree count.
// Blocks 3750..3753: B-fragment prep — pack one weight matrix each into MFMA
// B-fragment order (bf16, scale folded) so k_post loads fragments with single
// coalesced 16B loads. Fragment layout: uint idx = ((kc*2+tile)*64+lane)*4+jp.
// ---------------------------------------------------------------------------
__global__ __launch_bounds__(256) void k_pre(
    const float* __restrict__ node_s,   // (N,32)
    const float* __restrict__ node_v,   // (N,32,3)
    const float* __restrict__ W1_0,     // (32,32) [u][w]
    const float* __restrict__ W1_1,
    const float* __restrict__ Wsc0,     // (32,8,32) -> (256,32)
    const float* __restrict__ Wsc1,
    const float* __restrict__ W2_0,     // (64,32)
    const float* __restrict__ W2_1,
    const int* __restrict__ edge_src,
    int* __restrict__ deg,
    unsigned short* __restrict__ xnode, // (N,128) bf16 packed
    unsigned* __restrict__ bsc0,        // 4096 uints
    unsigned* __restrict__ bsc1,
    unsigned* __restrict__ b20,         // 1024 uints
    unsigned* __restrict__ b21)
{
    __shared__ float sW0[1024];
    __shared__ float sW1[1024];
    int tid = threadIdx.x;

    if (blockIdx.x >= 3750) {
        int b = blockIdx.x - 3750;
        const float* Wm = (b == 0) ? Wsc0 : (b == 1) ? Wsc1 : (b == 2) ? W2_0 : W2_1;
        unsigned* dst = (b == 0) ? bsc0 : (b == 1) ? bsc1 : (b == 2) ? b20 : b21;
        float scale = (b < 2) ? 0.0625f : 0.03125f;  // exact pow2 folds
        int nu = (b < 2) ? 4096 : 1024;
        for (int idx = tid; idx < nu; idx += 256) {
            int jp = idx & 3;
            int lane = (idx >> 2) & 63;
            int ft = (idx >> 8) & 1;
            int kc = idx >> 9;
            int quad = lane >> 4, col = lane & 15;
            int k = kc * 32 + quad * 8 + jp * 2;
            int c = ft * 16 + col;
            dst[idx] = packbf(Wm[k * 32 + c] * scale, Wm[(k + 1) * 32 + c] * scale);
        }
        return;
    }

    if (tid < 128) atomicAdd(&deg[edge_src[blockIdx.x * 128 + tid]], 1);
    for (int i = tid; i < 1024; i += 256) { sW0[i] = W1_0[i]; sW1[i] = W1_1[i]; }
    __syncthreads();
    int node = blockIdx.x * 8 + (tid >> 5);
    int w = tid & 31;
    const float inv_m = 0.1767766953f;  // 1/sqrt(32)
    float x0 = 0.f, x1a = 0.f, x1b = 0.f, x1c = 0.f;
    const float* sp = node_s + (size_t)node * 32;
    const float* vp = node_v + (size_t)node * 96;
#pragma unroll
    for (int u = 0; u < 32; ++u) {
        float su = sp[u];
        float w0 = sW0[u * 32 + w];
        float w1 = sW1[u * 32 + w];
        x0 = fmaf(su, w0, x0);
        x1a = fmaf(vp[u * 3 + 0], w1, x1a);
        x1b = fmaf(vp[u * 3 + 1], w1, x1b);
        x1c = fmaf(vp[u * 3 + 2], w1, x1c);
    }
    uint2 pk;
    pk.x = packbf(x0 * inv_m, x1a * inv_m);
    pk.y = packbf(x1b * inv_m, x1c * inv_m);
    *(uint2*)(xnode + (size_t)node * 128 + w * 4) = pk;
}

// ---------------------------------------------------------------------------
// scan: single-block exclusive prefix over deg, LDS-staged.
// ---------------------------------------------------------------------------
__global__ __launch_bounds__(1024) void scan_kernel(const int* __restrict__ deg,
                                                    int* __restrict__ offs,
                                                    int* __restrict__ cursor) {
    __shared__ int sdeg[N_NODES];
    __shared__ int wsum[16];
    int tid = threadIdx.x;
#pragma unroll
    for (int k = 0; k < 30; ++k) {
        int idx = k * 1024 + tid;
        if (idx < N_NODES) sdeg[idx] = deg[idx];
    }
    __syncthreads();
    int base = tid * 30;
    int s = 0;
    if (base < N_NODES) {
#pragma unroll
        for (int k = 0; k < 30; ++k) s += sdeg[base + k];
    }
    int lane = tid & 63, wid = tid >> 6;
    int inc = s;
#pragma unroll
    for (int d = 1; d < 64; d <<= 1) {
        int o = __shfl_up(inc, d, 64);
        if (lane >= d) inc += o;
    }
    if (lane == 63) wsum[wid] = inc;
    __syncthreads();
    if (tid < 16) {
        int v = wsum[tid];
        int t = v;
#pragma unroll
        for (int d = 1; d < 16; d <<= 1) {
            int o = __shfl_up(t, d, 64);
            if (tid >= d) t += o;
        }
        wsum[tid] = t - v;
    }
    __syncthreads();
    int run = inc - s + wsum[wid];
    if (base < N_NODES) {
#pragma unroll
        for (int k = 0; k < 30; ++k) {
            int n = base + k;
            int d = sdeg[n];
            sdeg[n] = run;
            run += d;
        }
    }
    __syncthreads();
#pragma unroll
    for (int k = 0; k < 30; ++k) {
        int idx = k * 1024 + tid;
        if (idx < N_NODES) {
            int v = sdeg[idx];
            offs[idx] = v;
            cursor[idx] = v;
        }
    }
    if (tid == 0) offs[N_NODES] = N_EDGES;
}

// ---------------------------------------------------------------------------
// fill: per-edge radial MLP h = ssp(es@Wfc1/sqrt(8)); h/ea written coalesced
// at e; single scattered 8B {dst,eid} write at CSR position.
// ---------------------------------------------------------------------------
__global__ __launch_bounds__(256) void fill_kernel(
    const float* __restrict__ edge_attr,     // (E,4)
    const float* __restrict__ edge_scalars,  // (E,8)
    const float* __restrict__ Wfc1,          // (8,8) [k][i]
    const int* __restrict__ edge_src,
    const int* __restrict__ edge_dst,
    int* __restrict__ cursor,
    unsigned short* __restrict__ hE,         // (E,8) bf16, at e
    unsigned short* __restrict__ eaE,        // (E,4) bf16, at e
    int2* __restrict__ edPerm)               // (E) {dst, eid} at pos
{
    __shared__ float sW[64];
    int tid = threadIdx.x;
    if (tid < 64) sW[tid] = Wfc1[tid];
    __syncthreads();

    int e = blockIdx.x * 256 + tid;
    float4 es0 = *(const float4*)(edge_scalars + (size_t)e * 8);
    float4 es1 = *(const float4*)(edge_scalars + (size_t)e * 8 + 4);
    float4 ea  = *(const float4*)(edge_attr + (size_t)e * 4);
    int src = edge_src[e];
    int dst = edge_dst[e];
    int pos = atomicAdd(&cursor[src], 1);

    const float inv8 = 0.3535533906f;
    float h[8];
#pragma unroll
    for (int i = 0; i < 8; ++i) {
        float acc = es0.x * sW[0 * 8 + i];
        acc = fmaf(es0.y, sW[1 * 8 + i], acc);
        acc = fmaf(es0.z, sW[2 * 8 + i], acc);
        acc = fmaf(es0.w, sW[3 * 8 + i], acc);
        acc = fmaf(es1.x, sW[4 * 8 + i], acc);
        acc = fmaf(es1.y, sW[5 * 8 + i], acc);
        acc = fmaf(es1.z, sW[6 * 8 + i], acc);
        acc = fmaf(es1.w, sW[7 * 8 + i], acc);
        acc *= inv8;
        float ax = fabsf(acc);
        float tt = __expf(-ax);
        h[i] = fmaxf(acc, 0.f) + __logf(1.f + tt) - 0.6931471806f;
    }
    uint4 hp;
    hp.x = packbf(h[0], h[1]); hp.y = packbf(h[2], h[3]);
    hp.z = packbf(h[4], h[5]); hp.w = packbf(h[6], h[7]);
    *(uint4*)(hE + (size_t)e * 8) = hp;
    uint2 eo;
    eo.x = packbf(ea.x, ea.y); eo.y = packbf(ea.z, ea.w);
    *(uint2*)(eaE + (size_t)e * 4) = eo;
    int2 ed; ed.x = dst; ed.y = e;
    edPerm[pos] = ed;
}

// ---------------------------------------------------------------------------
// gather: wave per node, half-wave per edge. Branch-free hot loop: prefetch
// indices clamped to [.., end-1] (every executed iteration is in-range, so
// clamped prefetches are valid-memory and only feed unexecuted iterations).
// Pipeline: {dst,eid} 3 iters ahead, x/h/ea 2 iters ahead (~200cyc cover).
// ---------------------------------------------------------------------------
__global__ __launch_bounds__(256) void gather_kernel(
    const int* __restrict__ offs,
    const int2* __restrict__ edPerm,
    const unsigned short* __restrict__ hE,
    const unsigned short* __restrict__ eaE,
    const float* __restrict__ Wfc2,          // (8,128)
    const unsigned short* __restrict__ xnode,
    unsigned short* __restrict__ agg)        // (N,256) bf16
{
    int tid = threadIdx.x;
    int lane = tid & 63;
    int u = lane & 31;
    int half = lane >> 5;
    int node = blockIdx.x * 4 + (tid >> 6);

    const float inv8 = 0.3535533906f;
    const float inv_s3 = 0.5773502692f;
    float wf0[8], wf1[8], wf2[8], wf3[8];
#pragma unroll
    for (int i = 0; i < 8; ++i) {
        wf0[i] = Wfc2[i * 128 + u] * inv8;
        wf1[i] = Wfc2[i * 128 + 32 + u] * inv8;
        wf2[i] = Wfc2[i * 128 + 64 + u] * inv8;
        wf3[i] = Wfc2[i * 128 + 96 + u] * inv8 * inv_s3;
    }

    int beg = offs[node], end = offs[node + 1];
    float a_sa = 0.f, a_sb = 0.f;
    float a_va0 = 0.f, a_va1 = 0.f, a_va2 = 0.f;
    float a_vb0 = 0.f, a_vb1 = 0.f, a_vb2 = 0.f;

    if (end > beg) {
        int last = end - 1;
        int i = beg + half;
        int2 edA = edPerm[min(i, last)];
        int2 edB = edPerm[min(i + 2, last)];
        int2 edC = edPerm[min(i + 4, last)];
        uint2 xA = *(const uint2*)(xnode + (size_t)edA.x * 128 + u * 4);
        uint4 hA = *(const uint4*)(hE + (size_t)edA.y * 8);
        uint2 eA = *(const uint2*)(eaE + (size_t)edA.y * 4);
        uint2 xB = *(const uint2*)(xnode + (size_t)edB.x * 128 + u * 4);
        uint4 hB = *(const uint4*)(hE + (size_t)edB.y * 8);
        uint2 eB = *(const uint2*)(eaE + (size_t)edB.y * 4);

        for (; i < end; i += 2) {
            int2 edD = edPerm[min(i + 6, last)];
            uint2 xC = *(const uint2*)(xnode + (size_t)edC.x * 128 + u * 4);
            uint4 hC = *(const uint4*)(hE + (size_t)edC.y * 8);
            uint2 eC = *(const uint2*)(eaE + (size_t)edC.y * 4);

            float h0 = bfLO(hA.x), h1 = bfHI(hA.x), h2 = bfLO(hA.y), h3 = bfHI(hA.y);
            float h4 = bfLO(hA.z), h5 = bfHI(hA.z), h6 = bfLO(hA.w), h7 = bfHI(hA.w);
            float a00 = h0 * wf0[0], a01 = h0 * wf1[0], a10 = h0 * wf2[0], a11 = h0 * wf3[0];
            a00 = fmaf(h1, wf0[1], a00); a01 = fmaf(h1, wf1[1], a01); a10 = fmaf(h1, wf2[1], a10); a11 = fmaf(h1, wf3[1], a11);
            a00 = fmaf(h2, wf0[2], a00); a01 = fmaf(h2, wf1[2], a01); a10 = fmaf(h2, wf2[2], a10); a11 = fmaf(h2, wf3[2], a11);
            a00 = fmaf(h3, wf0[3], a00); a01 = fmaf(h3, wf1[3], a01); a10 = fmaf(h3, wf2[3], a10); a11 = fmaf(h3, wf3[3], a11);
            a00 = fmaf(h4, wf0[4], a00); a01 = fmaf(h4, wf1[4], a01); a10 = fmaf(h4, wf2[4], a10); a11 = fmaf(h4, wf3[4], a11);
            a00 = fmaf(h5, wf0[5], a00); a01 = fmaf(h5, wf1[5], a01); a10 = fmaf(h5, wf2[5], a10); a11 = fmaf(h5, wf3[5], a11);
            a00 = fmaf(h6, wf0[6], a00); a01 = fmaf(h6, wf1[6], a01); a10 = fmaf(h6, wf2[6], a10); a11 = fmaf(h6, wf3[6], a11);
            a00 = fmaf(h7, wf0[7], a00); a01 = fmaf(h7, wf1[7], a01); a10 = fmaf(h7, wf2[7], a10); a11 = fmaf(h7, wf3[7], a11);

            float sh0 = bfLO(eA.x), s1xe = bfHI(eA.x), s1ye = bfLO(eA.y), s1ze = bfHI(eA.y);
            float x0 = bfLO(xA.x), xd0 = bfHI(xA.x), xd1 = bfLO(xA.y), xd2 = bfHI(xA.y);

            float dot = xd0 * s1xe + xd1 * s1ye + xd2 * s1ze;
            a_sa = fmaf(a00 * sh0, x0, a_sa);
            a_sb = fmaf(a11, dot, a_sb);
            float w01x0 = a01 * x0;
            a_va0 = fmaf(w01x0, s1xe, a_va0);
            a_va1 = fmaf(w01x0, s1ye, a_va1);
            a_va2 = fmaf(w01x0, s1ze, a_va2);
            float t10 = a10 * sh0;
            a_vb0 = fmaf(t10, xd0, a_vb0);
            a_vb1 = fmaf(t10, xd1, a_vb1);
            a_vb2 = fmaf(t10, xd2, a_vb2);

            hA = hB; eA = eB; xA = xB;
            hB = hC; eB = eC; xB = xC;
            edC = edD;
        }
    }
    a_sa  += __shfl_xor(a_sa, 32, 64);
    a_sb  += __shfl_xor(a_sb, 32, 64);
    a_va0 += __shfl_xor(a_va0, 32, 64);
    a_va1 += __shfl_xor(a_va1, 32, 64);
    a_va2 += __shfl_xor(a_va2, 32, 64);
    a_vb0 += __shfl_xor(a_vb0, 32, 64);
    a_vb1 += __shfl_xor(a_vb1, 32, 64);
    a_vb2 += __shfl_xor(a_vb2, 32, 64);

    unsigned short* ap = agg + (size_t)node * 256;
    if (half == 0) {
        ap[u]       = f2bf(a_sa);
        ap[32 + u]  = f2bf(a_sb);
        ap[64 + u]  = f2bf(a_va0);
        ap[96 + u]  = f2bf(a_vb0);
    } else {
        ap[128 + u] = f2bf(a_va1);
        ap[160 + u] = f2bf(a_vb1);
        ap[192 + u] = f2bf(a_va2);
        ap[224 + u] = f2bf(a_vb2);
    }
}

// ---------------------------------------------------------------------------
// k_post: fused self-connection GEMM (K=256) + W2-apply GEMM (K=64) into the
// SAME MFMA accumulators; plain f32 store of out (no RMW). Tiles of 16 rows:
// t<1875 = scalar rows (n), t>=1875 = vector rows (R=3n+d). B-fragments come
// pre-packed from k_pre's prep blocks (scales folded), one 16B load each.
// mfma_f32_16x16x32_bf16: A[m=lane&15][k=quad*8+j], B[k][n=lane&15],
// D col=lane&15, row=quad*4+reg.
// ---------------------------------------------------------------------------
__global__ __launch_bounds__(256) void k_post(
    const float* __restrict__ node_s,     // (N,32)
    const float* __restrict__ node_v,     // (N,32,3)
    const float* __restrict__ node_attr,  // (N,8)
    const unsigned* __restrict__ bsc0,    // prepped B frags (scale 1/16)
    const unsigned* __restrict__ bsc1,
    const unsigned* __restrict__ b20,     // prepped B frags (scale 1/32)
    const unsigned* __restrict__ b21,
    const unsigned short* __restrict__ agg,  // (N,256) bf16
    float* __restrict__ out)              // (N,128)
{
    __shared__ float stg[4][688];
    int tid = threadIdx.x;
    int lane = tid & 63;
    int wv = tid >> 6;
    int t = blockIdx.x * 4 + wv;
    int col = lane & 15;
    int quad = lane >> 4;
    int m = lane & 15;
    bool is_s = (t < 1875);

    // ---- B fragments: coalesced 16B loads from prep buffers ----
    const short* Bs = (const short*)(is_s ? bsc0 : bsc1);
    const short* B2 = (const short*)(is_s ? b20 : b21);
    short8 bs0[8], bs1[8], b2f[2][2];
#pragma unroll
    for (int kc = 0; kc < 8; ++kc) {
        bs0[kc] = *(const short8*)(Bs + ((kc * 2 + 0) * 64 + lane) * 8);
        bs1[kc] = *(const short8*)(Bs + ((kc * 2 + 1) * 64 + lane) * 8);
    }
#pragma unroll
    for (int kc = 0; kc < 2; ++kc) {
#pragma unroll
        for (int ft = 0; ft < 2; ++ft)
            b2f[kc][ft] = *(const short8*)(B2 + ((kc * 2 + ft) * 64 + lane) * 8);
    }

    // ---- stage factor data; compute A-row indices ----
    float* S = stg[wv];
    int fbase, fstep, n_a, aoff;
    if (is_s) {
        for (int q = lane; q < 512; q += 64)
            S[(q >> 5) * 33 + (q & 31)] = node_s[(size_t)t * 512 + q];
        n_a = t * 16 + m;
        fbase = m * 33;
        fstep = 1;
        aoff = n_a * 256;                    // agg A-row base (shorts)
    } else {
        int vt = t - 1875;
        int R0 = vt * 16;
        int nlo = R0 / 3;
        int nhi = (R0 + 15) / 3;
        int cnt = (nhi - nlo + 1) * 96;
        const float* src = node_v + (size_t)nlo * 96;
        for (int q = lane; q < cnt; q += 64)
            S[(q / 96) * 97 + (q % 96)] = src[q];
        int R = R0 + m;
        n_a = R / 3;
        int d_a = R - n_a * 3;
        fbase = (n_a - nlo) * 97 + d_a;
        fstep = 3;
        aoff = n_a * 256 + 64 + 64 * d_a;
    }
    float4 A0 = *(const float4*)(node_attr + (size_t)n_a * 8);
    float4 A1 = *(const float4*)(node_attr + (size_t)n_a * 8 + 4);
    float aa0 = A0.x, aa1 = A0.y, aa2 = A0.z, aa3 = A0.w;
    float aa4 = A1.x, aa5 = A1.y, aa6 = A1.z, aa7 = A1.w;

    f32x4 acc0 = {0.f, 0.f, 0.f, 0.f};
    f32x4 acc1 = {0.f, 0.f, 0.f, 0.f};

    // ---- W2 GEMM: K=64, A direct from agg (aligned short8) ----
#pragma unroll
    for (int kc = 0; kc < 2; ++kc) {
        short8 af = *(const short8*)((const short*)agg + (size_t)aoff + kc * 32 + quad * 8);
        acc0 = __builtin_amdgcn_mfma_f32_16x16x32_bf16(af, b2f[kc][0], acc0, 0, 0, 0);
        acc1 = __builtin_amdgcn_mfma_f32_16x16x32_bf16(af, b2f[kc][1], acc1, 0, 0, 0);
    }

    // ---- self-connection GEMM: K=256, A built from staged factor * attr ----
#pragma unroll
    for (int kc = 0; kc < 8; ++kc) {
        int u = kc * 4 + quad;
        float f = S[fbase + u * fstep];
        U8 af;
        af.u[0] = ptk(f * aa0, f * aa1);
        af.u[1] = ptk(f * aa2, f * aa3);
        af.u[2] = ptk(f * aa4, f * aa5);
        af.u[3] = ptk(f * aa6, f * aa7);
        acc0 = __builtin_amdgcn_mfma_f32_16x16x32_bf16(af.v, bs0[kc], acc0, 0, 0, 0);
        acc1 = __builtin_amdgcn_mfma_f32_16x16x32_bf16(af.v, bs1[kc], acc1, 0, 0, 0);
    }

    // ---- epilogue: plain store ----
    C4 c0, c1;
    c0.v = acc0; c1.v = acc1;
    if (is_s) {
#pragma unroll
        for (int r = 0; r < 4; ++r) {
            int n = t * 16 + (quad << 2) + r;
            out[(size_t)n * 128 + col]      = c0.f[r];
            out[(size_t)n * 128 + col + 16] = c1.f[r];
        }
    } else {
        int R0 = (t - 1875) * 16;
#pragma unroll
        for (int r = 0; r < 4; ++r) {
            int R = R0 + (quad << 2) + r;
            int nn = R / 3;
            int dd = R - nn * 3;
            out[(size_t)nn * 128 + 32 + 3 * col + dd]        = c0.f[r];
            out[(size_t)nn * 128 + 32 + 3 * (col + 16) + dd] = c1.f[r];
        }
    }
}

extern "C" void kernel_launch(void* const* d_in, const int* in_sizes, int n_in,
                              void* d_out, int out_size, void* d_ws, size_t ws_size,
                              hipStream_t stream) {
    const float* node_s       = (const float*)d_in[0];
    const float* node_v       = (const float*)d_in[1];
    const float* node_attr    = (const float*)d_in[2];
    const float* edge_attr    = (const float*)d_in[3];
    const float* edge_scalars = (const float*)d_in[4];
    const float* W1_0 = (const float*)d_in[5];
    const float* W1_1 = (const float*)d_in[6];
    const float* Wfc1 = (const float*)d_in[7];
    const float* Wfc2 = (const float*)d_in[8];
    const float* W2_0 = (const float*)d_in[9];
    const float* W2_1 = (const float*)d_in[10];
    const float* Wsc0 = (const float*)d_in[11];
    const float* Wsc1 = (const float*)d_in[12];
    const int* edge_src = (const int*)d_in[13];
    const int* edge_dst = (const int*)d_in[14];

    // workspace layout (bytes), total ~38.8MB <= proven capacity (46MB in r2)
    char* ws = (char*)d_ws;
    unsigned short* xnode = (unsigned short*)(ws);              // N*128*2 = 7,680,000
    unsigned short* hE    = (unsigned short*)(ws + 7680000);    // E*8*2   = 7,680,000
    unsigned short* eaE   = (unsigned short*)(ws + 15360000);   // E*4*2   = 3,840,000
    int2* edPerm          = (int2*)(ws + 19200000);             // E*8     = 3,840,000
    unsigned short* agg   = (unsigned short*)(ws + 23040000);   // N*256*2 = 15,360,000
    int* deg    = (int*)(ws + 38400000);                        // N*4
    int* offs   = (int*)(ws + 38520000);                        // (N+1)*4 pad
    int* cursor = (int*)(ws + 38640016);                        // N*4
    unsigned* bsc0 = (unsigned*)(ws + 38760064);                // 16,384
    unsigned* bsc1 = (unsigned*)(ws + 38776448);                // 16,384
    unsigned* b20  = (unsigned*)(ws + 38792832);                // 4,096
    unsigned* b21  = (unsigned*)(ws + 38796928);                // 4,096

    hipMemsetAsync(deg, 0, (size_t)N_NODES * sizeof(int), stream);
    k_pre<<<3754, 256, 0, stream>>>(node_s, node_v, W1_0, W1_1, Wsc0, Wsc1,
                                    W2_0, W2_1, edge_src, deg, xnode,
                                    bsc0, bsc1, b20, b21);
    scan_kernel<<<1, 1024, 0, stream>>>(deg, offs, cursor);
    fill_kernel<<<1875, 256, 0, stream>>>(edge_attr, edge_scalars, Wfc1,
                                          edge_src, edge_dst, cursor, hE, eaE, edPerm);
    gather_kernel<<<7500, 256, 0, stream>>>(offs, edPerm, hE, eaE, Wfc2, xnode, agg);
    k_post<<<1875, 256, 0, stream>>>(node_s, node_v, node_attr,
                                     bsc0, bsc1, b20, b21, agg, (float*)d_out);
}

// Round 8
// 240.806 us; speedup vs baseline: 2.4572x; 1.0076x over previous
//
#include <hip/hip_runtime.h>
#include <math.h>

#define N_NODES 30000
#define N_EDGES 480000

typedef __attribute__((ext_vector_type(8))) short short8;
typedef __attribute__((ext_vector_type(4))) float f32x4;

__device__ __forceinline__ unsigned short f2bf(float f) {
    unsigned u = __float_as_uint(f);
    u += 0x7fff + ((u >> 16) & 1);          // RNE
    return (unsigned short)(u >> 16);
}
__device__ __forceinline__ float bfLO(unsigned v) { return __uint_as_float(v << 16); }
__device__ __forceinline__ float bfHI(unsigned v) { return __uint_as_float(v & 0xffff0000u); }
__device__ __forceinline__ unsigned packbf(float a, float b) {
    return (unsigned)f2bf(a) | ((unsigned)f2bf(b) << 16);
}
// truncation pack (products of bf16-exact values: err <= 2^-8, no carry chain)
__device__ __forceinline__ unsigned ptk(float a, float b) {
    return (__float_as_uint(a) >> 16) | (__float_as_uint(b) & 0xffff0000u);
}

union U8 { short8 v; unsigned u[4]; };
union C4 { f32x4 v; float f[4]; };

#define VE(A, B, C, idx) ((idx) < 4 ? (&(A).x)[(idx)] : (idx) < 8 ? (&(B).x)[(idx) - 4] : (&(C).x)[(idx) - 8])

// ---------------------------------------------------------------------------
// k_pre: blocks 0..1874: x-precompute (2 nodes/thread, float4 broadcast loads,
// bf16-packed W1 LDS) -> xnode bf16, + fused CSR degree count (256 edges/blk).
// Blocks 1875..1878: pack Wsc0/Wsc1/W2_0/W2_1 into MFMA B-fragment order.
// ---------------------------------------------------------------------------
__global__ __launch_bounds__(256) void k_pre(
    const float* __restrict__ node_s,   // (N,32)
    const float* __restrict__ node_v,   // (N,32,3)
    const float* __restrict__ W1_0,     // (32,32) [u][w]
    const float* __restrict__ W1_1,
    const float* __restrict__ Wsc0,     // (256,32)
    const float* __restrict__ Wsc1,
    const float* __restrict__ W2_0,     // (64,32)
    const float* __restrict__ W2_1,
    const int* __restrict__ edge_src,
    int* __restrict__ deg,
    unsigned short* __restrict__ xnode, // (N,128) bf16 packed
    unsigned* __restrict__ bsc0,        // 4096 uints
    unsigned* __restrict__ bsc1,
    unsigned* __restrict__ b20,         // 1024 uints
    unsigned* __restrict__ b21)
{
    __shared__ unsigned sW1p[1024];     // {W1_0,W1_1} bf16 pair at [u*32+w]
    int tid = threadIdx.x;

    if (blockIdx.x >= 1875) {
        int b = blockIdx.x - 1875;
        const float* Wm = (b == 0) ? Wsc0 : (b == 1) ? Wsc1 : (b == 2) ? W2_0 : W2_1;
        unsigned* dst = (b == 0) ? bsc0 : (b == 1) ? bsc1 : (b == 2) ? b20 : b21;
        float scale = (b < 2) ? 0.0625f : 0.03125f;  // exact pow2 folds
        int nu = (b < 2) ? 4096 : 1024;
        for (int idx = tid; idx < nu; idx += 256) {
            int jp = idx & 3;
            int lane = (idx >> 2) & 63;
            int ft = (idx >> 8) & 1;
            int kc = idx >> 9;
            int quad = lane >> 4, col = lane & 15;
            int k = kc * 32 + quad * 8 + jp * 2;
            int c = ft * 16 + col;
            dst[idx] = packbf(Wm[k * 32 + c] * scale, Wm[(k + 1) * 32 + c] * scale);
        }
        return;
    }

    atomicAdd(&deg[edge_src[blockIdx.x * 256 + tid]], 1);
    for (int i = tid; i < 1024; i += 256) sW1p[i] = packbf(W1_0[i], W1_1[i]);
    __syncthreads();

    int w = tid & 31;
    int n0 = blockIdx.x * 16 + (tid >> 5) * 2;   // 2 nodes per thread
    const float inv_m = 0.1767766953f;           // 1/sqrt(32)
    float x0[2] = {0.f, 0.f}, x1a[2] = {0.f, 0.f};
    float x1b[2] = {0.f, 0.f}, x1c[2] = {0.f, 0.f};

    for (int uc = 0; uc < 32; uc += 4) {
        float4 sv[2], v0[2], v1[2], v2[2];
#pragma unroll
        for (int j = 0; j < 2; ++j) {
            sv[j] = *(const float4*)(node_s + (size_t)(n0 + j) * 32 + uc);
            const float* vp = node_v + (size_t)(n0 + j) * 96 + uc * 3;
            v0[j] = *(const float4*)(vp);
            v1[j] = *(const float4*)(vp + 4);
            v2[j] = *(const float4*)(vp + 8);
        }
#pragma unroll
        for (int kk = 0; kk < 4; ++kk) {
            int u = uc + kk;
            unsigned wp = sW1p[u * 32 + w];
            float w0k = bfLO(wp), w1k = bfHI(wp);
#pragma unroll
            for (int j = 0; j < 2; ++j) {
                float s  = (&sv[j].x)[kk];
                float vx = VE(v0[j], v1[j], v2[j], kk * 3 + 0);
                float vy = VE(v0[j], v1[j], v2[j], kk * 3 + 1);
                float vz = VE(v0[j], v1[j], v2[j], kk * 3 + 2);
                x0[j]  = fmaf(s,  w0k, x0[j]);
                x1a[j] = fmaf(vx, w1k, x1a[j]);
                x1b[j] = fmaf(vy, w1k, x1b[j]);
                x1c[j] = fmaf(vz, w1k, x1c[j]);
            }
        }
    }
#pragma unroll
    for (int j = 0; j < 2; ++j) {
        uint2 pk;
        pk.x = packbf(x0[j] * inv_m, x1a[j] * inv_m);
        pk.y = packbf(x1b[j] * inv_m, x1c[j] * inv_m);
        *(uint2*)(xnode + (size_t)(n0 + j) * 128 + w * 4) = pk;
    }
}

// ---------------------------------------------------------------------------
// scan: single-block exclusive prefix over deg, LDS-staged.
// ---------------------------------------------------------------------------
__global__ __launch_bounds__(1024) void scan_kernel(const int* __restrict__ deg,
                                                    int* __restrict__ offs,
                                                    int* __restrict__ cursor) {
    __shared__ int sdeg[N_NODES];
    __shared__ int wsum[16];
    int tid = threadIdx.x;
#pragma unroll
    for (int k = 0; k < 30; ++k) {
        int idx = k * 1024 + tid;
        if (idx < N_NODES) sdeg[idx] = deg[idx];
    }
    __syncthreads();
    int base = tid * 30;
    int s = 0;
    if (base < N_NODES) {
#pragma unroll
        for (int k = 0; k < 30; ++k) s += sdeg[base + k];
    }
    int lane = tid & 63, wid = tid >> 6;
    int inc = s;
#pragma unroll
    for (int d = 1; d < 64; d <<= 1) {
        int o = __shfl_up(inc, d, 64);
        if (lane >= d) inc += o;
    }
    if (lane == 63) wsum[wid] = inc;
    __syncthreads();
    if (tid < 16) {
        int v = wsum[tid];
        int t = v;
#pragma unroll
        for (int d = 1; d < 16; d <<= 1) {
            int o = __shfl_up(t, d, 64);
            if (tid >= d) t += o;
        }
        wsum[tid] = t - v;
    }
    __syncthreads();
    int run = inc - s + wsum[wid];
    if (base < N_NODES) {
#pragma unroll
        for (int k = 0; k < 30; ++k) {
            int n = base + k;
            int d = sdeg[n];
            sdeg[n] = run;
            run += d;
        }
    }
    __syncthreads();
#pragma unroll
    for (int k = 0; k < 30; ++k) {
        int idx = k * 1024 + tid;
        if (idx < N_NODES) {
            int v = sdeg[idx];
            offs[idx] = v;
            cursor[idx] = v;
        }
    }
    if (tid == 0) offs[N_NODES] = N_EDGES;
}

// ---------------------------------------------------------------------------
// fill: per-edge radial MLP h = ssp(es@Wfc1/sqrt(8)); writes ONE 32B record
// per edge at its CSR slot: {h[8] bf16 | ea[4] bf16, dst, pad}. gather then
// streams records with zero indirection.
// ---------------------------------------------------------------------------
__global__ __launch_bounds__(256) void fill_kernel(
    const float* __restrict__ edge_attr,     // (E,4)
    const float* __restrict__ edge_scalars,  // (E,8)
    const float* __restrict__ Wfc1,          // (8,8) [k][i]
    const int* __restrict__ edge_src,
    const int* __restrict__ edge_dst,
    int* __restrict__ cursor,
    uint4* __restrict__ rec)                 // (E,2) uint4
{
    __shared__ float sW[64];
    int tid = threadIdx.x;
    if (tid < 64) sW[tid] = Wfc1[tid];
    __syncthreads();

    int e = blockIdx.x * 256 + tid;
    float4 es0 = *(const float4*)(edge_scalars + (size_t)e * 8);
    float4 es1 = *(const float4*)(edge_scalars + (size_t)e * 8 + 4);
    float4 ea  = *(const float4*)(edge_attr + (size_t)e * 4);
    int src = edge_src[e];
    int dst = edge_dst[e];
    int pos = atomicAdd(&cursor[src], 1);

    const float inv8 = 0.3535533906f;
    float h[8];
#pragma unroll
    for (int i = 0; i < 8; ++i) {
        float acc = es0.x * sW[0 * 8 + i];
        acc = fmaf(es0.y, sW[1 * 8 + i], acc);
        acc = fmaf(es0.z, sW[2 * 8 + i], acc);
        acc = fmaf(es0.w, sW[3 * 8 + i], acc);
        acc = fmaf(es1.x, sW[4 * 8 + i], acc);
        acc = fmaf(es1.y, sW[5 * 8 + i], acc);
        acc = fmaf(es1.z, sW[6 * 8 + i], acc);
        acc = fmaf(es1.w, sW[7 * 8 + i], acc);
        acc *= inv8;
        float ax = fabsf(acc);
        float tt = __expf(-ax);
        h[i] = fmaxf(acc, 0.f) + __logf(1.f + tt) - 0.6931471806f;
    }
    uint4 r0, r1;
    r0.x = packbf(h[0], h[1]); r0.y = packbf(h[2], h[3]);
    r0.z = packbf(h[4], h[5]); r0.w = packbf(h[6], h[7]);
    r1.x = packbf(ea.x, ea.y); r1.y = packbf(ea.z, ea.w);
    r1.z = (unsigned)dst; r1.w = 0;
    rec[2 * pos]     = r0;
    rec[2 * pos + 1] = r1;
}

// ---------------------------------------------------------------------------
// gather: wave per node, half-wave per edge. Records stream in CSR order
// (no indirection); only xnode is a random gather (issued 2 iters early,
// dst from the record pipeline). Branch-free clamped prefetch.
// ---------------------------------------------------------------------------
__global__ __launch_bounds__(256) void gather_kernel(
    const int* __restrict__ offs,
    const uint4* __restrict__ rec,           // (E,2)
    const float* __restrict__ Wfc2,          // (8,128)
    const unsigned short* __restrict__ xnode,
    unsigned short* __restrict__ agg)        // (N,256) bf16
{
    int tid = threadIdx.x;
    int lane = tid & 63;
    int u = lane & 31;
    int half = lane >> 5;
    int node = blockIdx.x * 4 + (tid >> 6);

    const float inv8 = 0.3535533906f;
    const float inv_s3 = 0.5773502692f;
    float wf0[8], wf1[8], wf2[8], wf3[8];
#pragma unroll
    for (int i = 0; i < 8; ++i) {
        wf0[i] = Wfc2[i * 128 + u] * inv8;
        wf1[i] = Wfc2[i * 128 + 32 + u] * inv8;
        wf2[i] = Wfc2[i * 128 + 64 + u] * inv8;
        wf3[i] = Wfc2[i * 128 + 96 + u] * inv8 * inv_s3;
    }

    int beg = offs[node], end = offs[node + 1];
    float a_sa = 0.f, a_sb = 0.f;
    float a_va0 = 0.f, a_va1 = 0.f, a_va2 = 0.f;
    float a_vb0 = 0.f, a_vb1 = 0.f, a_vb2 = 0.f;

    if (end > beg) {
        int last = end - 1;
        int i = beg + half;
        int p = min(i, last);
        uint4 a0 = rec[2 * p], a1 = rec[2 * p + 1];
        p = min(i + 2, last);
        uint4 b0 = rec[2 * p], b1 = rec[2 * p + 1];
        p = min(i + 4, last);
        uint4 c0 = rec[2 * p], c1 = rec[2 * p + 1];
        uint2 xA = *(const uint2*)(xnode + (size_t)(int)a1.z * 128 + u * 4);
        uint2 xB = *(const uint2*)(xnode + (size_t)(int)b1.z * 128 + u * 4);

        for (; i < end; i += 2) {
            int pD = min(i + 6, last);
            uint4 d0 = rec[2 * pD], d1 = rec[2 * pD + 1];
            uint2 xC = *(const uint2*)(xnode + (size_t)(int)c1.z * 128 + u * 4);

            float h0 = bfLO(a0.x), h1 = bfHI(a0.x), h2 = bfLO(a0.y), h3 = bfHI(a0.y);
            float h4 = bfLO(a0.z), h5 = bfHI(a0.z), h6 = bfLO(a0.w), h7 = bfHI(a0.w);
            float a00 = h0 * wf0[0], a01 = h0 * wf1[0], a10 = h0 * wf2[0], a11 = h0 * wf3[0];
            a00 = fmaf(h1, wf0[1], a00); a01 = fmaf(h1, wf1[1], a01); a10 = fmaf(h1, wf2[1], a10); a11 = fmaf(h1, wf3[1], a11);
            a00 = fmaf(h2, wf0[2], a00); a01 = fmaf(h2, wf1[2], a01); a10 = fmaf(h2, wf2[2], a10); a11 = fmaf(h2, wf3[2], a11);
            a00 = fmaf(h3, wf0[3], a00); a01 = fmaf(h3, wf1[3], a01); a10 = fmaf(h3, wf2[3], a10); a11 = fmaf(h3, wf3[3], a11);
            a00 = fmaf(h4, wf0[4], a00); a01 = fmaf(h4, wf1[4], a01); a10 = fmaf(h4, wf2[4], a10); a11 = fmaf(h4, wf3[4], a11);
            a00 = fmaf(h5, wf0[5], a00); a01 = fmaf(h5, wf1[5], a01); a10 = fmaf(h5, wf2[5], a10); a11 = fmaf(h5, wf3[5], a11);
            a00 = fmaf(h6, wf0[6], a00); a01 = fmaf(h6, wf1[6], a01); a10 = fmaf(h6, wf2[6], a10); a11 = fmaf(h6, wf3[6], a11);
            a00 = fmaf(h7, wf0[7], a00); a01 = fmaf(h7, wf1[7], a01); a10 = fmaf(h7, wf2[7], a10); a11 = fmaf(h7, wf3[7], a11);

            float sh0 = bfLO(a1.x), s1xe = bfHI(a1.x), s1ye = bfLO(a1.y), s1ze = bfHI(a1.y);
            float x0 = bfLO(xA.x), xd0 = bfHI(xA.x), xd1 = bfLO(xA.y), xd2 = bfHI(xA.y);

            float dot = xd0 * s1xe + xd1 * s1ye + xd2 * s1ze;
            a_sa = fmaf(a00 * sh0, x0, a_sa);
            a_sb = fmaf(a11, dot, a_sb);
            float w01x0 = a01 * x0;
            a_va0 = fmaf(w01x0, s1xe, a_va0);
            a_va1 = fmaf(w01x0, s1ye, a_va1);
            a_va2 = fmaf(w01x0, s1ze, a_va2);
            float t10 = a10 * sh0;
            a_vb0 = fmaf(t10, xd0, a_vb0);
            a_vb1 = fmaf(t10, xd1, a_vb1);
            a_vb2 = fmaf(t10, xd2, a_vb2);

            a0 = b0; a1 = b1; xA = xB;
            b0 = c0; b1 = c1; xB = xC;
            c0 = d0; c1 = d1;
        }
    }
    a_sa  += __shfl_xor(a_sa, 32, 64);
    a_sb  += __shfl_xor(a_sb, 32, 64);
    a_va0 += __shfl_xor(a_va0, 32, 64);
    a_va1 += __shfl_xor(a_va1, 32, 64);
    a_va2 += __shfl_xor(a_va2, 32, 64);
    a_vb0 += __shfl_xor(a_vb0, 32, 64);
    a_vb1 += __shfl_xor(a_vb1, 32, 64);
    a_vb2 += __shfl_xor(a_vb2, 32, 64);

    unsigned short* ap = agg + (size_t)node * 256;
    if (half == 0) {
        ap[u]       = f2bf(a_sa);
        ap[32 + u]  = f2bf(a_sb);
        ap[64 + u]  = f2bf(a_va0);
        ap[96 + u]  = f2bf(a_vb0);
    } else {
        ap[128 + u] = f2bf(a_va1);
        ap[160 + u] = f2bf(a_vb1);
        ap[192 + u] = f2bf(a_va2);
        ap[224 + u] = f2bf(a_vb2);
    }
}

// ---------------------------------------------------------------------------
// k_post: fused self-connection GEMM (K=256) + W2-apply GEMM (K=64) into the
// SAME MFMA accumulators; plain f32 store (no RMW). Pre-packed B fragments.
// ---------------------------------------------------------------------------
__global__ __launch_bounds__(256) void k_post(
    const float* __restrict__ node_s,     // (N,32)
    const float* __restrict__ node_v,     // (N,32,3)
    const float* __restrict__ node_attr,  // (N,8)
    const unsigned* __restrict__ bsc0,
    const unsigned* __restrict__ bsc1,
    const unsigned* __restrict__ b20,
    const unsigned* __restrict__ b21,
    const unsigned short* __restrict__ agg,  // (N,256) bf16
    float* __restrict__ out)              // (N,128)
{
    __shared__ float stg[4][688];
    int tid = threadIdx.x;
    int lane = tid & 63;
    int wv = tid >> 6;
    int t = blockIdx.x * 4 + wv;
    int col = lane & 15;
    int quad = lane >> 4;
    int m = lane & 15;
    bool is_s = (t < 1875);

    const short* Bs = (const short*)(is_s ? bsc0 : bsc1);
    const short* B2 = (const short*)(is_s ? b20 : b21);
    short8 bs0[8], bs1[8], b2f[2][2];
#pragma unroll
    for (int kc = 0; kc < 8; ++kc) {
        bs0[kc] = *(const short8*)(Bs + ((kc * 2 + 0) * 64 + lane) * 8);
        bs1[kc] = *(const short8*)(Bs + ((kc * 2 + 1) * 64 + lane) * 8);
    }
#pragma unroll
    for (int kc = 0; kc < 2; ++kc) {
#pragma unroll
        for (int ft = 0; ft < 2; ++ft)
            b2f[kc][ft] = *(const short8*)(B2 + ((kc * 2 + ft) * 64 + lane) * 8);
    }

    float* S = stg[wv];
    int fbase, fstep, n_a, aoff;
    if (is_s) {
        for (int q = lane; q < 512; q += 64)
            S[(q >> 5) * 33 + (q & 31)] = node_s[(size_t)t * 512 + q];
        n_a = t * 16 + m;
        fbase = m * 33;
        fstep = 1;
        aoff = n_a * 256;
    } else {
        int vt = t - 1875;
        int R0 = vt * 16;
        int nlo = R0 / 3;
        int nhi = (R0 + 15) / 3;
        int cnt = (nhi - nlo + 1) * 96;
        const float* src = node_v + (size_t)nlo * 96;
        for (int q = lane; q < cnt; q += 64)
            S[(q / 96) * 97 + (q % 96)] = src[q];
        int R = R0 + m;
        n_a = R / 3;
        int d_a = R - n_a * 3;
        fbase = (n_a - nlo) * 97 + d_a;
        fstep = 3;
        aoff = n_a * 256 + 64 + 64 * d_a;
    }
    float4 A0 = *(const float4*)(node_attr + (size_t)n_a * 8);
    float4 A1 = *(const float4*)(node_attr + (size_t)n_a * 8 + 4);
    float aa0 = A0.x, aa1 = A0.y, aa2 = A0.z, aa3 = A0.w;
    float aa4 = A1.x, aa5 = A1.y, aa6 = A1.z, aa7 = A1.w;

    f32x4 acc0 = {0.f, 0.f, 0.f, 0.f};
    f32x4 acc1 = {0.f, 0.f, 0.f, 0.f};

#pragma unroll
    for (int kc = 0; kc < 2; ++kc) {
        short8 af = *(const short8*)((const short*)agg + (size_t)aoff + kc * 32 + quad * 8);
        acc0 = __builtin_amdgcn_mfma_f32_16x16x32_bf16(af, b2f[kc][0], acc0, 0, 0, 0);
        acc1 = __builtin_amdgcn_mfma_f32_16x16x32_bf16(af, b2f[kc][1], acc1, 0, 0, 0);
    }
#pragma unroll
    for (int kc = 0; kc < 8; ++kc) {
        int u = kc * 4 + quad;
        float f = S[fbase + u * fstep];
        U8 af;
        af.u[0] = ptk(f * aa0, f * aa1);
        af.u[1] = ptk(f * aa2, f * aa3);
        af.u[2] = ptk(f * aa4, f * aa5);
        af.u[3] = ptk(f * aa6, f * aa7);
        acc0 = __builtin_amdgcn_mfma_f32_16x16x32_bf16(af.v, bs0[kc], acc0, 0, 0, 0);
        acc1 = __builtin_amdgcn_mfma_f32_16x16x32_bf16(af.v, bs1[kc], acc1, 0, 0, 0);
    }

    C4 c0, c1;
    c0.v = acc0; c1.v = acc1;
    if (is_s) {
#pragma unroll
        for (int r = 0; r < 4; ++r) {
            int n = t * 16 + (quad << 2) + r;
            out[(size_t)n * 128 + col]      = c0.f[r];
            out[(size_t)n * 128 + col + 16] = c1.f[r];
        }
    } else {
        int R0 = (t - 1875) * 16;
#pragma unroll
        for (int r = 0; r < 4; ++r) {
            int R = R0 + (quad << 2) + r;
            int nn = R / 3;
            int dd = R - nn * 3;
            out[(size_t)nn * 128 + 32 + 3 * col + dd]        = c0.f[r];
            out[(size_t)nn * 128 + 32 + 3 * (col + 16) + dd] = c1.f[r];
        }
    }
}

extern "C" void kernel_launch(void* const* d_in, const int* in_sizes, int n_in,
                              void* d_out, int out_size, void* d_ws, size_t ws_size,
                              hipStream_t stream) {
    const float* node_s       = (const float*)d_in[0];
    const float* node_v       = (const float*)d_in[1];
    const float* node_attr    = (const float*)d_in[2];
    const float* edge_attr    = (const float*)d_in[3];
    const float* edge_scalars = (const float*)d_in[4];
    const float* W1_0 = (const float*)d_in[5];
    const float* W1_1 = (const float*)d_in[6];
    const float* Wfc1 = (const float*)d_in[7];
    const float* Wfc2 = (const float*)d_in[8];
    const float* W2_0 = (const float*)d_in[9];
    const float* W2_1 = (const float*)d_in[10];
    const float* Wsc0 = (const float*)d_in[11];
    const float* Wsc1 = (const float*)d_in[12];
    const int* edge_src = (const int*)d_in[13];
    const int* edge_dst = (const int*)d_in[14];

    // workspace layout (bytes), total ~38.8MB <= proven capacity
    char* ws = (char*)d_ws;
    unsigned short* xnode = (unsigned short*)(ws);              // N*128*2 = 7,680,000
    uint4* rec            = (uint4*)(ws + 7680000);             // E*32    = 15,360,000
    unsigned short* agg   = (unsigned short*)(ws + 23040000);   // N*256*2 = 15,360,000
    int* deg    = (int*)(ws + 38400000);                        // N*4
    int* offs   = (int*)(ws + 38520000);                        // (N+1)*4 pad
    int* cursor = (int*)(ws + 38640016);                        // N*4
    unsigned* bsc0 = (unsigned*)(ws + 38760064);                // 16,384
    unsigned* bsc1 = (unsigned*)(ws + 38776448);                // 16,384
    unsigned* b20  = (unsigned*)(ws + 38792832);                // 4,096
    unsigned* b21  = (unsigned*)(ws + 38796928);                // 4,096

    hipMemsetAsync(deg, 0, (size_t)N_NODES * sizeof(int), stream);
    k_pre<<<1879, 256, 0, stream>>>(node_s, node_v, W1_0, W1_1, Wsc0, Wsc1,
                                    W2_0, W2_1, edge_src, deg, xnode,
                                    bsc0, bsc1, b20, b21);
    scan_kernel<<<1, 1024, 0, stream>>>(deg, offs, cursor);
    fill_kernel<<<1875, 256, 0, stream>>>(edge_attr, edge_scalars, Wfc1,
                                          edge_src, edge_dst, cursor, rec);
    gather_kernel<<<7500, 256, 0, stream>>>(offs, rec, Wfc2, xnode, agg);
    k_post<<<1875, 256, 0, stream>>>(node_s, node_v, node_attr,
                                     bsc0, bsc1, b20, b21, agg, (float*)d_out);
}

// Round 9
// 236.705 us; speedup vs baseline: 2.4998x; 1.0173x over previous
//
#include <hip/hip_runtime.h>
#include <math.h>

#define N_NODES 30000
#define N_EDGES 480000

typedef __attribute__((ext_vector_type(8))) short short8;
typedef __attribute__((ext_vector_type(4))) float f32x4;
typedef __attribute__((ext_vector_type(2))) float f32x2;

__device__ __forceinline__ unsigned short f2bf(float f) {
    unsigned u = __float_as_uint(f);
    u += 0x7fff + ((u >> 16) & 1);          // RNE
    return (unsigned short)(u >> 16);
}
__device__ __forceinline__ float bfLO(unsigned v) { return __uint_as_float(v << 16); }
__device__ __forceinline__ float bfHI(unsigned v) { return __uint_as_float(v & 0xffff0000u); }
__device__ __forceinline__ unsigned packbf(float a, float b) {
    return (unsigned)f2bf(a) | ((unsigned)f2bf(b) << 16);
}
// truncation pack (products of bf16-exact values: err <= 2^-8, no carry chain)
__device__ __forceinline__ unsigned ptk(float a, float b) {
    return (__float_as_uint(a) >> 16) | (__float_as_uint(b) & 0xffff0000u);
}

union U8 { short8 v; unsigned u[4]; };
union C4 { f32x4 v; float f[4]; };

#define VE(A, B, C, idx) ((idx) < 4 ? (&(A).x)[(idx)] : (idx) < 8 ? (&(B).x)[(idx) - 4] : (&(C).x)[(idx) - 8])

// ---------------------------------------------------------------------------
// k_pre: blocks 0..1874: x-precompute (2 nodes/thread, float4 broadcast loads,
// bf16-packed W1 LDS) -> xnode bf16, + fused CSR degree count (256 edges/blk).
// Blocks 1875..1878: pack Wsc0/Wsc1/W2_0/W2_1 into MFMA B-fragment order.
// ---------------------------------------------------------------------------
__global__ __launch_bounds__(256) void k_pre(
    const float* __restrict__ node_s,   // (N,32)
    const float* __restrict__ node_v,   // (N,32,3)
    const float* __restrict__ W1_0,     // (32,32) [u][w]
    const float* __restrict__ W1_1,
    const float* __restrict__ Wsc0,     // (256,32)
    const float* __restrict__ Wsc1,
    const float* __restrict__ W2_0,     // (64,32)
    const float* __restrict__ W2_1,
    const int* __restrict__ edge_src,
    int* __restrict__ deg,
    unsigned short* __restrict__ xnode, // (N,128) bf16 packed
    unsigned* __restrict__ bsc0,        // 4096 uints
    unsigned* __restrict__ bsc1,
    unsigned* __restrict__ b20,         // 1024 uints
    unsigned* __restrict__ b21)
{
    __shared__ unsigned sW1p[1024];     // {W1_0,W1_1} bf16 pair at [u*32+w]
    int tid = threadIdx.x;

    if (blockIdx.x >= 1875) {
        int b = blockIdx.x - 1875;
        const float* Wm = (b == 0) ? Wsc0 : (b == 1) ? Wsc1 : (b == 2) ? W2_0 : W2_1;
        unsigned* dst = (b == 0) ? bsc0 : (b == 1) ? bsc1 : (b == 2) ? b20 : b21;
        float scale = (b < 2) ? 0.0625f : 0.03125f;  // exact pow2 folds
        int nu = (b < 2) ? 4096 : 1024;
        for (int idx = tid; idx < nu; idx += 256) {
            int jp = idx & 3;
            int lane = (idx >> 2) & 63;
            int ft = (idx >> 8) & 1;
            int kc = idx >> 9;
            int quad = lane >> 4, col = lane & 15;
            int k = kc * 32 + quad * 8 + jp * 2;
            int c = ft * 16 + col;
            dst[idx] = packbf(Wm[k * 32 + c] * scale, Wm[(k + 1) * 32 + c] * scale);
        }
        return;
    }

    atomicAdd(&deg[edge_src[blockIdx.x * 256 + tid]], 1);
    for (int i = tid; i < 1024; i += 256) sW1p[i] = packbf(W1_0[i], W1_1[i]);
    __syncthreads();

    int w = tid & 31;
    int n0 = blockIdx.x * 16 + (tid >> 5) * 2;   // 2 nodes per thread
    const float inv_m = 0.1767766953f;           // 1/sqrt(32)
    float x0[2] = {0.f, 0.f}, x1a[2] = {0.f, 0.f};
    float x1b[2] = {0.f, 0.f}, x1c[2] = {0.f, 0.f};

    for (int uc = 0; uc < 32; uc += 4) {
        float4 sv[2], v0[2], v1[2], v2[2];
#pragma unroll
        for (int j = 0; j < 2; ++j) {
            sv[j] = *(const float4*)(node_s + (size_t)(n0 + j) * 32 + uc);
            const float* vp = node_v + (size_t)(n0 + j) * 96 + uc * 3;
            v0[j] = *(const float4*)(vp);
            v1[j] = *(const float4*)(vp + 4);
            v2[j] = *(const float4*)(vp + 8);
        }
#pragma unroll
        for (int kk = 0; kk < 4; ++kk) {
            int u = uc + kk;
            unsigned wp = sW1p[u * 32 + w];
            float w0k = bfLO(wp), w1k = bfHI(wp);
#pragma unroll
            for (int j = 0; j < 2; ++j) {
                float s  = (&sv[j].x)[kk];
                float vx = VE(v0[j], v1[j], v2[j], kk * 3 + 0);
                float vy = VE(v0[j], v1[j], v2[j], kk * 3 + 1);
                float vz = VE(v0[j], v1[j], v2[j], kk * 3 + 2);
                x0[j]  = fmaf(s,  w0k, x0[j]);
                x1a[j] = fmaf(vx, w1k, x1a[j]);
                x1b[j] = fmaf(vy, w1k, x1b[j]);
                x1c[j] = fmaf(vz, w1k, x1c[j]);
            }
        }
    }
#pragma unroll
    for (int j = 0; j < 2; ++j) {
        uint2 pk;
        pk.x = packbf(x0[j] * inv_m, x1a[j] * inv_m);
        pk.y = packbf(x1b[j] * inv_m, x1c[j] * inv_m);
        *(uint2*)(xnode + (size_t)(n0 + j) * 128 + w * 4) = pk;
    }
}

// ---------------------------------------------------------------------------
// scan: single-block exclusive prefix over deg, LDS-staged.
// ---------------------------------------------------------------------------
__global__ __launch_bounds__(1024) void scan_kernel(const int* __restrict__ deg,
                                                    int* __restrict__ offs,
                                                    int* __restrict__ cursor) {
    __shared__ int sdeg[N_NODES];
    __shared__ int wsum[16];
    int tid = threadIdx.x;
#pragma unroll
    for (int k = 0; k < 30; ++k) {
        int idx = k * 1024 + tid;
        if (idx < N_NODES) sdeg[idx] = deg[idx];
    }
    __syncthreads();
    int base = tid * 30;
    int s = 0;
    if (base < N_NODES) {
#pragma unroll
        for (int k = 0; k < 30; ++k) s += sdeg[base + k];
    }
    int lane = tid & 63, wid = tid >> 6;
    int inc = s;
#pragma unroll
    for (int d = 1; d < 64; d <<= 1) {
        int o = __shfl_up(inc, d, 64);
        if (lane >= d) inc += o;
    }
    if (lane == 63) wsum[wid] = inc;
    __syncthreads();
    if (tid < 16) {
        int v = wsum[tid];
        int t = v;
#pragma unroll
        for (int d = 1; d < 16; d <<= 1) {
            int o = __shfl_up(t, d, 64);
            if (tid >= d) t += o;
        }
        wsum[tid] = t - v;
    }
    __syncthreads();
    int run = inc - s + wsum[wid];
    if (base < N_NODES) {
#pragma unroll
        for (int k = 0; k < 30; ++k) {
            int n = base + k;
            int d = sdeg[n];
            sdeg[n] = run;
            run += d;
        }
    }
    __syncthreads();
#pragma unroll
    for (int k = 0; k < 30; ++k) {
        int idx = k * 1024 + tid;
        if (idx < N_NODES) {
            int v = sdeg[idx];
            offs[idx] = v;
            cursor[idx] = v;
        }
    }
    if (tid == 0) offs[N_NODES] = N_EDGES;
}

// ---------------------------------------------------------------------------
// fill: per-edge radial MLP h = ssp(es@Wfc1/sqrt(8)); writes ONE 32B record
// per edge at its CSR slot: {h[8] bf16 | ea[4] bf16, dst, pad}.
// ---------------------------------------------------------------------------
__global__ __launch_bounds__(256) void fill_kernel(
    const float* __restrict__ edge_attr,     // (E,4)
    const float* __restrict__ edge_scalars,  // (E,8)
    const float* __restrict__ Wfc1,          // (8,8) [k][i]
    const int* __restrict__ edge_src,
    const int* __restrict__ edge_dst,
    int* __restrict__ cursor,
    uint4* __restrict__ rec)                 // (E,2) uint4
{
    __shared__ float sW[64];
    int tid = threadIdx.x;
    if (tid < 64) sW[tid] = Wfc1[tid];
    __syncthreads();

    int e = blockIdx.x * 256 + tid;
    float4 es0 = *(const float4*)(edge_scalars + (size_t)e * 8);
    float4 es1 = *(const float4*)(edge_scalars + (size_t)e * 8 + 4);
    float4 ea  = *(const float4*)(edge_attr + (size_t)e * 4);
    int src = edge_src[e];
    int dst = edge_dst[e];
    int pos = atomicAdd(&cursor[src], 1);

    const float inv8 = 0.3535533906f;
    float h[8];
#pragma unroll
    for (int i = 0; i < 8; ++i) {
        float acc = es0.x * sW[0 * 8 + i];
        acc = fmaf(es0.y, sW[1 * 8 + i], acc);
        acc = fmaf(es0.z, sW[2 * 8 + i], acc);
        acc = fmaf(es0.w, sW[3 * 8 + i], acc);
        acc = fmaf(es1.x, sW[4 * 8 + i], acc);
        acc = fmaf(es1.y, sW[5 * 8 + i], acc);
        acc = fmaf(es1.z, sW[6 * 8 + i], acc);
        acc = fmaf(es1.w, sW[7 * 8 + i], acc);
        acc *= inv8;
        float ax = fabsf(acc);
        float tt = __expf(-ax);
        h[i] = fmaxf(acc, 0.f) + __logf(1.f + tt) - 0.6931471806f;
    }
    uint4 r0, r1;
    r0.x = packbf(h[0], h[1]); r0.y = packbf(h[2], h[3]);
    r0.z = packbf(h[4], h[5]); r0.w = packbf(h[6], h[7]);
    r1.x = packbf(ea.x, ea.y); r1.y = packbf(ea.z, ea.w);
    r1.z = (unsigned)dst; r1.w = 0;
    rec[2 * pos]     = r0;
    rec[2 * pos + 1] = r1;
}

// ---------------------------------------------------------------------------
// k_main: fused gather + output GEMMs. 16 nodes per block (grid 1875).
// Phase 1: each of 4 waves gathers 4 nodes (half-wave per edge, records
//   stream in CSR order, xnode the only random load, pk-fma for h@Wfc2),
//   writing bf16 agg rows to LDS (no global agg round-trip).
// Phase 2 (after one barrier): wave 0 = scalar out-tile, waves 1-3 = vector
//   out-tiles. W2 GEMM (K=64, A = ds_read_b128 from LDS agg) + self-connection
//   GEMM (K=256, A = staged node_s/node_v * attr) into the same MFMA
//   accumulators; plain f32 store.
// ---------------------------------------------------------------------------
__global__ __launch_bounds__(256) void k_main(
    const int* __restrict__ offs,
    const uint4* __restrict__ rec,           // (E,2)
    const float* __restrict__ Wfc2,          // (8,128)
    const unsigned short* __restrict__ xnode,
    const float* __restrict__ node_s,        // (N,32)
    const float* __restrict__ node_v,        // (N,32,3)
    const float* __restrict__ node_attr,     // (N,8)
    const unsigned* __restrict__ bsc0,
    const unsigned* __restrict__ bsc1,
    const unsigned* __restrict__ b20,
    const unsigned* __restrict__ b21,
    float* __restrict__ out)                 // (N,128)
{
    __shared__ float sS[16 * 33];            // node_s staged [nl][u]
    __shared__ float sV[16 * 100];           // node_v staged [nl][u*3+d]
    __shared__ unsigned short sAgg[16 * 264];// agg rows [nl][ch], pad 8
    int tid = threadIdx.x;
    int lane = tid & 63;
    int u = lane & 31;
    int half = lane >> 5;
    int wv = tid >> 6;
    int nbase = blockIdx.x * 16;

    // stage node_s / node_v for the block's 16 nodes (used in phase 2)
    for (int i = tid; i < 512; i += 256)
        sS[(i >> 5) * 33 + (i & 31)] = node_s[(size_t)nbase * 32 + i];
    for (int i = tid; i < 1536; i += 256)
        sV[(i / 96) * 100 + (i % 96)] = node_v[(size_t)nbase * 96 + i];

    // ---- phase 1: gather 4 nodes per wave ----
    const float inv8 = 0.3535533906f;
    const float inv_s3 = 0.5773502692f;
    f32x2 wfA[8], wfB[8];
#pragma unroll
    for (int i = 0; i < 8; ++i) {
        wfA[i].x = Wfc2[i * 128 + u] * inv8;
        wfA[i].y = Wfc2[i * 128 + 32 + u] * inv8;
        wfB[i].x = Wfc2[i * 128 + 64 + u] * inv8;
        wfB[i].y = Wfc2[i * 128 + 96 + u] * inv8 * inv_s3;
    }

    for (int jn = 0; jn < 4; ++jn) {
        int nl = wv * 4 + jn;
        int node = nbase + nl;
        int beg = offs[node], end = offs[node + 1];
        float a_sa = 0.f, a_sb = 0.f;
        float a_va0 = 0.f, a_va1 = 0.f, a_va2 = 0.f;
        float a_vb0 = 0.f, a_vb1 = 0.f, a_vb2 = 0.f;

        if (end > beg) {
            int last = end - 1;
            int i = beg + half;
            int p = min(i, last);
            uint4 a0 = rec[2 * p], a1 = rec[2 * p + 1];
            p = min(i + 2, last);
            uint4 b0 = rec[2 * p], b1 = rec[2 * p + 1];
            p = min(i + 4, last);
            uint4 c0 = rec[2 * p], c1 = rec[2 * p + 1];
            uint2 xA = *(const uint2*)(xnode + (size_t)(int)a1.z * 128 + u * 4);
            uint2 xB = *(const uint2*)(xnode + (size_t)(int)b1.z * 128 + u * 4);

            for (; i < end; i += 2) {
                int pD = min(i + 6, last);
                uint4 d0 = rec[2 * pD], d1 = rec[2 * pD + 1];
                uint2 xC = *(const uint2*)(xnode + (size_t)(int)c1.z * 128 + u * 4);

                float hv[8];
                hv[0] = bfLO(a0.x); hv[1] = bfHI(a0.x);
                hv[2] = bfLO(a0.y); hv[3] = bfHI(a0.y);
                hv[4] = bfLO(a0.z); hv[5] = bfHI(a0.z);
                hv[6] = bfLO(a0.w); hv[7] = bfHI(a0.w);
                f32x2 aA = {0.f, 0.f}, aB = {0.f, 0.f};
#pragma unroll
                for (int q = 0; q < 8; ++q) {
                    f32x2 hh = {hv[q], hv[q]};
                    aA = __builtin_elementwise_fma(hh, wfA[q], aA);
                    aB = __builtin_elementwise_fma(hh, wfB[q], aB);
                }
                float a00 = aA.x, a01 = aA.y, a10 = aB.x, a11 = aB.y;

                float sh0 = bfLO(a1.x), s1xe = bfHI(a1.x);
                float s1ye = bfLO(a1.y), s1ze = bfHI(a1.y);
                float x0 = bfLO(xA.x), xd0 = bfHI(xA.x);
                float xd1 = bfLO(xA.y), xd2 = bfHI(xA.y);

                float dot = xd0 * s1xe + xd1 * s1ye + xd2 * s1ze;
                a_sa = fmaf(a00 * sh0, x0, a_sa);
                a_sb = fmaf(a11, dot, a_sb);
                float w01x0 = a01 * x0;
                a_va0 = fmaf(w01x0, s1xe, a_va0);
                a_va1 = fmaf(w01x0, s1ye, a_va1);
                a_va2 = fmaf(w01x0, s1ze, a_va2);
                float t10 = a10 * sh0;
                a_vb0 = fmaf(t10, xd0, a_vb0);
                a_vb1 = fmaf(t10, xd1, a_vb1);
                a_vb2 = fmaf(t10, xd2, a_vb2);

                a0 = b0; a1 = b1; xA = xB;
                b0 = c0; b1 = c1; xB = xC;
                c0 = d0; c1 = d1;
            }
        }
        a_sa  += __shfl_xor(a_sa, 32, 64);
        a_sb  += __shfl_xor(a_sb, 32, 64);
        a_va0 += __shfl_xor(a_va0, 32, 64);
        a_va1 += __shfl_xor(a_va1, 32, 64);
        a_va2 += __shfl_xor(a_va2, 32, 64);
        a_vb0 += __shfl_xor(a_vb0, 32, 64);
        a_vb1 += __shfl_xor(a_vb1, 32, 64);
        a_vb2 += __shfl_xor(a_vb2, 32, 64);

        unsigned short* ap = sAgg + nl * 264;
        if (half == 0) {
            ap[u]       = f2bf(a_sa);
            ap[32 + u]  = f2bf(a_sb);
            ap[64 + u]  = f2bf(a_va0);
            ap[96 + u]  = f2bf(a_vb0);
        } else {
            ap[128 + u] = f2bf(a_va1);
            ap[160 + u] = f2bf(a_vb1);
            ap[192 + u] = f2bf(a_va2);
            ap[224 + u] = f2bf(a_vb2);
        }
    }
    __syncthreads();

    // ---- phase 2: MFMA output ----
    int col = lane & 15;
    int quad = lane >> 4;
    int m = col;
    bool is_s = (wv == 0);
    int sub = wv - 1;                        // v-waves: 0..2

    const short* Bs = (const short*)(is_s ? bsc0 : bsc1);
    const short* B2 = (const short*)(is_s ? b20 : b21);

    // A-row mapping for this lane's row m
    int aBase, fbase, fstep, n_a;
    if (is_s) {
        aBase = m * 264;                     // agg_s channels 0..63
        fbase = m * 33;
        fstep = 1;
        n_a = nbase + m;
    } else {
        int r16 = 16 * sub + m;              // local v-row 0..47
        int nl = r16 / 3;
        int dd = r16 - nl * 3;
        aBase = nl * 264 + 64 + 64 * dd;
        fbase = nl * 100 + dd;
        fstep = 3;
        n_a = nbase + nl;
    }
    float4 A0 = *(const float4*)(node_attr + (size_t)n_a * 8);
    float4 A1 = *(const float4*)(node_attr + (size_t)n_a * 8 + 4);
    float aa0 = A0.x, aa1 = A0.y, aa2 = A0.z, aa3 = A0.w;
    float aa4 = A1.x, aa5 = A1.y, aa6 = A1.z, aa7 = A1.w;

    f32x4 acc0 = {0.f, 0.f, 0.f, 0.f};
    f32x4 acc1 = {0.f, 0.f, 0.f, 0.f};

    // W2 GEMM: K=64, A from LDS agg
#pragma unroll
    for (int kc = 0; kc < 2; ++kc) {
        short8 af = *(const short8*)((const short*)sAgg + aBase + kc * 32 + quad * 8);
        short8 bf0 = *(const short8*)(B2 + ((kc * 2 + 0) * 64 + lane) * 8);
        short8 bf1 = *(const short8*)(B2 + ((kc * 2 + 1) * 64 + lane) * 8);
        acc0 = __builtin_amdgcn_mfma_f32_16x16x32_bf16(af, bf0, acc0, 0, 0, 0);
        acc1 = __builtin_amdgcn_mfma_f32_16x16x32_bf16(af, bf1, acc1, 0, 0, 0);
    }
    // self-connection GEMM: K=256
    const float* Sf = is_s ? sS : sV;
#pragma unroll
    for (int kc = 0; kc < 8; ++kc) {
        int uu = kc * 4 + quad;
        float f = Sf[fbase + uu * fstep];
        U8 af;
        af.u[0] = ptk(f * aa0, f * aa1);
        af.u[1] = ptk(f * aa2, f * aa3);
        af.u[2] = ptk(f * aa4, f * aa5);
        af.u[3] = ptk(f * aa6, f * aa7);
        short8 bf0 = *(const short8*)(Bs + ((kc * 2 + 0) * 64 + lane) * 8);
        short8 bf1 = *(const short8*)(Bs + ((kc * 2 + 1) * 64 + lane) * 8);
        acc0 = __builtin_amdgcn_mfma_f32_16x16x32_bf16(af.v, bf0, acc0, 0, 0, 0);
        acc1 = __builtin_amdgcn_mfma_f32_16x16x32_bf16(af.v, bf1, acc1, 0, 0, 0);
    }

    // epilogue
    C4 c0, c1;
    c0.v = acc0; c1.v = acc1;
    if (is_s) {
#pragma unroll
        for (int r = 0; r < 4; ++r) {
            int n = nbase + (quad << 2) + r;
            out[(size_t)n * 128 + col]      = c0.f[r];
            out[(size_t)n * 128 + col + 16] = c1.f[r];
        }
    } else {
#pragma unroll
        for (int r = 0; r < 4; ++r) {
            int rl = 16 * sub + (quad << 2) + r;   // local v-row 0..47
            int nn = rl / 3;
            int dd = rl - nn * 3;
            int n = nbase + nn;
            out[(size_t)n * 128 + 32 + 3 * col + dd]        = c0.f[r];
            out[(size_t)n * 128 + 32 + 3 * (col + 16) + dd] = c1.f[r];
        }
    }
}

extern "C" void kernel_launch(void* const* d_in, const int* in_sizes, int n_in,
                              void* d_out, int out_size, void* d_ws, size_t ws_size,
                              hipStream_t stream) {
    const float* node_s       = (const float*)d_in[0];
    const float* node_v       = (const float*)d_in[1];
    const float* node_attr    = (const float*)d_in[2];
    const float* edge_attr    = (const float*)d_in[3];
    const float* edge_scalars = (const float*)d_in[4];
    const float* W1_0 = (const float*)d_in[5];
    const float* W1_1 = (const float*)d_in[6];
    const float* Wfc1 = (const float*)d_in[7];
    const float* Wfc2 = (const float*)d_in[8];
    const float* W2_0 = (const float*)d_in[9];
    const float* W2_1 = (const float*)d_in[10];
    const float* Wsc0 = (const float*)d_in[11];
    const float* Wsc1 = (const float*)d_in[12];
    const int* edge_src = (const int*)d_in[13];
    const int* edge_dst = (const int*)d_in[14];

    // workspace layout (bytes), total ~23.4MB (agg eliminated)
    char* ws = (char*)d_ws;
    unsigned short* xnode = (unsigned short*)(ws);              // N*128*2 = 7,680,000
    uint4* rec            = (uint4*)(ws + 7680000);             // E*32    = 15,360,000
    int* deg    = (int*)(ws + 23040000);                        // N*4
    int* offs   = (int*)(ws + 23160000);                        // (N+1)*4 pad
    int* cursor = (int*)(ws + 23280016);                        // N*4
    unsigned* bsc0 = (unsigned*)(ws + 23400064);                // 16,384
    unsigned* bsc1 = (unsigned*)(ws + 23416448);                // 16,384
    unsigned* b20  = (unsigned*)(ws + 23432832);                // 4,096
    unsigned* b21  = (unsigned*)(ws + 23436928);                // 4,096

    hipMemsetAsync(deg, 0, (size_t)N_NODES * sizeof(int), stream);
    k_pre<<<1879, 256, 0, stream>>>(node_s, node_v, W1_0, W1_1, Wsc0, Wsc1,
                                    W2_0, W2_1, edge_src, deg, xnode,
                                    bsc0, bsc1, b20, b21);
    scan_kernel<<<1, 1024, 0, stream>>>(deg, offs, cursor);
    fill_kernel<<<1875, 256, 0, stream>>>(edge_attr, edge_scalars, Wfc1,
                                          edge_src, edge_dst, cursor, rec);
    k_main<<<1875, 256, 0, stream>>>(offs, rec, Wfc2, xnode,
                                     node_s, node_v, node_attr,
                                     bsc0, bsc1, b20, b21, (float*)d_out);
}

// Round 10
// 229.519 us; speedup vs baseline: 2.5781x; 1.0313x over previous
//
#include <hip/hip_runtime.h>
#include <math.h>

#define N_NODES 30000
#define N_EDGES 480000

typedef __attribute__((ext_vector_type(8))) short short8;
typedef __attribute__((ext_vector_type(4))) float f32x4;
typedef __attribute__((ext_vector_type(2))) float f32x2;

__device__ __forceinline__ unsigned short f2bf(float f) {
    unsigned u = __float_as_uint(f);
    u += 0x7fff + ((u >> 16) & 1);          // RNE
    return (unsigned short)(u >> 16);
}
__device__ __forceinline__ float bfLO(unsigned v) { return __uint_as_float(v << 16); }
__device__ __forceinline__ float bfHI(unsigned v) { return __uint_as_float(v & 0xffff0000u); }
__device__ __forceinline__ unsigned packbf(float a, float b) {
    return (unsigned)f2bf(a) | ((unsigned)f2bf(b) << 16);
}
// truncation pack (products of bf16-exact values: err <= 2^-8, no carry chain)
__device__ __forceinline__ unsigned ptk(float a, float b) {
    return (__float_as_uint(a) >> 16) | (__float_as_uint(b) & 0xffff0000u);
}

union U8 { short8 v; unsigned u[4]; };
union C4 { f32x4 v; float f[4]; };

// ---------------------------------------------------------------------------
// k_pre: blocks 0..1874 (16 nodes each): x-precompute as MFMA GEMM
//   x0 = s @ W1_0 (wave0), x1_d = v_d @ W1_1 (waves 1-3), K=32 -> 2 MFMAs/wave.
//   C staged through LDS so xnode's interleaved {x0,x1x,x1y,x1z} uint2 writes
//   are coalesced. Fused CSR degree count (256 edges/block, grid = E/256).
// Blocks 1875..1878: pack Wsc0/Wsc1/W2_0/W2_1 into MFMA B-fragment order.
// ---------------------------------------------------------------------------
__global__ __launch_bounds__(256) void k_pre(
    const float* __restrict__ node_s,   // (N,32)
    const float* __restrict__ node_v,   // (N,32,3)
    const float* __restrict__ W1_0,     // (32,32) [u][w]
    const float* __restrict__ W1_1,
    const float* __restrict__ Wsc0,     // (256,32)
    const float* __restrict__ Wsc1,
    const float* __restrict__ W2_0,     // (64,32)
    const float* __restrict__ W2_1,
    const int* __restrict__ edge_src,
    int* __restrict__ deg,
    unsigned short* __restrict__ xnode, // (N,128) bf16 packed
    unsigned* __restrict__ bsc0,        // 4096 uints
    unsigned* __restrict__ bsc1,
    unsigned* __restrict__ b20,         // 1024 uints
    unsigned* __restrict__ b21)
{
    __shared__ float sVT[16 * 100];     // [nl][d*32+u]
    __shared__ float sXo[16 * 140];     // [nl][p*34+w], p=0:x0, 1+d:x1_d
    int tid = threadIdx.x;

    if (blockIdx.x >= 1875) {
        int b = blockIdx.x - 1875;
        const float* Wm = (b == 0) ? Wsc0 : (b == 1) ? Wsc1 : (b == 2) ? W2_0 : W2_1;
        unsigned* dst = (b == 0) ? bsc0 : (b == 1) ? bsc1 : (b == 2) ? b20 : b21;
        float scale = (b < 2) ? 0.0625f : 0.03125f;  // exact pow2 folds
        int nu = (b < 2) ? 4096 : 1024;
        for (int idx = tid; idx < nu; idx += 256) {
            int jp = idx & 3;
            int lane = (idx >> 2) & 63;
            int ft = (idx >> 8) & 1;
            int kc = idx >> 9;
            int quad = lane >> 4, col = lane & 15;
            int k = kc * 32 + quad * 8 + jp * 2;
            int c = ft * 16 + col;
            dst[idx] = packbf(Wm[k * 32 + c] * scale, Wm[(k + 1) * 32 + c] * scale);
        }
        return;
    }

    atomicAdd(&deg[edge_src[blockIdx.x * 256 + tid]], 1);

    int nbase = blockIdx.x * 16;
    // stage node_v transposed: sVT[nl][d*32+u]
    for (int i = tid; i < 1536; i += 256) {
        int nl = i / 96, r = i - nl * 96;
        int u = r / 3, d = r - u * 3;
        sVT[nl * 100 + d * 32 + u] = node_v[(size_t)nbase * 96 + i];
    }
    __syncthreads();

    int lane = tid & 63;
    int wv = tid >> 6;
    int col = lane & 15, quad = lane >> 4, m = lane & 15;

    // B fragments from W1 (scale applied at pack stage)
    const float* W1 = (wv == 0) ? W1_0 : W1_1;
    U8 bf0, bf1;
#pragma unroll
    for (int p = 0; p < 4; ++p) {
        int k = quad * 8 + 2 * p;
        bf0.u[p] = packbf(W1[k * 32 + col],      W1[(k + 1) * 32 + col]);
        bf1.u[p] = packbf(W1[k * 32 + col + 16], W1[(k + 1) * 32 + col + 16]);
    }

    // A fragment (K=32 covered by one MFMA)
    U8 af;
    if (wv == 0) {
        const float* sp = node_s + (size_t)(nbase + m) * 32 + quad * 8;
        float4 a0 = *(const float4*)(sp);
        float4 a1 = *(const float4*)(sp + 4);
        af.u[0] = packbf(a0.x, a0.y); af.u[1] = packbf(a0.z, a0.w);
        af.u[2] = packbf(a1.x, a1.y); af.u[3] = packbf(a1.z, a1.w);
    } else {
        int R = 16 * (wv - 1) + m;
        int nl = R / 3, d = R - nl * 3;
        const float* vp = sVT + nl * 100 + d * 32 + quad * 8;
        af.u[0] = packbf(vp[0], vp[1]); af.u[1] = packbf(vp[2], vp[3]);
        af.u[2] = packbf(vp[4], vp[5]); af.u[3] = packbf(vp[6], vp[7]);
    }

    f32x4 acc0 = {0.f, 0.f, 0.f, 0.f};
    f32x4 acc1 = {0.f, 0.f, 0.f, 0.f};
    acc0 = __builtin_amdgcn_mfma_f32_16x16x32_bf16(af.v, bf0.v, acc0, 0, 0, 0);
    acc1 = __builtin_amdgcn_mfma_f32_16x16x32_bf16(af.v, bf1.v, acc1, 0, 0, 0);

    C4 c0, c1;
    c0.v = acc0; c1.v = acc1;
    if (wv == 0) {
#pragma unroll
        for (int r = 0; r < 4; ++r) {
            int nl = (quad << 2) + r;
            sXo[nl * 140 + col]      = c0.f[r];
            sXo[nl * 140 + col + 16] = c1.f[r];
        }
    } else {
#pragma unroll
        for (int r = 0; r < 4; ++r) {
            int R = 16 * (wv - 1) + (quad << 2) + r;
            int nl = R / 3, d = R - nl * 3;
            sXo[nl * 140 + (1 + d) * 34 + col]      = c0.f[r];
            sXo[nl * 140 + (1 + d) * 34 + col + 16] = c1.f[r];
        }
    }
    __syncthreads();

    const float inv_m = 0.1767766953f;  // 1/sqrt(32)
    for (int i = tid; i < 512; i += 256) {
        int nl = i >> 5, u = i & 31;
        const float* xp = sXo + nl * 140;
        uint2 pk;
        pk.x = packbf(xp[u] * inv_m,       xp[34 + u] * inv_m);
        pk.y = packbf(xp[68 + u] * inv_m,  xp[102 + u] * inv_m);
        *(uint2*)(xnode + (size_t)(nbase + nl) * 128 + u * 4) = pk;
    }
}

// ---------------------------------------------------------------------------
// scan: single-block exclusive prefix over deg, LDS-staged.
// ---------------------------------------------------------------------------
__global__ __launch_bounds__(1024) void scan_kernel(const int* __restrict__ deg,
                                                    int* __restrict__ offs,
                                                    int* __restrict__ cursor) {
    __shared__ int sdeg[N_NODES];
    __shared__ int wsum[16];
    int tid = threadIdx.x;
#pragma unroll
    for (int k = 0; k < 30; ++k) {
        int idx = k * 1024 + tid;
        if (idx < N_NODES) sdeg[idx] = deg[idx];
    }
    __syncthreads();
    int base = tid * 30;
    int s = 0;
    if (base < N_NODES) {
#pragma unroll
        for (int k = 0; k < 30; ++k) s += sdeg[base + k];
    }
    int lane = tid & 63, wid = tid >> 6;
    int inc = s;
#pragma unroll
    for (int d = 1; d < 64; d <<= 1) {
        int o = __shfl_up(inc, d, 64);
        if (lane >= d) inc += o;
    }
    if (lane == 63) wsum[wid] = inc;
    __syncthreads();
    if (tid < 16) {
        int v = wsum[tid];
        int t = v;
#pragma unroll
        for (int d = 1; d < 16; d <<= 1) {
            int o = __shfl_up(t, d, 64);
            if (tid >= d) t += o;
        }
        wsum[tid] = t - v;
    }
    __syncthreads();
    int run = inc - s + wsum[wid];
    if (base < N_NODES) {
#pragma unroll
        for (int k = 0; k < 30; ++k) {
            int n = base + k;
            int d = sdeg[n];
            sdeg[n] = run;
            run += d;
        }
    }
    __syncthreads();
#pragma unroll
    for (int k = 0; k < 30; ++k) {
        int idx = k * 1024 + tid;
        if (idx < N_NODES) {
            int v = sdeg[idx];
            offs[idx] = v;
            cursor[idx] = v;
        }
    }
    if (tid == 0) offs[N_NODES] = N_EDGES;
}

// ---------------------------------------------------------------------------
// fill: per-edge radial MLP h = ssp(es@Wfc1/sqrt(8)); writes ONE 32B record
// per edge at its CSR slot: {h[8] bf16 | ea[4] bf16, dst, pad}.
// ---------------------------------------------------------------------------
__global__ __launch_bounds__(256) void fill_kernel(
    const float* __restrict__ edge_attr,     // (E,4)
    const float* __restrict__ edge_scalars,  // (E,8)
    const float* __restrict__ Wfc1,          // (8,8) [k][i]
    const int* __restrict__ edge_src,
    const int* __restrict__ edge_dst,
    int* __restrict__ cursor,
    uint4* __restrict__ rec)                 // (E,2) uint4
{
    __shared__ float sW[64];
    int tid = threadIdx.x;
    if (tid < 64) sW[tid] = Wfc1[tid];
    __syncthreads();

    int e = blockIdx.x * 256 + tid;
    float4 es0 = *(const float4*)(edge_scalars + (size_t)e * 8);
    float4 es1 = *(const float4*)(edge_scalars + (size_t)e * 8 + 4);
    float4 ea  = *(const float4*)(edge_attr + (size_t)e * 4);
    int src = edge_src[e];
    int dst = edge_dst[e];
    int pos = atomicAdd(&cursor[src], 1);

    const float inv8 = 0.3535533906f;
    float h[8];
#pragma unroll
    for (int i = 0; i < 8; ++i) {
        float acc = es0.x * sW[0 * 8 + i];
        acc = fmaf(es0.y, sW[1 * 8 + i], acc);
        acc = fmaf(es0.z, sW[2 * 8 + i], acc);
        acc = fmaf(es0.w, sW[3 * 8 + i], acc);
        acc = fmaf(es1.x, sW[4 * 8 + i], acc);
        acc = fmaf(es1.y, sW[5 * 8 + i], acc);
        acc = fmaf(es1.z, sW[6 * 8 + i], acc);
        acc = fmaf(es1.w, sW[7 * 8 + i], acc);
        acc *= inv8;
        float ax = fabsf(acc);
        float tt = __expf(-ax);
        h[i] = fmaxf(acc, 0.f) + __logf(1.f + tt) - 0.6931471806f;
    }
    uint4 r0, r1;
    r0.x = packbf(h[0], h[1]); r0.y = packbf(h[2], h[3]);
    r0.z = packbf(h[4], h[5]); r0.w = packbf(h[6], h[7]);
    r1.x = packbf(ea.x, ea.y); r1.y = packbf(ea.z, ea.w);
    r1.z = (unsigned)dst; r1.w = 0;
    rec[2 * pos]     = r0;
    rec[2 * pos + 1] = r1;
}

// ---------------------------------------------------------------------------
// k_main: fused gather + output GEMMs. 16 nodes per block (grid 1875).
// Phase 1: 4 waves gather 4 nodes each (records stream in CSR order, xnode
//   the only random load, pk-fma math), bf16 agg rows -> LDS.
// Phase 2: wave0 = scalar out-tile, waves 1-3 = vector out-tiles; W2 GEMM
//   (K=64, A from LDS agg) + self-connection GEMM (K=256) into the same
//   accumulators; plain f32 store.
// ---------------------------------------------------------------------------
__global__ __launch_bounds__(256) void k_main(
    const int* __restrict__ offs,
    const uint4* __restrict__ rec,           // (E,2)
    const float* __restrict__ Wfc2,          // (8,128)
    const unsigned short* __restrict__ xnode,
    const float* __restrict__ node_s,        // (N,32)
    const float* __restrict__ node_v,        // (N,32,3)
    const float* __restrict__ node_attr,     // (N,8)
    const unsigned* __restrict__ bsc0,
    const unsigned* __restrict__ bsc1,
    const unsigned* __restrict__ b20,
    const unsigned* __restrict__ b21,
    float* __restrict__ out)                 // (N,128)
{
    __shared__ float sS[16 * 33];            // node_s staged [nl][u]
    __shared__ float sV[16 * 100];           // node_v staged [nl][u*3+d]
    __shared__ unsigned short sAgg[16 * 264];// agg rows [nl][ch], pad 8
    int tid = threadIdx.x;
    int lane = tid & 63;
    int u = lane & 31;
    int half = lane >> 5;
    int wv = tid >> 6;
    int nbase = blockIdx.x * 16;

    for (int i = tid; i < 512; i += 256)
        sS[(i >> 5) * 33 + (i & 31)] = node_s[(size_t)nbase * 32 + i];
    for (int i = tid; i < 1536; i += 256)
        sV[(i / 96) * 100 + (i % 96)] = node_v[(size_t)nbase * 96 + i];

    // ---- phase 1 ----
    const float inv8 = 0.3535533906f;
    const float inv_s3 = 0.5773502692f;
    f32x2 wfA[8], wfB[8];
#pragma unroll
    for (int i = 0; i < 8; ++i) {
        wfA[i].x = Wfc2[i * 128 + u] * inv8;
        wfA[i].y = Wfc2[i * 128 + 32 + u] * inv8;
        wfB[i].x = Wfc2[i * 128 + 64 + u] * inv8;
        wfB[i].y = Wfc2[i * 128 + 96 + u] * inv8 * inv_s3;
    }

    for (int jn = 0; jn < 4; ++jn) {
        int nl = wv * 4 + jn;
        int node = nbase + nl;
        int beg = offs[node], end = offs[node + 1];
        float a_sa = 0.f, a_sb = 0.f;
        f32x2 a_va01 = {0.f, 0.f}, a_vb01 = {0.f, 0.f};
        float a_va2 = 0.f, a_vb2 = 0.f;

        if (end > beg) {
            int last = end - 1;
            int i = beg + half;
            int p = min(i, last);
            uint4 a0 = rec[2 * p], a1 = rec[2 * p + 1];
            p = min(i + 2, last);
            uint4 b0 = rec[2 * p], b1 = rec[2 * p + 1];
            p = min(i + 4, last);
            uint4 c0 = rec[2 * p], c1 = rec[2 * p + 1];
            uint2 xA = *(const uint2*)(xnode + (size_t)(int)a1.z * 128 + u * 4);
            uint2 xB = *(const uint2*)(xnode + (size_t)(int)b1.z * 128 + u * 4);

            for (; i < end; i += 2) {
                int pD = min(i + 6, last);
                uint4 d0 = rec[2 * pD], d1 = rec[2 * pD + 1];
                uint2 xC = *(const uint2*)(xnode + (size_t)(int)c1.z * 128 + u * 4);

                float hv[8];
                hv[0] = bfLO(a0.x); hv[1] = bfHI(a0.x);
                hv[2] = bfLO(a0.y); hv[3] = bfHI(a0.y);
                hv[4] = bfLO(a0.z); hv[5] = bfHI(a0.z);
                hv[6] = bfLO(a0.w); hv[7] = bfHI(a0.w);
                f32x2 aA = {0.f, 0.f}, aB = {0.f, 0.f};
#pragma unroll
                for (int q = 0; q < 8; ++q) {
                    f32x2 hh = {hv[q], hv[q]};
                    aA = __builtin_elementwise_fma(hh, wfA[q], aA);
                    aB = __builtin_elementwise_fma(hh, wfB[q], aB);
                }
                float a00 = aA.x, a01 = aA.y, a10 = aB.x, a11 = aB.y;

                float sh0 = bfLO(a1.x), s1xe = bfHI(a1.x);
                float s1ye = bfLO(a1.y), s1ze = bfHI(a1.y);
                float x0 = bfLO(xA.x), xd0 = bfHI(xA.x);
                float xd1 = bfLO(xA.y), xd2 = bfHI(xA.y);

                float dot = xd0 * s1xe + xd1 * s1ye + xd2 * s1ze;
                a_sa = fmaf(a00 * sh0, x0, a_sa);
                a_sb = fmaf(a11, dot, a_sb);
                float w01x0 = a01 * x0;
                float t10 = a10 * sh0;
                f32x2 wb = {w01x0, w01x0};
                f32x2 tb = {t10, t10};
                f32x2 s01 = {s1xe, s1ye};
                f32x2 xd01 = {xd0, xd1};
                a_va01 = __builtin_elementwise_fma(wb, s01, a_va01);
                a_vb01 = __builtin_elementwise_fma(tb, xd01, a_vb01);
                a_va2 = fmaf(w01x0, s1ze, a_va2);
                a_vb2 = fmaf(t10, xd2, a_vb2);

                a0 = b0; a1 = b1; xA = xB;
                b0 = c0; b1 = c1; xB = xC;
                c0 = d0; c1 = d1;
            }
        }
        a_sa    += __shfl_xor(a_sa, 32, 64);
        a_sb    += __shfl_xor(a_sb, 32, 64);
        a_va01.x += __shfl_xor(a_va01.x, 32, 64);
        a_va01.y += __shfl_xor(a_va01.y, 32, 64);
        a_vb01.x += __shfl_xor(a_vb01.x, 32, 64);
        a_vb01.y += __shfl_xor(a_vb01.y, 32, 64);
        a_va2   += __shfl_xor(a_va2, 32, 64);
        a_vb2   += __shfl_xor(a_vb2, 32, 64);

        unsigned short* ap = sAgg + nl * 264;
        if (half == 0) {
            ap[u]       = f2bf(a_sa);
            ap[32 + u]  = f2bf(a_sb);
            ap[64 + u]  = f2bf(a_va01.x);
            ap[96 + u]  = f2bf(a_vb01.x);
        } else {
            ap[128 + u] = f2bf(a_va01.y);
            ap[160 + u] = f2bf(a_vb01.y);
            ap[192 + u] = f2bf(a_va2);
            ap[224 + u] = f2bf(a_vb2);
        }
    }
    __syncthreads();

    // ---- phase 2: MFMA output ----
    int col = lane & 15;
    int quad = lane >> 4;
    int m = col;
    bool is_s = (wv == 0);
    int sub = wv - 1;

    const short* Bs = (const short*)(is_s ? bsc0 : bsc1);
    const short* B2 = (const short*)(is_s ? b20 : b21);

    int aBase, fbase, fstep, n_a;
    if (is_s) {
        aBase = m * 264;
        fbase = m * 33;
        fstep = 1;
        n_a = nbase + m;
    } else {
        int r16 = 16 * sub + m;
        int nl = r16 / 3;
        int dd = r16 - nl * 3;
        aBase = nl * 264 + 64 + 64 * dd;
        fbase = nl * 100 + dd;
        fstep = 3;
        n_a = nbase + nl;
    }
    float4 A0 = *(const float4*)(node_attr + (size_t)n_a * 8);
    float4 A1 = *(const float4*)(node_attr + (size_t)n_a * 8 + 4);
    float aa0 = A0.x, aa1 = A0.y, aa2 = A0.z, aa3 = A0.w;
    float aa4 = A1.x, aa5 = A1.y, aa6 = A1.z, aa7 = A1.w;

    f32x4 acc0 = {0.f, 0.f, 0.f, 0.f};
    f32x4 acc1 = {0.f, 0.f, 0.f, 0.f};

#pragma unroll
    for (int kc = 0; kc < 2; ++kc) {
        short8 af = *(const short8*)((const short*)sAgg + aBase + kc * 32 + quad * 8);
        short8 bf0 = *(const short8*)(B2 + ((kc * 2 + 0) * 64 + lane) * 8);
        short8 bf1 = *(const short8*)(B2 + ((kc * 2 + 1) * 64 + lane) * 8);
        acc0 = __builtin_amdgcn_mfma_f32_16x16x32_bf16(af, bf0, acc0, 0, 0, 0);
        acc1 = __builtin_amdgcn_mfma_f32_16x16x32_bf16(af, bf1, acc1, 0, 0, 0);
    }
    const float* Sf = is_s ? sS : sV;
#pragma unroll
    for (int kc = 0; kc < 8; ++kc) {
        int uu = kc * 4 + quad;
        float f = Sf[fbase + uu * fstep];
        U8 af;
        af.u[0] = ptk(f * aa0, f * aa1);
        af.u[1] = ptk(f * aa2, f * aa3);
        af.u[2] = ptk(f * aa4, f * aa5);
        af.u[3] = ptk(f * aa6, f * aa7);
        short8 bf0 = *(const short8*)(Bs + ((kc * 2 + 0) * 64 + lane) * 8);
        short8 bf1 = *(const short8*)(Bs + ((kc * 2 + 1) * 64 + lane) * 8);
        acc0 = __builtin_amdgcn_mfma_f32_16x16x32_bf16(af.v, bf0, acc0, 0, 0, 0);
        acc1 = __builtin_amdgcn_mfma_f32_16x16x32_bf16(af.v, bf1, acc1, 0, 0, 0);
    }

    C4 c0, c1;
    c0.v = acc0; c1.v = acc1;
    if (is_s) {
#pragma unroll
        for (int r = 0; r < 4; ++r) {
            int n = nbase + (quad << 2) + r;
            out[(size_t)n * 128 + col]      = c0.f[r];
            out[(size_t)n * 128 + col + 16] = c1.f[r];
        }
    } else {
#pragma unroll
        for (int r = 0; r < 4; ++r) {
            int rl = 16 * sub + (quad << 2) + r;
            int nn = rl / 3;
            int dd = rl - nn * 3;
            int n = nbase + nn;
            out[(size_t)n * 128 + 32 + 3 * col + dd]        = c0.f[r];
            out[(size_t)n * 128 + 32 + 3 * (col + 16) + dd] = c1.f[r];
        }
    }
}

extern "C" void kernel_launch(void* const* d_in, const int* in_sizes, int n_in,
                              void* d_out, int out_size, void* d_ws, size_t ws_size,
                              hipStream_t stream) {
    const float* node_s       = (const float*)d_in[0];
    const float* node_v       = (const float*)d_in[1];
    const float* node_attr    = (const float*)d_in[2];
    const float* edge_attr    = (const float*)d_in[3];
    const float* edge_scalars = (const float*)d_in[4];
    const float* W1_0 = (const float*)d_in[5];
    const float* W1_1 = (const float*)d_in[6];
    const float* Wfc1 = (const float*)d_in[7];
    const float* Wfc2 = (const float*)d_in[8];
    const float* W2_0 = (const float*)d_in[9];
    const float* W2_1 = (const float*)d_in[10];
    const float* Wsc0 = (const float*)d_in[11];
    const float* Wsc1 = (const float*)d_in[12];
    const int* edge_src = (const int*)d_in[13];
    const int* edge_dst = (const int*)d_in[14];

    // workspace layout (bytes), total ~23.4MB
    char* ws = (char*)d_ws;
    unsigned short* xnode = (unsigned short*)(ws);              // N*128*2 = 7,680,000
    uint4* rec            = (uint4*)(ws + 7680000);             // E*32    = 15,360,000
    int* deg    = (int*)(ws + 23040000);                        // N*4
    int* offs   = (int*)(ws + 23160000);                        // (N+1)*4 pad
    int* cursor = (int*)(ws + 23280016);                        // N*4
    unsigned* bsc0 = (unsigned*)(ws + 23400064);                // 16,384
    unsigned* bsc1 = (unsigned*)(ws + 23416448);                // 16,384
    unsigned* b20  = (unsigned*)(ws + 23432832);                // 4,096
    unsigned* b21  = (unsigned*)(ws + 23436928);                // 4,096

    hipMemsetAsync(deg, 0, (size_t)N_NODES * sizeof(int), stream);
    k_pre<<<1879, 256, 0, stream>>>(node_s, node_v, W1_0, W1_1, Wsc0, Wsc1,
                                    W2_0, W2_1, edge_src, deg, xnode,
                                    bsc0, bsc1, b20, b21);
    scan_kernel<<<1, 1024, 0, stream>>>(deg, offs, cursor);
    fill_kernel<<<1875, 256, 0, stream>>>(edge_attr, edge_scalars, Wfc1,
                                          edge_src, edge_dst, cursor, rec);
    k_main<<<1875, 256, 0, stream>>>(offs, rec, Wfc2, xnode,
                                     node_s, node_v, node_attr,
                                     bsc0, bsc1, b20, b21, (float*)d_out);
}